// Round 1
// 1294.859 us; speedup vs baseline: 1.0247x; 1.0247x over previous
//
#include <hip/hip_runtime.h>
#include <hip/hip_bf16.h>
#include <math.h>

constexpr int kB   = 2;
constexpr int kS   = 1024;
constexpr int kD   = 1024;
constexpr int kH   = 16;
constexpr int kDH  = 64;
constexpr int kHID = 2048;
constexpr int kE   = 8;
constexpr int kTok = kB * kS;         // 2048
constexpr float kScale = 0.125f;
constexpr long long kOutLogits = (long long)kTok * kD;
constexpr long long kOutProbs  = kOutLogits + kE * kB;

using u16 = unsigned short;
typedef __attribute__((ext_vector_type(8))) short short8;
typedef __attribute__((ext_vector_type(4))) float f32x4;

__device__ __forceinline__ float b2f(u16 u) {
  union { unsigned int i; float f; } c; c.i = ((unsigned int)u) << 16; return c.f;
}
__device__ __forceinline__ u16 f2b(float f) {
  __hip_bfloat16 h = __float2bfloat16(f);
  u16 u; __builtin_memcpy(&u, &h, 2); return u;
}
__device__ __forceinline__ float ldIn(const void* p, long long i, int f32) {
  return f32 ? ((const float*)p)[i] : b2f(((const u16*)p)[i]);
}
__device__ __forceinline__ void ld8f(const void* p, long long i, int f32, float v[8]) {
  if (f32) {
    const float* fp = (const float*)p + i;
    float4 a = *(const float4*)fp, b = *(const float4*)(fp + 4);
    v[0]=a.x; v[1]=a.y; v[2]=a.z; v[3]=a.w; v[4]=b.x; v[5]=b.y; v[6]=b.z; v[7]=b.w;
  } else {
    short8 s = *(const short8*)((const u16*)p + i);
#pragma unroll
    for (int j = 0; j < 8; j++) v[j] = b2f((u16)s[j]);
  }
}
__device__ __forceinline__ void stOut(void* base, long long i, float v, int f32) {
  if (f32) ((float*)base)[i] = v; else ((u16*)base)[i] = f2b(v);
}

// async global->LDS, 16B per lane. LDS dest is wave-uniform base + lane*16.
__device__ __forceinline__ void gll16(const void* g, void* l) {
  __builtin_amdgcn_global_load_lds(
      (__attribute__((address_space(1))) unsigned int*)(unsigned long long)g,
      (__attribute__((address_space(3))) unsigned int*)l, 16, 0, 0);
}

__device__ __forceinline__ float blockReduceSum(float v) {
  __shared__ float sh[4];
  int lane = threadIdx.x & 63, wv = threadIdx.x >> 6;
#pragma unroll
  for (int o = 32; o; o >>= 1) v += __shfl_down(v, o, 64);
  __syncthreads();
  if (lane == 0) sh[wv] = v;
  __syncthreads();
  return sh[0] + sh[1] + sh[2] + sh[3];
}
__device__ __forceinline__ float blockReduceMax(float v) {
  __shared__ float sh[4];
  int lane = threadIdx.x & 63, wv = threadIdx.x >> 6;
#pragma unroll
  for (int o = 32; o; o >>= 1) v = fmaxf(v, __shfl_down(v, o, 64));
  __syncthreads();
  if (lane == 0) sh[wv] = v;
  __syncthreads();
  return fmaxf(fmaxf(sh[0], sh[1]), fmaxf(sh[2], sh[3]));
}

// ------------------------------------------------------------- detect -------
__global__ void detect_k(const void* x, int* dflag) {
  __shared__ int sg, st;
  int tid = threadIdx.x;
  if (tid == 0) { sg = 0; st = 0; }
  __syncthreads();
  const unsigned int* w = (const unsigned int*)x;
  int good = 0, tot = 0;
  for (int i = tid; i < 1024; i += 256) {
    unsigned int lo = w[i] & 0xffffu;
    if (lo) {
      tot++;
      unsigned int e = (lo >> 7) & 0xffu;
      if (e >= 97 && e <= 159) good++;
    }
  }
  atomicAdd(&sg, good); atomicAdd(&st, tot);
  __syncthreads();
  if (tid == 0) dflag[0] = (sg * 10 < st * 9) ? 1 : 0;
}

// --------------------------------------- high-precision split-bf16 GEMM -----
// C[M,N] (fp32) = A[M,K] @ B; A,B split hi+lo bf16; 3 MFMA terms
// (hh + hl + lh; ll dropped, rel err ~1.5e-5).
struct G3P {
  const void* A; const void* Bm; float* C;
  long long a0, a1, b0, b1, c0, c1;
  int zdiv, zA, zB, zC;
  int lda, ldb, ldc, M, N, K;
  int bT, aF, bF;
  const int* dflag;
  const void* bias;
};

__global__ __launch_bounds__(256) void gemm3_k(G3P p) {
  const int z = blockIdx.z;
  const int m0 = blockIdx.y * 64, n0 = blockIdx.x * 64;
  const int f32in = p.dflag[0];
  const int af32 = (p.aF == 2) || (p.aF == 1 && f32in);
  const int bf32 = (p.bF == 2) || (p.bF == 1 && f32in);
  const int gA = z + p.zA, gB = z + p.zB, gC = z + p.zC;
  const long long aoff = (long long)(gA / p.zdiv) * p.a0 + (long long)(gA % p.zdiv) * p.a1;
  const long long boff = (long long)(gB / p.zdiv) * p.b0 + (long long)(gB % p.zdiv) * p.b1;
  const long long coff = (long long)(gC / p.zdiv) * p.c0 + (long long)(gC % p.zdiv) * p.c1;

  __shared__ short Ah[64][32], Al[64][32];
  __shared__ short Bh2[4][64][8], Bl2[4][64][8];

  const int tid = threadIdx.x;
  const int wave = tid >> 6, lane = tid & 63;
  const int wr = wave >> 1, wc = wave & 1;
  const int quad = lane >> 4, l16 = lane & 15;

  const int arow = tid >> 2, ak = (tid & 3) * 8;
  const long long abase = aoff + (long long)(m0 + arow) * p.lda + ak;
  const int btn = tid >> 2, btkg = tid & 3;   // bT=1 coords
  const int bn = tid & 63, bkg = tid >> 6;    // bT=0 coords

  f32x4 acc[2][2];
  const f32x4 z4 = {0.f, 0.f, 0.f, 0.f};
  acc[0][0] = z4; acc[0][1] = z4; acc[1][0] = z4; acc[1][1] = z4;

  for (int k0 = 0; k0 < p.K; k0 += 32) {
    float va[8];
    ld8f(p.A, abase + k0, af32, va);
    short8 ah8, al8;
#pragma unroll
    for (int j = 0; j < 8; j++) {
      u16 h = f2b(va[j]);
      ah8[j] = (short)h;
      al8[j] = (short)f2b(va[j] - b2f(h));
    }
    *(short8*)(&Ah[arow][ak]) = ah8;
    *(short8*)(&Al[arow][ak]) = al8;

    short8 bh8, bl8;
    if (p.bT) {
      float vb[8];
      ld8f(p.Bm, boff + (long long)(n0 + btn) * p.ldb + k0 + btkg * 8, bf32, vb);
#pragma unroll
      for (int j = 0; j < 8; j++) {
        u16 h = f2b(vb[j]);
        bh8[j] = (short)h;
        bl8[j] = (short)f2b(vb[j] - b2f(h));
      }
      *(short8*)(&Bh2[btkg][btn][0]) = bh8;
      *(short8*)(&Bl2[btkg][btn][0]) = bl8;
    } else {
#pragma unroll
      for (int j = 0; j < 8; j++) {
        float v = ldIn(p.Bm, boff + (long long)(k0 + bkg * 8 + j) * p.ldb + n0 + bn, bf32);
        u16 h = f2b(v);
        bh8[j] = (short)h;
        bl8[j] = (short)f2b(v - b2f(h));
      }
      *(short8*)(&Bh2[bkg][bn][0]) = bh8;
      *(short8*)(&Bl2[bkg][bn][0]) = bl8;
    }
    __syncthreads();
    short8 ah0 = *(const short8*)(&Ah[wr * 32 + l16][quad * 8]);
    short8 ah1 = *(const short8*)(&Ah[wr * 32 + 16 + l16][quad * 8]);
    short8 al0 = *(const short8*)(&Al[wr * 32 + l16][quad * 8]);
    short8 al1 = *(const short8*)(&Al[wr * 32 + 16 + l16][quad * 8]);
    short8 bh0 = *(const short8*)(&Bh2[quad][wc * 32 + l16][0]);
    short8 bh1 = *(const short8*)(&Bh2[quad][wc * 32 + 16 + l16][0]);
    short8 bl0 = *(const short8*)(&Bl2[quad][wc * 32 + l16][0]);
    short8 bl1 = *(const short8*)(&Bl2[quad][wc * 32 + 16 + l16][0]);
    acc[0][0] = __builtin_amdgcn_mfma_f32_16x16x32_bf16(al0, bh0, acc[0][0], 0, 0, 0);
    acc[0][1] = __builtin_amdgcn_mfma_f32_16x16x32_bf16(al0, bh1, acc[0][1], 0, 0, 0);
    acc[1][0] = __builtin_amdgcn_mfma_f32_16x16x32_bf16(al1, bh0, acc[1][0], 0, 0, 0);
    acc[1][1] = __builtin_amdgcn_mfma_f32_16x16x32_bf16(al1, bh1, acc[1][1], 0, 0, 0);
    acc[0][0] = __builtin_amdgcn_mfma_f32_16x16x32_bf16(ah0, bl0, acc[0][0], 0, 0, 0);
    acc[0][1] = __builtin_amdgcn_mfma_f32_16x16x32_bf16(ah0, bl1, acc[0][1], 0, 0, 0);
    acc[1][0] = __builtin_amdgcn_mfma_f32_16x16x32_bf16(ah1, bl0, acc[1][0], 0, 0, 0);
    acc[1][1] = __builtin_amdgcn_mfma_f32_16x16x32_bf16(ah1, bl1, acc[1][1], 0, 0, 0);
    acc[0][0] = __builtin_amdgcn_mfma_f32_16x16x32_bf16(ah0, bh0, acc[0][0], 0, 0, 0);
    acc[0][1] = __builtin_amdgcn_mfma_f32_16x16x32_bf16(ah0, bh1, acc[0][1], 0, 0, 0);
    acc[1][0] = __builtin_amdgcn_mfma_f32_16x16x32_bf16(ah1, bh0, acc[1][0], 0, 0, 0);
    acc[1][1] = __builtin_amdgcn_mfma_f32_16x16x32_bf16(ah1, bh1, acc[1][1], 0, 0, 0);
    __syncthreads();
  }

#pragma unroll
  for (int sm = 0; sm < 2; sm++) {
#pragma unroll
    for (int r = 0; r < 4; r++) {
      int row = m0 + wr * 32 + sm * 16 + quad * 4 + r;
#pragma unroll
      for (int sn = 0; sn < 2; sn++) {
        int col = n0 + wc * 32 + sn * 16 + l16;
        float v = acc[sm][sn][r];
        if (p.bias) v += ldIn(p.bias, col, f32in);
        p.C[coff + (long long)row * p.ldc + col] = v;
      }
    }
  }
}

// ------------------------------------- MoE weight repack fp32 -> bf16 -------
// dst layout per expert: [kb=K/32][kg=4][n=N][j=8] bf16, so each MFMA B
// fragment slice (8 consecutive k at fixed n) is one contiguous 16B granule.
// One thread = one output granule. gid*8 is exactly the dst element offset.
__global__ __launch_bounds__(256) void cvtW_k(const void* src, u16* dst,
                                              int nSh, int kbSh, const int* dflag) {
  const int f32 = dflag[0];
  const int gid = blockIdx.x * 256 + threadIdx.x;
  const int N = 1 << nSh;
  const int n = gid & (N - 1);
  const int rest = gid >> nSh;
  const int kg = rest & 3;
  const int kb = (rest >> 2) & ((1 << kbSh) - 1);
  const int e = rest >> (2 + kbSh);
  const long long src0 = ((long long)e << (5 + kbSh + nSh)) +
                         (long long)(kb * 32 + kg * 8) * N + n;
  short8 o;
#pragma unroll
  for (int j = 0; j < 8; j++) o[j] = (short)f2b(ldIn(src, src0 + (long long)j * N, f32));
  *(short8*)(dst + (long long)gid * 8) = o;
}

// x2f (fp32) -> bf16, linear layout (row-major [tok][kD])
__global__ __launch_bounds__(256) void cvtX_k(const float* src, u16* dst) {
  const int gid = blockIdx.x * 256 + threadIdx.x;
  const float* s = src + (long long)gid * 8;
  float4 a = *(const float4*)s, b = *(const float4*)(s + 4);
  short8 o;
  o[0]=(short)f2b(a.x); o[1]=(short)f2b(a.y); o[2]=(short)f2b(a.z); o[3]=(short)f2b(a.w);
  o[4]=(short)f2b(b.x); o[5]=(short)f2b(b.y); o[6]=(short)f2b(b.z); o[7]=(short)f2b(b.w);
  *(short8*)(dst + (long long)gid * 8) = o;
}

// -------------------------------------------- fused MoE W1/W3 + SwiGLU ------
// 128x128 tile, 512 threads (2x4 waves, each wave owns 64x32 of each output),
// global_load_lds staging (3 issues/K-step, zero staging VALU/VGPR).
__global__ __launch_bounds__(512) void moe13_k(const u16* Xb, const u16* W1c, const u16* W3c,
                                               const int* counts, const int* offsets,
                                               const int* aidxArr, u16* Hbuf) {
  const int e = blockIdx.z;
  const int Meff = counts[e];
  const int m0 = blockIdx.y * 128;
  if (m0 >= Meff) return;
  const int n0 = blockIdx.x * 128;
  const int csr = offsets[e];

  __shared__ __align__(16) u16 As[128][32];
  __shared__ __align__(16) u16 B1s[4][128][8];
  __shared__ __align__(16) u16 B3s[4][128][8];

  const int tid = threadIdx.x, wave = tid >> 6, lane = tid & 63;
  const int wr = wave >> 2, wc = wave & 3, quad = lane >> 4, l16 = lane & 15;

  int grow = m0 + (tid >> 2); if (grow >= Meff) grow = Meff - 1;
  const u16* pA = Xb + (long long)aidxArr[csr + grow] * kD + (tid & 3) * 8;
  const long long bOff = (long long)e * kD * kHID +
                         ((long long)(tid >> 7) * kHID + n0 + (tid & 127)) * 8;
  const u16* pB1 = W1c + bOff;
  const u16* pB3 = W3c + bOff;

  char* aDst  = (char*)&As[0][0]     + (wave << 10);
  char* b1Dst = (char*)&B1s[0][0][0] + (wave << 10);
  char* b3Dst = (char*)&B3s[0][0][0] + (wave << 10);

  f32x4 acc1[4][2], acc3[4][2];
  const f32x4 z4 = {0.f, 0.f, 0.f, 0.f};
#pragma unroll
  for (int i = 0; i < 4; i++) { acc1[i][0]=z4; acc1[i][1]=z4; acc3[i][0]=z4; acc3[i][1]=z4; }

  for (int kb = 0; kb < kD / 32; kb++) {
    gll16(pA, aDst);
    gll16(pB1, b1Dst);
    gll16(pB3, b3Dst);
    pA += 32; pB1 += 4 * kHID * 8; pB3 += 4 * kHID * 8;
    __syncthreads();
    short8 af[4], b1f[2], b3f[2];
#pragma unroll
    for (int sm = 0; sm < 4; sm++)
      af[sm] = *(const short8*)&As[wr * 64 + sm * 16 + l16][quad * 8];
#pragma unroll
    for (int sn = 0; sn < 2; sn++) {
      b1f[sn] = *(const short8*)&B1s[quad][wc * 32 + sn * 16 + l16][0];
      b3f[sn] = *(const short8*)&B3s[quad][wc * 32 + sn * 16 + l16][0];
    }
#pragma unroll
    for (int sm = 0; sm < 4; sm++) {
#pragma unroll
      for (int sn = 0; sn < 2; sn++) {
        acc1[sm][sn] = __builtin_amdgcn_mfma_f32_16x16x32_bf16(af[sm], b1f[sn], acc1[sm][sn], 0, 0, 0);
        acc3[sm][sn] = __builtin_amdgcn_mfma_f32_16x16x32_bf16(af[sm], b3f[sn], acc3[sm][sn], 0, 0, 0);
      }
    }
    __syncthreads();
  }

#pragma unroll
  for (int sm = 0; sm < 4; sm++) {
#pragma unroll
    for (int r = 0; r < 4; r++) {
      int row = m0 + wr * 64 + sm * 16 + quad * 4 + r;
      if (row >= Meff) continue;
#pragma unroll
      for (int sn = 0; sn < 2; sn++) {
        int col = n0 + wc * 32 + sn * 16 + l16;
        float g1 = acc1[sm][sn][r], g3 = acc3[sm][sn][r];
        float h = (g1 / (1.f + __expf(-g1))) * g3;
        Hbuf[(long long)(csr + row) * kHID + col] = f2b(h);
      }
    }
  }
}

// ------------------------------------------------ MoE W2 + scatter ---------
__global__ __launch_bounds__(512) void w2_k(const u16* Hbuf, const u16* W2c,
                                            const int* counts, const int* offsets,
                                            const int* aidxArr, const int* slotArr,
                                            const float* wgtArr, float* contrib) {
  const int e = blockIdx.z;
  const int Meff = counts[e];
  const int m0 = blockIdx.y * 128;
  if (m0 >= Meff) return;
  const int n0 = blockIdx.x * 128;
  const int csr = offsets[e];

  __shared__ __align__(16) u16 As[128][32];
  __shared__ __align__(16) u16 Bs[4][128][8];

  const int tid = threadIdx.x, wave = tid >> 6, lane = tid & 63;
  const int wr = wave >> 2, wc = wave & 3, quad = lane >> 4, l16 = lane & 15;

  int grow = m0 + (tid >> 2); if (grow >= Meff) grow = Meff - 1;
  const u16* pA = Hbuf + (long long)(csr + grow) * kHID + (tid & 3) * 8;
  const u16* pB = W2c + (long long)e * kHID * kD +
                  ((long long)(tid >> 7) * kD + n0 + (tid & 127)) * 8;

  char* aDst = (char*)&As[0][0]    + (wave << 10);
  char* bDst = (char*)&Bs[0][0][0] + (wave << 10);

  f32x4 acc[4][2];
  const f32x4 z4 = {0.f, 0.f, 0.f, 0.f};
#pragma unroll
  for (int i = 0; i < 4; i++) { acc[i][0] = z4; acc[i][1] = z4; }

  for (int kb = 0; kb < kHID / 32; kb++) {
    gll16(pA, aDst);
    gll16(pB, bDst);
    pA += 32; pB += 4 * kD * 8;
    __syncthreads();
    short8 af[4], bf[2];
#pragma unroll
    for (int sm = 0; sm < 4; sm++)
      af[sm] = *(const short8*)&As[wr * 64 + sm * 16 + l16][quad * 8];
#pragma unroll
    for (int sn = 0; sn < 2; sn++)
      bf[sn] = *(const short8*)&Bs[quad][wc * 32 + sn * 16 + l16][0];
#pragma unroll
    for (int sm = 0; sm < 4; sm++) {
#pragma unroll
      for (int sn = 0; sn < 2; sn++)
        acc[sm][sn] = __builtin_amdgcn_mfma_f32_16x16x32_bf16(af[sm], bf[sn], acc[sm][sn], 0, 0, 0);
    }
    __syncthreads();
  }

#pragma unroll
  for (int sm = 0; sm < 4; sm++) {
#pragma unroll
    for (int r = 0; r < 4; r++) {
      int row = m0 + wr * 64 + sm * 16 + quad * 4 + r;
      if (row >= Meff) continue;
      int a = csr + row;
      int t = aidxArr[a]; int s = slotArr[a]; float w = wgtArr[a];
#pragma unroll
      for (int sn = 0; sn < 2; sn++) {
        int col = n0 + wc * 32 + sn * 16 + l16;
        contrib[((long long)s * kTok + t) * kD + col] = acc[sm][sn][r] * w;
      }
    }
  }
}

// ------------------------------------------------------------ small ops -----
__global__ void maskprep_k(const void* srcm, const void* tgtm, const void* midm,
                           float* srcf, float* padf, float* keepf, float* denom) {
  __shared__ int okInt, okFloat, okBf16;
  int tid = threadIdx.x;
  if (tid == 0) { okInt = 1; okFloat = 1; okBf16 = 1; }
  __syncthreads();
  const unsigned int* wi = (const unsigned int*)tgtm;
  const float* wf = (const float*)tgtm;
  int badI = 0, badF = 0, badB = 0;
  for (int i = tid; i < 512; i += 256) {
    unsigned int w = wi[i];
    if (w > 1u) badI = 1;
    float f = wf[i];
    if (!(f == 0.f || f == 1.f)) badF = 1;
    unsigned int lo = w & 0xffffu, hi = w >> 16;
    if (!((lo == 0 || lo == 0x3f80u) && (hi == 0 || hi == 0x3f80u))) badB = 1;
  }
  if (badI) atomicExch(&okInt, 0);
  if (badF) atomicExch(&okFloat, 0);
  if (badB) atomicExch(&okBf16, 0);
  __syncthreads();
  int mode = okInt ? 0 : (okFloat ? 2 : (okBf16 ? 3 : 1));
  for (int i = tid; i < kTok; i += 256) {
    bool sv, pv, mv;
    if (mode == 0) {
      sv = ((const int*)srcm)[i] != 0; pv = ((const int*)tgtm)[i] != 0; mv = ((const int*)midm)[i] != 0;
    } else if (mode == 2) {
      sv = ((const float*)srcm)[i] != 0.f; pv = ((const float*)tgtm)[i] != 0.f; mv = ((const float*)midm)[i] != 0.f;
    } else if (mode == 3) {
      sv = ((const u16*)srcm)[i] != 0; pv = ((const u16*)tgtm)[i] != 0; mv = ((const u16*)midm)[i] != 0;
    } else {
      sv = ((const unsigned char*)srcm)[i] != 0; pv = ((const unsigned char*)tgtm)[i] != 0; mv = ((const unsigned char*)midm)[i] != 0;
    }
    srcf[i] = sv ? 1.f : 0.f;
    padf[i] = pv ? 1.f : 0.f;
    keepf[i] = (pv || mv) ? 0.f : 1.f;
  }
  __syncthreads();
  if (tid < 2) {
    float s = 0;
    for (int j = 0; j < kS; j++) s += keepf[tid * kS + j];
    denom[tid] = fmaxf(s, 1.f);
  }
}

__global__ __launch_bounds__(256) void softmax_k(float* sc, const float* maskf, int zbase) {
  int row = blockIdx.x;
  int gz = zbase + (row >> 10);
  int b = gz >> 4;
  const long long base = (long long)row * kS;
  int tid = threadIdx.x;
  float s[4];
#pragma unroll
  for (int i = 0; i < 4; i++) {
    int j = tid + i * 256;
    float v = sc[base + j] * kScale;
    if (maskf[b * kS + j] != 0.f) v = -1e30f;
    s[i] = v;
  }
  float mx = blockReduceMax(fmaxf(fmaxf(s[0], s[1]), fmaxf(s[2], s[3])));
  float sum = 0;
#pragma unroll
  for (int i = 0; i < 4; i++) { s[i] = __expf(s[i] - mx); sum += s[i]; }
  sum = blockReduceSum(sum);
  float inv = 1.f / sum;
#pragma unroll
  for (int i = 0; i < 4; i++) {
    int j = tid + i * 256;
    sc[base + j] = s[i] * inv;
  }
}

__global__ __launch_bounds__(256) void ln_k(const float* basef, const void* baseb,
                                            const int* dflag, int baseIsIn,
                                            const float* add1, const float* add2,
                                            const void* g, const void* bb,
                                            float* outf, void* outFinal) {
  const int f32in = dflag[0];
  const int baseF32 = baseIsIn && f32in;
  long long base = (long long)blockIdx.x * kD;
  int tid = threadIdx.x;
  float v[4]; float s = 0;
#pragma unroll
  for (int i = 0; i < 4; i++) {
    int d = tid + i * 256;
    float x = basef ? basef[base + d] : ldIn(baseb, base + d, baseF32);
    if (add1) x += add1[base + d];
    if (add2) x += add2[base + d];
    v[i] = x; s += x;
  }
  float mean = blockReduceSum(s) * (1.f / kD);
  float q = 0;
#pragma unroll
  for (int i = 0; i < 4; i++) { float d0 = v[i] - mean; q += d0 * d0; }
  float var = blockReduceSum(q) * (1.f / kD);
  float rstd = rsqrtf(var + 1e-5f);
#pragma unroll
  for (int i = 0; i < 4; i++) {
    int d = tid + i * 256;
    float y = (v[i] - mean) * rstd * ldIn(g, d, f32in) + ldIn(bb, d, f32in);
    if (outf) outf[base + d] = y;
    if (outFinal) stOut(outFinal, base + d, y, f32in);
  }
}

__global__ __launch_bounds__(256) void router_k(const float* xf, const void* gw, void* outBase,
                                                int* sel, float* wsel, int* counts,
                                                const int* dflag) {
  const int f32in = dflag[0];
  int wv = threadIdx.x >> 6, lane = threadIdx.x & 63;
  int t = blockIdx.x * 4 + wv;
  const float* xr = xf + (long long)t * kD;
  float acc[8];
#pragma unroll
  for (int e = 0; e < 8; e++) acc[e] = 0.f;
  for (int d = lane; d < kD; d += 64) {
    float xv = xr[d];
    float gv[8];
    ld8f(gw, (long long)d * 8, f32in, gv);
#pragma unroll
    for (int e = 0; e < 8; e++) acc[e] += xv * gv[e];
  }
#pragma unroll
  for (int o = 32; o; o >>= 1) {
#pragma unroll
    for (int e = 0; e < 8; e++) acc[e] += __shfl_down(acc[e], o, 64);
  }
  if (lane == 0) {
    float mx = acc[0];
    for (int e = 1; e < 8; e++) mx = fmaxf(mx, acc[e]);
    float p[8], sum = 0;
    for (int e = 0; e < 8; e++) { p[e] = expf(acc[e] - mx); sum += p[e]; }
    float inv = 1.f / sum;
    for (int e = 0; e < 8; e++) {
      p[e] *= inv;
      stOut(outBase, kOutProbs + (long long)t * 8 + e, p[e], f32in);
    }
    int e0 = 0; for (int e = 1; e < 8; e++) if (p[e] > p[e0]) e0 = e;
    int e1 = -1; for (int e = 0; e < 8; e++) { if (e == e0) continue; if (e1 < 0 || p[e] > p[e1]) e1 = e; }
    float s2 = p[e0] + p[e1];
    sel[t * 2] = e0; sel[t * 2 + 1] = e1;
    wsel[t * 2] = p[e0] / s2; wsel[t * 2 + 1] = p[e1] / s2;
    atomicAdd(&counts[e0], 1); atomicAdd(&counts[e1], 1);
  }
}

__global__ void offsets_k(const int* counts, int* offsets) {
  if (threadIdx.x == 0) {
    int s = 0;
    for (int e = 0; e < kE; e++) { offsets[e] = s; s += counts[e]; }
    offsets[kE] = s;
  }
}

__global__ void place_k(const int* sel, const float* wsel, const int* offsets, int* fill,
                        int* aidxArr, int* slotArr, float* wgtArr) {
  int t = blockIdx.x * 256 + threadIdx.x;
  if (t >= kTok) return;
  for (int s = 0; s < 2; s++) {
    int e = sel[t * 2 + s];
    int pos = offsets[e] + atomicAdd(&fill[e], 1);
    aidxArr[pos] = t; slotArr[pos] = s; wgtArr[pos] = wsel[t * 2 + s];
  }
}

__global__ void meanacc_k(const int* counts, const int* offsets, const int* aidxArr,
                          const int* slotArr, const float* keepf, const float* contrib,
                          float* meanAcc) {
  int e = blockIdx.x, dc = blockIdx.y, ch = blockIdx.z;
  int d = dc * 128 + threadIdx.x;
  int cnt = counts[e], off = offsets[e];
  int per = (cnt + 15) / 16;
  int i0 = ch * per, i1 = i0 + per; if (i1 > cnt) i1 = cnt;
  float a0 = 0, a1 = 0;
  for (int i = i0; i < i1; i++) {
    int a = off + i; int t = aidxArr[a];
    if (keepf[t] != 0.f) {
      float v = contrib[((long long)slotArr[a] * kTok + t) * kD + d];
      if (t < kS) a0 += v; else a1 += v;
    }
  }
  if (a0 != 0.f) atomicAdd(&meanAcc[(e * 2 + 0) * kD + d], a0);
  if (a1 != 0.f) atomicAdd(&meanAcc[(e * 2 + 1) * kD + d], a1);
}

__global__ __launch_bounds__(256) void dots_k(const float* meanAcc, const void* cls_w,
                                              const float* denom, float* dots,
                                              const int* dflag) {
  const int f32in = dflag[0];
  int eb = blockIdx.x;
  int b = eb & 1;
  float s = 0;
  for (int d = threadIdx.x; d < kD; d += 256)
    s += meanAcc[(long long)eb * kD + d] * ldIn(cls_w, d, f32in);
  s = blockReduceSum(s);
  if (threadIdx.x == 0) dots[eb] = s / denom[b];
}

__global__ void final_logits_k(const float* dots, const void* cls_b, void* outBase,
                               const int* dflag) {
  const int f32in = dflag[0];
  int i = threadIdx.x;
  if (i < kE * kB) {
    int e = i >> 1, b = i & 1;
    float s = ldIn(cls_b, 0, f32in);
    for (int e2 = 0; e2 <= e; e2++) s += dots[e2 * 2 + b];
    stOut(outBase, kOutLogits + e * kB + b, s, f32in);
  }
}

// ------------------------------------------------------------------ host ----
extern "C" void kernel_launch(void* const* d_in, const int* in_sizes, int n_in,
                              void* d_out, int out_size, void* d_ws, size_t ws_size,
                              hipStream_t stream) {
  (void)in_sizes; (void)n_in; (void)out_size; (void)ws_size;

  const void* x_in  = d_in[0];
  const void* enc   = d_in[1];
  const void* srcm = d_in[2];
  const void* tgtm = d_in[3];
  const void* midm = d_in[4];
  const void* ln1g = d_in[5];  const void* ln1b = d_in[6];
  const void* ln2g = d_in[7];  const void* ln2b = d_in[8];
  const void* ln3g = d_in[9];  const void* ln3b = d_in[10];
  const void* sa_wq = d_in[11]; const void* sa_wk = d_in[12];
  const void* sa_wv = d_in[13]; const void* sa_wo = d_in[14];
  const void* sa_bo = d_in[15];
  const void* ca_wq = d_in[16]; const void* ca_wk = d_in[17];
  const void* ca_wv = d_in[18]; const void* ca_wo = d_in[19];
  const void* ca_bo = d_in[20];
  const void* gate_w = d_in[21];
  const void* cls_w  = d_in[22]; const void* cls_b = d_in[23];
  const void* moe_w1 = d_in[24];
  const void* moe_w2 = d_in[25];
  const void* moe_w3 = d_in[26];

  char* wp = (char*)d_ws;
  size_t off = 0;
  auto alloc = [&](size_t bytes) -> void* {
    void* p = wp + off; off = (off + bytes + 255) & ~(size_t)255; return p;
  };
  float* scFP = (float*)alloc((size_t)16 * kS * kS * 4);          // 64 MiB
  u16*   Hbuf = (u16*)scFP;                                        // [0,16) MiB
  float* contrib = (float*)((char*)scFP + (size_t)2 * kTok * kHID * 2); // [16,32) MiB
  float* qf    = (float*)alloc((size_t)kTok * kD * 4);
  float* kf    = (float*)alloc((size_t)kTok * kD * 4);
  float* vf    = (float*)alloc((size_t)kTok * kD * 4);
  float* attnof= (float*)alloc((size_t)kTok * kD * 4);
  float* obuf  = (float*)alloc((size_t)kTok * kD * 4);
  float* x1f   = (float*)alloc((size_t)kTok * kD * 4);
  float* x2f   = (float*)alloc((size_t)kTok * kD * 4);
  float* meanAcc = (float*)alloc((size_t)kE * kB * kD * 4);
  float* srcf = (float*)alloc(kTok * 4);
  float* padf = (float*)alloc(kTok * 4);
  float* keepf = (float*)alloc(kTok * 4);
  float* denom = (float*)alloc(2 * 4);
  int* counts = (int*)alloc(256); int* fill = counts + 8;
  int* offsets = (int*)alloc(256);
  int* sel = (int*)alloc(kTok * 2 * 4);
  float* wsel = (float*)alloc(kTok * 2 * 4);
  int* aidxArr = (int*)alloc(2 * kTok * 4);
  int* slotArr = (int*)alloc(2 * kTok * 4);
  float* wgtArr = (float*)alloc(2 * kTok * 4);
  float* dots = (float*)alloc(256);
  int* dflag = (int*)alloc(256);

  // MoE repack buffers live in regions that are dead by the time MoE runs:
  //   W1c: qf..attnof   (32 MiB contiguous, dead after cross-attn)
  //   W3c: scFP+[32,64) MiB (scores dead after cross-attn; Hbuf/contrib below 32 MiB)
  //   W2c: same region as W1c, converted AFTER moe13_k consumed W1c (stream order)
  //   Xb : obuf (4 MiB of 8, dead after ln2)
  u16* W1c = (u16*)qf;
  u16* W2c = (u16*)qf;
  u16* W3c = (u16*)((char*)scFP + ((size_t)32 << 20));
  u16* Xb  = (u16*)obuf;

  auto g3 = [&](const void* A, const void* Bmat, float* C, int M, int N, int K,
                int lda, int ldb, int ldc, int bT, int aF, int bF,
                long long a0, long long a1, long long b0, long long b1,
                long long c0, long long c1, int zdiv, int zA, int zB, int zC,
                int nz, const void* bias) {
    G3P p;
    p.A = A; p.Bm = Bmat; p.C = C;
    p.a0 = a0; p.a1 = a1; p.b0 = b0; p.b1 = b1; p.c0 = c0; p.c1 = c1;
    p.zdiv = zdiv; p.zA = zA; p.zB = zB; p.zC = zC;
    p.lda = lda; p.ldb = ldb; p.ldc = ldc; p.M = M; p.N = N; p.K = K;
    p.bT = bT; p.aF = aF; p.bF = bF; p.dflag = dflag; p.bias = bias;
    dim3 grid(N / 64, M / 64, nz);
    gemm3_k<<<grid, dim3(256), 0, stream>>>(p);
  };

  hipMemsetAsync(counts, 0, 64, stream);
  hipMemsetAsync(meanAcc, 0, (size_t)kE * kB * kD * 4, stream);
  detect_k<<<1, 256, 0, stream>>>(x_in, dflag);
  maskprep_k<<<1, 256, 0, stream>>>(srcm, tgtm, midm, srcf, padf, keepf, denom);

  const long long SD = (long long)kS * kD;
  const long long SS = (long long)kS * kS;

  auto attention = [&](const void* qsrc, int qF, const void* ksrc, int kvF,
                       const void* wq, const void* wk, const void* wv,
                       const void* wo, const void* bo, const float* maskf) {
    g3(qsrc, wq, qf, kTok, kD, kD, kD, kD, kD, 0, qF, 1, 0,0,0,0,0,0, 1,0,0,0, 1, nullptr);
    g3(ksrc, wk, kf, kTok, kD, kD, kD, kD, kD, 0, kvF, 1, 0,0,0,0,0,0, 1,0,0,0, 1, nullptr);
    g3(ksrc, wv, vf, kTok, kD, kD, kD, kD, kD, 0, kvF, 1, 0,0,0,0,0,0, 1,0,0,0, 1, nullptr);
    for (int c = 0; c < 2; c++) {
      int zb = c * 16;
      g3(qf, kf, scFP, kS, kS, kDH, kD, kD, kS, 1, 2, 2,
         SD, 64, SD, 64, 0, SS, 16, zb, zb, 0, 16, nullptr);
      softmax_k<<<16 * kS, 256, 0, stream>>>(scFP, maskf, zb);
      g3(scFP, vf, attnof, kS, kDH, kS, kS, kD, kD, 0, 2, 2,
         0, SS, SD, 64, SD, 64, 16, 0, zb, zb, 16, nullptr);
    }
    g3(attnof, wo, obuf, kTok, kD, kD, kD, kD, kD, 0, 2, 1, 0,0,0,0,0,0, 1,0,0,0, 1, bo);
  };

  // ---- self attention ----
  attention(x_in, 1, x_in, 1, sa_wq, sa_wk, sa_wv, sa_wo, sa_bo, padf);
  ln_k<<<kTok, 256, 0, stream>>>(nullptr, x_in, dflag, 1, obuf, nullptr, ln1g, ln1b, x1f, nullptr);

  // ---- cross attention ----
  attention(x1f, 2, enc, 1, ca_wq, ca_wk, ca_wv, ca_wo, ca_bo, srcf);
  ln_k<<<kTok, 256, 0, stream>>>(x1f, nullptr, dflag, 0, obuf, nullptr, ln2g, ln2b, x2f, nullptr);

  // ---- MoE ----
  router_k<<<kTok / 4, 256, 0, stream>>>(x2f, gate_w, d_out, sel, wsel, counts, dflag);
  offsets_k<<<1, 64, 0, stream>>>(counts, offsets);
  place_k<<<kTok / 256, 256, 0, stream>>>(sel, wsel, offsets, fill, aidxArr, slotArr, wgtArr);

  // repack: x2f -> bf16, W1/W3 -> blocked fragment-ordered bf16
  cvtX_k<<<kTok * kD / (8 * 256), 256, 0, stream>>>(x2f, Xb);
  const int wGrid = (kE * kD * kHID / 8) / 256;   // 8192
  cvtW_k<<<wGrid, 256, 0, stream>>>(moe_w1, W1c, 11, 5, dflag);  // K=1024,N=2048
  cvtW_k<<<wGrid, 256, 0, stream>>>(moe_w3, W3c, 11, 5, dflag);

  moe13_k<<<dim3(kHID / 128, kTok / 128, kE), 512, 0, stream>>>(
      Xb, W1c, W3c, counts, offsets, aidxArr, Hbuf);

  cvtW_k<<<wGrid, 256, 0, stream>>>(moe_w2, W2c, 10, 6, dflag);  // K=2048,N=1024

  w2_k<<<dim3(kD / 128, kTok / 128, kE), 512, 0, stream>>>(
      Hbuf, W2c, counts, offsets, aidxArr, slotArr, wgtArr, contrib);

  meanacc_k<<<dim3(kE, kD / 128, 16), 128, 0, stream>>>(counts, offsets, aidxArr, slotArr, keepf, contrib, meanAcc);
  dots_k<<<kE * kB, 256, 0, stream>>>(meanAcc, cls_w, denom, dots, dflag);
  final_logits_k<<<1, 64, 0, stream>>>(dots, cls_b, d_out, dflag);
  ln_k<<<kTok, 256, 0, stream>>>(x2f, nullptr, dflag, 0, contrib, contrib + (size_t)kTok * kD, ln3g, ln3b, nullptr, d_out);
}

// Round 2
// 1131.277 us; speedup vs baseline: 1.1728x; 1.1446x over previous
//
#include <hip/hip_runtime.h>
#include <hip/hip_bf16.h>
#include <math.h>

constexpr int kB   = 2;
constexpr int kS   = 1024;
constexpr int kD   = 1024;
constexpr int kH   = 16;
constexpr int kDH  = 64;
constexpr int kHID = 2048;
constexpr int kE   = 8;
constexpr int kTok = kB * kS;         // 2048
constexpr float kScale = 0.125f;
constexpr long long kOutLogits = (long long)kTok * kD;
constexpr long long kOutProbs  = kOutLogits + kE * kB;

using u16 = unsigned short;
typedef __attribute__((ext_vector_type(8))) short short8;
typedef __attribute__((ext_vector_type(4))) float f32x4;

__device__ __forceinline__ float b2f(u16 u) {
  union { unsigned int i; float f; } c; c.i = ((unsigned int)u) << 16; return c.f;
}
__device__ __forceinline__ u16 f2b(float f) {
  __hip_bfloat16 h = __float2bfloat16(f);
  u16 u; __builtin_memcpy(&u, &h, 2); return u;
}
__device__ __forceinline__ float ldIn(const void* p, long long i, int f32) {
  return f32 ? ((const float*)p)[i] : b2f(((const u16*)p)[i]);
}
__device__ __forceinline__ void ld8f(const void* p, long long i, int f32, float v[8]) {
  if (f32) {
    const float* fp = (const float*)p + i;
    float4 a = *(const float4*)fp, b = *(const float4*)(fp + 4);
    v[0]=a.x; v[1]=a.y; v[2]=a.z; v[3]=a.w; v[4]=b.x; v[5]=b.y; v[6]=b.z; v[7]=b.w;
  } else {
    short8 s = *(const short8*)((const u16*)p + i);
#pragma unroll
    for (int j = 0; j < 8; j++) v[j] = b2f((u16)s[j]);
  }
}
__device__ __forceinline__ void stOut(void* base, long long i, float v, int f32) {
  if (f32) ((float*)base)[i] = v; else ((u16*)base)[i] = f2b(v);
}

// async global->LDS, 16B per lane. LDS dest is wave-uniform base + lane*16.
__device__ __forceinline__ void gll16(const void* g, void* l) {
  __builtin_amdgcn_global_load_lds(
      (__attribute__((address_space(1))) unsigned int*)(unsigned long long)g,
      (__attribute__((address_space(3))) unsigned int*)l, 16, 0, 0);
}

__device__ __forceinline__ float blockReduceSum(float v) {
  __shared__ float sh[4];
  int lane = threadIdx.x & 63, wv = threadIdx.x >> 6;
#pragma unroll
  for (int o = 32; o; o >>= 1) v += __shfl_down(v, o, 64);
  __syncthreads();
  if (lane == 0) sh[wv] = v;
  __syncthreads();
  return sh[0] + sh[1] + sh[2] + sh[3];
}
__device__ __forceinline__ float blockReduceMax(float v) {
  __shared__ float sh[4];
  int lane = threadIdx.x & 63, wv = threadIdx.x >> 6;
#pragma unroll
  for (int o = 32; o; o >>= 1) v = fmaxf(v, __shfl_down(v, o, 64));
  __syncthreads();
  if (lane == 0) sh[wv] = v;
  __syncthreads();
  return fmaxf(fmaxf(sh[0], sh[1]), fmaxf(sh[2], sh[3]));
}

// ------------------------------------------------------------- detect -------
__global__ void detect_k(const void* x, int* dflag) {
  __shared__ int sg, st;
  int tid = threadIdx.x;
  if (tid == 0) { sg = 0; st = 0; }
  __syncthreads();
  const unsigned int* w = (const unsigned int*)x;
  int good = 0, tot = 0;
  for (int i = tid; i < 1024; i += 256) {
    unsigned int lo = w[i] & 0xffffu;
    if (lo) {
      tot++;
      unsigned int e = (lo >> 7) & 0xffu;
      if (e >= 97 && e <= 159) good++;
    }
  }
  atomicAdd(&sg, good); atomicAdd(&st, tot);
  __syncthreads();
  if (tid == 0) dflag[0] = (sg * 10 < st * 9) ? 1 : 0;
}

// --------------------------------------- high-precision split-bf16 GEMM -----
// (retained for the z-batched QK^T and PV only)
struct G3P {
  const void* A; const void* Bm; float* C;
  long long a0, a1, b0, b1, c0, c1;
  int zdiv, zA, zB, zC;
  int lda, ldb, ldc, M, N, K;
  int bT, aF, bF;
  const int* dflag;
  const void* bias;
};

__global__ __launch_bounds__(256) void gemm3_k(G3P p) {
  const int z = blockIdx.z;
  const int m0 = blockIdx.y * 64, n0 = blockIdx.x * 64;
  const int f32in = p.dflag[0];
  const int af32 = (p.aF == 2) || (p.aF == 1 && f32in);
  const int bf32 = (p.bF == 2) || (p.bF == 1 && f32in);
  const int gA = z + p.zA, gB = z + p.zB, gC = z + p.zC;
  const long long aoff = (long long)(gA / p.zdiv) * p.a0 + (long long)(gA % p.zdiv) * p.a1;
  const long long boff = (long long)(gB / p.zdiv) * p.b0 + (long long)(gB % p.zdiv) * p.b1;
  const long long coff = (long long)(gC / p.zdiv) * p.c0 + (long long)(gC % p.zdiv) * p.c1;

  __shared__ short Ah[64][32], Al[64][32];
  __shared__ short Bh2[4][64][8], Bl2[4][64][8];

  const int tid = threadIdx.x;
  const int wave = tid >> 6, lane = tid & 63;
  const int wr = wave >> 1, wc = wave & 1;
  const int quad = lane >> 4, l16 = lane & 15;

  const int arow = tid >> 2, ak = (tid & 3) * 8;
  const long long abase = aoff + (long long)(m0 + arow) * p.lda + ak;
  const int btn = tid >> 2, btkg = tid & 3;   // bT=1 coords
  const int bn = tid & 63, bkg = tid >> 6;    // bT=0 coords

  f32x4 acc[2][2];
  const f32x4 z4 = {0.f, 0.f, 0.f, 0.f};
  acc[0][0] = z4; acc[0][1] = z4; acc[1][0] = z4; acc[1][1] = z4;

  for (int k0 = 0; k0 < p.K; k0 += 32) {
    float va[8];
    ld8f(p.A, abase + k0, af32, va);
    short8 ah8, al8;
#pragma unroll
    for (int j = 0; j < 8; j++) {
      u16 h = f2b(va[j]);
      ah8[j] = (short)h;
      al8[j] = (short)f2b(va[j] - b2f(h));
    }
    *(short8*)(&Ah[arow][ak]) = ah8;
    *(short8*)(&Al[arow][ak]) = al8;

    short8 bh8, bl8;
    if (p.bT) {
      float vb[8];
      ld8f(p.Bm, boff + (long long)(n0 + btn) * p.ldb + k0 + btkg * 8, bf32, vb);
#pragma unroll
      for (int j = 0; j < 8; j++) {
        u16 h = f2b(vb[j]);
        bh8[j] = (short)h;
        bl8[j] = (short)f2b(vb[j] - b2f(h));
      }
      *(short8*)(&Bh2[btkg][btn][0]) = bh8;
      *(short8*)(&Bl2[btkg][btn][0]) = bl8;
    } else {
#pragma unroll
      for (int j = 0; j < 8; j++) {
        float v = ldIn(p.Bm, boff + (long long)(k0 + bkg * 8 + j) * p.ldb + n0 + bn, bf32);
        u16 h = f2b(v);
        bh8[j] = (short)h;
        bl8[j] = (short)f2b(v - b2f(h));
      }
      *(short8*)(&Bh2[bkg][bn][0]) = bh8;
      *(short8*)(&Bl2[bkg][bn][0]) = bl8;
    }
    __syncthreads();
    short8 ah0 = *(const short8*)(&Ah[wr * 32 + l16][quad * 8]);
    short8 ah1 = *(const short8*)(&Ah[wr * 32 + 16 + l16][quad * 8]);
    short8 al0 = *(const short8*)(&Al[wr * 32 + l16][quad * 8]);
    short8 al1 = *(const short8*)(&Al[wr * 32 + 16 + l16][quad * 8]);
    short8 bh0 = *(const short8*)(&Bh2[quad][wc * 32 + l16][0]);
    short8 bh1 = *(const short8*)(&Bh2[quad][wc * 32 + 16 + l16][0]);
    short8 bl0 = *(const short8*)(&Bl2[quad][wc * 32 + l16][0]);
    short8 bl1 = *(const short8*)(&Bl2[quad][wc * 32 + 16 + l16][0]);
    acc[0][0] = __builtin_amdgcn_mfma_f32_16x16x32_bf16(al0, bh0, acc[0][0], 0, 0, 0);
    acc[0][1] = __builtin_amdgcn_mfma_f32_16x16x32_bf16(al0, bh1, acc[0][1], 0, 0, 0);
    acc[1][0] = __builtin_amdgcn_mfma_f32_16x16x32_bf16(al1, bh0, acc[1][0], 0, 0, 0);
    acc[1][1] = __builtin_amdgcn_mfma_f32_16x16x32_bf16(al1, bh1, acc[1][1], 0, 0, 0);
    acc[0][0] = __builtin_amdgcn_mfma_f32_16x16x32_bf16(ah0, bl0, acc[0][0], 0, 0, 0);
    acc[0][1] = __builtin_amdgcn_mfma_f32_16x16x32_bf16(ah0, bl1, acc[0][1], 0, 0, 0);
    acc[1][0] = __builtin_amdgcn_mfma_f32_16x16x32_bf16(ah1, bl0, acc[1][0], 0, 0, 0);
    acc[1][1] = __builtin_amdgcn_mfma_f32_16x16x32_bf16(ah1, bl1, acc[1][1], 0, 0, 0);
    acc[0][0] = __builtin_amdgcn_mfma_f32_16x16x32_bf16(ah0, bh0, acc[0][0], 0, 0, 0);
    acc[0][1] = __builtin_amdgcn_mfma_f32_16x16x32_bf16(ah0, bh1, acc[0][1], 0, 0, 0);
    acc[1][0] = __builtin_amdgcn_mfma_f32_16x16x32_bf16(ah1, bh0, acc[1][0], 0, 0, 0);
    acc[1][1] = __builtin_amdgcn_mfma_f32_16x16x32_bf16(ah1, bh1, acc[1][1], 0, 0, 0);
    __syncthreads();
  }

#pragma unroll
  for (int sm = 0; sm < 2; sm++) {
#pragma unroll
    for (int r = 0; r < 4; r++) {
      int row = m0 + wr * 32 + sm * 16 + quad * 4 + r;
#pragma unroll
      for (int sn = 0; sn < 2; sn++) {
        int col = n0 + wc * 32 + sn * 16 + l16;
        float v = acc[sm][sn][r];
        if (p.bias) v += ldIn(p.bias, col, f32in);
        p.C[coff + (long long)row * p.ldc + col] = v;
      }
    }
  }
}

// ---------------------------- split repack: W [1024][1024] -> hi/lo frag ----
// frag layout: elem ((kb*4+kg)*1024 + n)*8 + j == gid*8 + j
__global__ __launch_bounds__(256) void splitW_k(const void* s0, const void* s1, const void* s2,
                                                u16* h0, u16* l0, u16* h1, u16* l1,
                                                u16* h2, u16* l2, const int* dflag) {
  const int f32 = dflag[0];
  const void* src = blockIdx.z == 0 ? s0 : (blockIdx.z == 1 ? s1 : s2);
  u16* hi = blockIdx.z == 0 ? h0 : (blockIdx.z == 1 ? h1 : h2);
  u16* lo = blockIdx.z == 0 ? l0 : (blockIdx.z == 1 ? l1 : l2);
  const int gid = blockIdx.x * 256 + threadIdx.x;     // < 131072
  const int n = gid & 1023;
  const int kb8 = gid >> 10;                          // k = kb8*8 + j
  const long long s0i = (long long)kb8 * 8 * 1024 + n;
  short8 h8, l8;
#pragma unroll
  for (int j = 0; j < 8; j++) {
    float v = ldIn(src, s0i + (long long)j * 1024, f32);
    u16 hh = f2b(v);
    h8[j] = (short)hh;
    l8[j] = (short)f2b(v - b2f(hh));
  }
  *(short8*)(hi + (long long)gid * 8) = h8;
  *(short8*)(lo + (long long)gid * 8) = l8;
}

// split repack: A [2048][1024] row-major -> hi/lo row-major bf16
__global__ __launch_bounds__(256) void splitA_k(const void* src, u16* hi, u16* lo,
                                                int forceF32, const int* dflag) {
  const int f32 = forceF32 ? 1 : dflag[0];
  const long long gid = (long long)blockIdx.x * 256 + threadIdx.x;   // < 262144
  float v[8];
  ld8f(src, gid * 8, f32, v);
  short8 h8, l8;
#pragma unroll
  for (int j = 0; j < 8; j++) {
    u16 hh = f2b(v[j]);
    h8[j] = (short)hh;
    l8[j] = (short)f2b(v[j] - b2f(hh));
  }
  *(short8*)(hi + gid * 8) = h8;
  *(short8*)(lo + gid * 8) = l8;
}

// ---------------- fast split-bf16 GEMM: C[2048,1024] = A @ B (NB outputs) ----
// 64x64 tile, 256 thr, pre-split inputs, gll16 staging, 2-phase dbuf pipeline,
// single barrier per K-step, x-major XCD-chunked swizzle (B slice L2-resident).
template <int NB>
__global__ __launch_bounds__(256) void gemmS_k(const u16* Ah, const u16* Al,
                                               const u16* Bh0, const u16* Bl0,
                                               const u16* Bh1, const u16* Bl1,
                                               const u16* Bh2, const u16* Bl2,
                                               float* C0, float* C1, float* C2,
                                               const void* bias, const int* dflag) {
  const int lin = blockIdx.y * gridDim.x + blockIdx.x;   // 512 blocks
  const int swz = (lin & 7) * 64 + (lin >> 3);           // XCD chunk (bijective, 512%8==0)
  const int tx = swz >> 5, ty = swz & 31;                // x-major within chunk
  const int m0 = ty * 64, n0 = tx * 64;
  const int f32in = dflag[0];

  __shared__ __align__(16) u16 AhS[2][64][32], AlS[2][64][32];
  __shared__ __align__(16) u16 BhS[NB][2][4][64][8], BlS[NB][2][4][64][8];

  const int tid = threadIdx.x, wave = tid >> 6, lane = tid & 63;
  const int wr = wave >> 1, wc = wave & 1, quad = lane >> 4, l16 = lane & 15;

  const long long aOff = (long long)(m0 + (tid >> 2)) * kD + (tid & 3) * 8;
  const long long bOff = ((long long)(tid >> 6) * kD + n0 + (tid & 63)) * 8;
  const u16* pBh[3] = {Bh0, Bh1, Bh2};
  const u16* pBl[3] = {Bl0, Bl1, Bl2};
  float* pC[3] = {C0, C1, C2};

  f32x4 acc[NB][2][2];
  const f32x4 z4 = {0.f, 0.f, 0.f, 0.f};
#pragma unroll
  for (int i = 0; i < NB; i++) {
    acc[i][0][0] = z4; acc[i][0][1] = z4; acc[i][1][0] = z4; acc[i][1][1] = z4;
  }

  auto stage = [&](int buf, int kb) {
    gll16(Ah + aOff + kb * 32, (char*)&AhS[buf][0][0] + (wave << 10));
    gll16(Al + aOff + kb * 32, (char*)&AlS[buf][0][0] + (wave << 10));
    const long long bo = bOff + (long long)kb * (kD * 32);
#pragma unroll
    for (int i = 0; i < NB; i++) {
      gll16(pBh[i] + bo, (char*)&BhS[i][buf][0][0][0] + (wave << 10));
      gll16(pBl[i] + bo, (char*)&BlS[i][buf][0][0][0] + (wave << 10));
    }
  };

  stage(0, 0);
  __syncthreads();
  for (int kb = 0; kb < kD / 32; kb++) {
    const int cur = kb & 1;
    if (kb + 1 < kD / 32) stage(cur ^ 1, kb + 1);
    short8 ah0 = *(const short8*)&AhS[cur][wr * 32 + l16][quad * 8];
    short8 ah1 = *(const short8*)&AhS[cur][wr * 32 + 16 + l16][quad * 8];
    short8 al0 = *(const short8*)&AlS[cur][wr * 32 + l16][quad * 8];
    short8 al1 = *(const short8*)&AlS[cur][wr * 32 + 16 + l16][quad * 8];
#pragma unroll
    for (int i = 0; i < NB; i++) {
      short8 bh0 = *(const short8*)&BhS[i][cur][quad][wc * 32 + l16][0];
      short8 bh1 = *(const short8*)&BhS[i][cur][quad][wc * 32 + 16 + l16][0];
      short8 bl0 = *(const short8*)&BlS[i][cur][quad][wc * 32 + l16][0];
      short8 bl1 = *(const short8*)&BlS[i][cur][quad][wc * 32 + 16 + l16][0];
      acc[i][0][0] = __builtin_amdgcn_mfma_f32_16x16x32_bf16(al0, bh0, acc[i][0][0], 0, 0, 0);
      acc[i][0][1] = __builtin_amdgcn_mfma_f32_16x16x32_bf16(al0, bh1, acc[i][0][1], 0, 0, 0);
      acc[i][1][0] = __builtin_amdgcn_mfma_f32_16x16x32_bf16(al1, bh0, acc[i][1][0], 0, 0, 0);
      acc[i][1][1] = __builtin_amdgcn_mfma_f32_16x16x32_bf16(al1, bh1, acc[i][1][1], 0, 0, 0);
      acc[i][0][0] = __builtin_amdgcn_mfma_f32_16x16x32_bf16(ah0, bl0, acc[i][0][0], 0, 0, 0);
      acc[i][0][1] = __builtin_amdgcn_mfma_f32_16x16x32_bf16(ah0, bl1, acc[i][0][1], 0, 0, 0);
      acc[i][1][0] = __builtin_amdgcn_mfma_f32_16x16x32_bf16(ah1, bl0, acc[i][1][0], 0, 0, 0);
      acc[i][1][1] = __builtin_amdgcn_mfma_f32_16x16x32_bf16(ah1, bl1, acc[i][1][1], 0, 0, 0);
      acc[i][0][0] = __builtin_amdgcn_mfma_f32_16x16x32_bf16(ah0, bh0, acc[i][0][0], 0, 0, 0);
      acc[i][0][1] = __builtin_amdgcn_mfma_f32_16x16x32_bf16(ah0, bh1, acc[i][0][1], 0, 0, 0);
      acc[i][1][0] = __builtin_amdgcn_mfma_f32_16x16x32_bf16(ah1, bh0, acc[i][1][0], 0, 0, 0);
      acc[i][1][1] = __builtin_amdgcn_mfma_f32_16x16x32_bf16(ah1, bh1, acc[i][1][1], 0, 0, 0);
    }
    __syncthreads();
  }

#pragma unroll
  for (int i = 0; i < NB; i++) {
#pragma unroll
    for (int sm = 0; sm < 2; sm++) {
#pragma unroll
      for (int r = 0; r < 4; r++) {
        int row = m0 + wr * 32 + sm * 16 + quad * 4 + r;
#pragma unroll
        for (int sn = 0; sn < 2; sn++) {
          int col = n0 + wc * 32 + sn * 16 + l16;
          float v = acc[i][sm][sn][r];
          if (bias && i == 0) v += ldIn(bias, col, f32in);
          pC[i][(long long)row * kD + col] = v;
        }
      }
    }
  }
}

// ------------------------------------- MoE weight repack fp32 -> bf16 -------
__global__ __launch_bounds__(256) void cvtW_k(const void* src, u16* dst,
                                              int nSh, int kbSh, const int* dflag) {
  const int f32 = dflag[0];
  const int gid = blockIdx.x * 256 + threadIdx.x;
  const int N = 1 << nSh;
  const int n = gid & (N - 1);
  const int rest = gid >> nSh;
  const int kg = rest & 3;
  const int kb = (rest >> 2) & ((1 << kbSh) - 1);
  const int e = rest >> (2 + kbSh);
  const long long src0 = ((long long)e << (5 + kbSh + nSh)) +
                         (long long)(kb * 32 + kg * 8) * N + n;
  short8 o;
#pragma unroll
  for (int j = 0; j < 8; j++) o[j] = (short)f2b(ldIn(src, src0 + (long long)j * N, f32));
  *(short8*)(dst + (long long)gid * 8) = o;
}

// x2f (fp32) -> bf16, linear layout
__global__ __launch_bounds__(256) void cvtX_k(const float* src, u16* dst) {
  const int gid = blockIdx.x * 256 + threadIdx.x;
  const float* s = src + (long long)gid * 8;
  float4 a = *(const float4*)s, b = *(const float4*)(s + 4);
  short8 o;
  o[0]=(short)f2b(a.x); o[1]=(short)f2b(a.y); o[2]=(short)f2b(a.z); o[3]=(short)f2b(a.w);
  o[4]=(short)f2b(b.x); o[5]=(short)f2b(b.y); o[6]=(short)f2b(b.z); o[7]=(short)f2b(b.w);
  *(short8*)(dst + (long long)gid * 8) = o;
}

// -------------------------------------------- fused MoE W1/W3 + SwiGLU ------
// 64x128 tile, 256 thr, 2-phase dbuf pipeline, one barrier per K-step.
__global__ __launch_bounds__(256) void moe13_k(const u16* Xb, const u16* W1c, const u16* W3c,
                                               const int* counts, const int* offsets,
                                               const int* aidxArr, u16* Hbuf) {
  const int e = blockIdx.z;
  const int Meff = counts[e];
  const int m0 = blockIdx.y * 64;
  if (m0 >= Meff) return;
  const int n0 = blockIdx.x * 128;
  const int csr = offsets[e];

  __shared__ __align__(16) u16 As[2][64][32];
  __shared__ __align__(16) u16 B1s[2][4][128][8];
  __shared__ __align__(16) u16 B3s[2][4][128][8];

  const int tid = threadIdx.x, wave = tid >> 6, lane = tid & 63;
  const int wc = wave, quad = lane >> 4, l16 = lane & 15;

  int grow = m0 + (tid >> 2); if (grow >= Meff) grow = Meff - 1;
  const u16* pA = Xb + (long long)aidxArr[csr + grow] * kD + (tid & 3) * 8;

  const long long ebase = (long long)e * kD * kHID;
  const int g0 = tid, g1 = 256 + tid;
  const long long b0o = ebase + ((long long)(g0 >> 7) * kHID + n0 + (g0 & 127)) * 8;
  const long long b1o = ebase + ((long long)(g1 >> 7) * kHID + n0 + (g1 & 127)) * 8;

  f32x4 acc1[4][2], acc3[4][2];
  const f32x4 z4 = {0.f, 0.f, 0.f, 0.f};
#pragma unroll
  for (int i = 0; i < 4; i++) { acc1[i][0]=z4; acc1[i][1]=z4; acc3[i][0]=z4; acc3[i][1]=z4; }

  auto stage = [&](int buf, int kb) {
    gll16(pA + kb * 32, (char*)&As[buf][0][0] + (wave << 10));
    const long long ko = (long long)kb * (4 * kHID * 8);
    gll16(W1c + b0o + ko, (char*)&B1s[buf][0][0][0] + (wave << 10));
    gll16(W1c + b1o + ko, (char*)&B1s[buf][0][0][0] + 4096 + (wave << 10));
    gll16(W3c + b0o + ko, (char*)&B3s[buf][0][0][0] + (wave << 10));
    gll16(W3c + b1o + ko, (char*)&B3s[buf][0][0][0] + 4096 + (wave << 10));
  };

  stage(0, 0);
  __syncthreads();
  for (int kb = 0; kb < kD / 32; kb++) {
    const int cur = kb & 1;
    if (kb + 1 < kD / 32) stage(cur ^ 1, kb + 1);
    short8 af[4];
#pragma unroll
    for (int sm = 0; sm < 4; sm++)
      af[sm] = *(const short8*)&As[cur][sm * 16 + l16][quad * 8];
    short8 b1f[2], b3f[2];
#pragma unroll
    for (int sn = 0; sn < 2; sn++) {
      b1f[sn] = *(const short8*)&B1s[cur][quad][wc * 32 + sn * 16 + l16][0];
      b3f[sn] = *(const short8*)&B3s[cur][quad][wc * 32 + sn * 16 + l16][0];
    }
#pragma unroll
    for (int sm = 0; sm < 4; sm++) {
#pragma unroll
      for (int sn = 0; sn < 2; sn++) {
        acc1[sm][sn] = __builtin_amdgcn_mfma_f32_16x16x32_bf16(af[sm], b1f[sn], acc1[sm][sn], 0, 0, 0);
        acc3[sm][sn] = __builtin_amdgcn_mfma_f32_16x16x32_bf16(af[sm], b3f[sn], acc3[sm][sn], 0, 0, 0);
      }
    }
    __syncthreads();
  }

#pragma unroll
  for (int sm = 0; sm < 4; sm++) {
#pragma unroll
    for (int r = 0; r < 4; r++) {
      int row = m0 + sm * 16 + quad * 4 + r;
      if (row >= Meff) continue;
#pragma unroll
      for (int sn = 0; sn < 2; sn++) {
        int col = n0 + wc * 32 + sn * 16 + l16;
        float g1 = acc1[sm][sn][r], g3 = acc3[sm][sn][r];
        float h = (g1 / (1.f + __expf(-g1))) * g3;
        Hbuf[(long long)(csr + row) * kHID + col] = f2b(h);
      }
    }
  }
}

// ------------------------------------------------ MoE W2 + scatter ---------
// 64x128 tile, 256 thr, 2-phase dbuf pipeline.
__global__ __launch_bounds__(256) void w2_k(const u16* Hbuf, const u16* W2c,
                                            const int* counts, const int* offsets,
                                            const int* aidxArr, const int* slotArr,
                                            const float* wgtArr, float* contrib) {
  const int e = blockIdx.z;
  const int Meff = counts[e];
  const int m0 = blockIdx.y * 64;
  if (m0 >= Meff) return;
  const int n0 = blockIdx.x * 128;
  const int csr = offsets[e];

  __shared__ __align__(16) u16 As[2][64][32];
  __shared__ __align__(16) u16 Bs[2][4][128][8];

  const int tid = threadIdx.x, wave = tid >> 6, lane = tid & 63;
  const int wc = wave, quad = lane >> 4, l16 = lane & 15;

  int grow = m0 + (tid >> 2); if (grow >= Meff) grow = Meff - 1;
  const u16* pA = Hbuf + (long long)(csr + grow) * kHID + (tid & 3) * 8;

  const long long ebase = (long long)e * kHID * kD;
  const int g0 = tid, g1 = 256 + tid;
  const long long b0o = ebase + ((long long)(g0 >> 7) * kD + n0 + (g0 & 127)) * 8;
  const long long b1o = ebase + ((long long)(g1 >> 7) * kD + n0 + (g1 & 127)) * 8;

  f32x4 acc[4][2];
  const f32x4 z4 = {0.f, 0.f, 0.f, 0.f};
#pragma unroll
  for (int i = 0; i < 4; i++) { acc[i][0] = z4; acc[i][1] = z4; }

  auto stage = [&](int buf, int kb) {
    gll16(pA + kb * 32, (char*)&As[buf][0][0] + (wave << 10));
    const long long ko = (long long)kb * (4 * kD * 8);
    gll16(W2c + b0o + ko, (char*)&Bs[buf][0][0][0] + (wave << 10));
    gll16(W2c + b1o + ko, (char*)&Bs[buf][0][0][0] + 4096 + (wave << 10));
  };

  stage(0, 0);
  __syncthreads();
  for (int kb = 0; kb < kHID / 32; kb++) {
    const int cur = kb & 1;
    if (kb + 1 < kHID / 32) stage(cur ^ 1, kb + 1);
    short8 af[4];
#pragma unroll
    for (int sm = 0; sm < 4; sm++)
      af[sm] = *(const short8*)&As[cur][sm * 16 + l16][quad * 8];
    short8 bf[2];
#pragma unroll
    for (int sn = 0; sn < 2; sn++)
      bf[sn] = *(const short8*)&Bs[cur][quad][wc * 32 + sn * 16 + l16][0];
#pragma unroll
    for (int sm = 0; sm < 4; sm++) {
#pragma unroll
      for (int sn = 0; sn < 2; sn++)
        acc[sm][sn] = __builtin_amdgcn_mfma_f32_16x16x32_bf16(af[sm], bf[sn], acc[sm][sn], 0, 0, 0);
    }
    __syncthreads();
  }

#pragma unroll
  for (int sm = 0; sm < 4; sm++) {
#pragma unroll
    for (int r = 0; r < 4; r++) {
      int row = m0 + sm * 16 + quad * 4 + r;
      if (row >= Meff) continue;
      int a = csr + row;
      int t = aidxArr[a]; int s = slotArr[a]; float w = wgtArr[a];
#pragma unroll
      for (int sn = 0; sn < 2; sn++) {
        int col = n0 + wc * 32 + sn * 16 + l16;
        contrib[((long long)s * kTok + t) * kD + col] = acc[sm][sn][r] * w;
      }
    }
  }
}

// ------------------------------------------------------------ small ops -----
__global__ void maskprep_k(const void* srcm, const void* tgtm, const void* midm,
                           float* srcf, float* padf, float* keepf, float* denom) {
  __shared__ int okInt, okFloat, okBf16;
  int tid = threadIdx.x;
  if (tid == 0) { okInt = 1; okFloat = 1; okBf16 = 1; }
  __syncthreads();
  const unsigned int* wi = (const unsigned int*)tgtm;
  const float* wf = (const float*)tgtm;
  int badI = 0, badF = 0, badB = 0;
  for (int i = tid; i < 512; i += 256) {
    unsigned int w = wi[i];
    if (w > 1u) badI = 1;
    float f = wf[i];
    if (!(f == 0.f || f == 1.f)) badF = 1;
    unsigned int lo = w & 0xffffu, hi = w >> 16;
    if (!((lo == 0 || lo == 0x3f80u) && (hi == 0 || hi == 0x3f80u))) badB = 1;
  }
  if (badI) atomicExch(&okInt, 0);
  if (badF) atomicExch(&okFloat, 0);
  if (badB) atomicExch(&okBf16, 0);
  __syncthreads();
  int mode = okInt ? 0 : (okFloat ? 2 : (okBf16 ? 3 : 1));
  for (int i = tid; i < kTok; i += 256) {
    bool sv, pv, mv;
    if (mode == 0) {
      sv = ((const int*)srcm)[i] != 0; pv = ((const int*)tgtm)[i] != 0; mv = ((const int*)midm)[i] != 0;
    } else if (mode == 2) {
      sv = ((const float*)srcm)[i] != 0.f; pv = ((const float*)tgtm)[i] != 0.f; mv = ((const float*)midm)[i] != 0.f;
    } else if (mode == 3) {
      sv = ((const u16*)srcm)[i] != 0; pv = ((const u16*)tgtm)[i] != 0; mv = ((const u16*)midm)[i] != 0;
    } else {
      sv = ((const unsigned char*)srcm)[i] != 0; pv = ((const unsigned char*)tgtm)[i] != 0; mv = ((const unsigned char*)midm)[i] != 0;
    }
    srcf[i] = sv ? 1.f : 0.f;
    padf[i] = pv ? 1.f : 0.f;
    keepf[i] = (pv || mv) ? 0.f : 1.f;
  }
  __syncthreads();
  if (tid < 2) {
    float s = 0;
    for (int j = 0; j < kS; j++) s += keepf[tid * kS + j];
    denom[tid] = fmaxf(s, 1.f);
  }
}

__global__ __launch_bounds__(256) void softmax_k(float* sc, const float* maskf, int zbase) {
  int row = blockIdx.x;
  int gz = zbase + (row >> 10);
  int b = gz >> 4;
  const long long base = (long long)row * kS;
  int tid = threadIdx.x;
  float s[4];
#pragma unroll
  for (int i = 0; i < 4; i++) {
    int j = tid + i * 256;
    float v = sc[base + j] * kScale;
    if (maskf[b * kS + j] != 0.f) v = -1e30f;
    s[i] = v;
  }
  float mx = blockReduceMax(fmaxf(fmaxf(s[0], s[1]), fmaxf(s[2], s[3])));
  float sum = 0;
#pragma unroll
  for (int i = 0; i < 4; i++) { s[i] = __expf(s[i] - mx); sum += s[i]; }
  sum = blockReduceSum(sum);
  float inv = 1.f / sum;
#pragma unroll
  for (int i = 0; i < 4; i++) {
    int j = tid + i * 256;
    sc[base + j] = s[i] * inv;
  }
}

__global__ __launch_bounds__(256) void ln_k(const float* basef, const void* baseb,
                                            const int* dflag, int baseIsIn,
                                            const float* add1, const float* add2,
                                            const void* g, const void* bb,
                                            float* outf, void* outFinal) {
  const int f32in = dflag[0];
  const int baseF32 = baseIsIn && f32in;
  long long base = (long long)blockIdx.x * kD;
  int tid = threadIdx.x;
  float v[4]; float s = 0;
#pragma unroll
  for (int i = 0; i < 4; i++) {
    int d = tid + i * 256;
    float x = basef ? basef[base + d] : ldIn(baseb, base + d, baseF32);
    if (add1) x += add1[base + d];
    if (add2) x += add2[base + d];
    v[i] = x; s += x;
  }
  float mean = blockReduceSum(s) * (1.f / kD);
  float q = 0;
#pragma unroll
  for (int i = 0; i < 4; i++) { float d0 = v[i] - mean; q += d0 * d0; }
  float var = blockReduceSum(q) * (1.f / kD);
  float rstd = rsqrtf(var + 1e-5f);
#pragma unroll
  for (int i = 0; i < 4; i++) {
    int d = tid + i * 256;
    float y = (v[i] - mean) * rstd * ldIn(g, d, f32in) + ldIn(bb, d, f32in);
    if (outf) outf[base + d] = y;
    if (outFinal) stOut(outFinal, base + d, y, f32in);
  }
}

__global__ __launch_bounds__(256) void router_k(const float* xf, const void* gw, void* outBase,
                                                int* sel, float* wsel, int* counts,
                                                const int* dflag) {
  const int f32in = dflag[0];
  int wv = threadIdx.x >> 6, lane = threadIdx.x & 63;
  int t = blockIdx.x * 4 + wv;
  const float* xr = xf + (long long)t * kD;
  float acc[8];
#pragma unroll
  for (int e = 0; e < 8; e++) acc[e] = 0.f;
  for (int d = lane; d < kD; d += 64) {
    float xv = xr[d];
    float gv[8];
    ld8f(gw, (long long)d * 8, f32in, gv);
#pragma unroll
    for (int e = 0; e < 8; e++) acc[e] += xv * gv[e];
  }
#pragma unroll
  for (int o = 32; o; o >>= 1) {
#pragma unroll
    for (int e = 0; e < 8; e++) acc[e] += __shfl_down(acc[e], o, 64);
  }
  if (lane == 0) {
    float mx = acc[0];
    for (int e = 1; e < 8; e++) mx = fmaxf(mx, acc[e]);
    float p[8], sum = 0;
    for (int e = 0; e < 8; e++) { p[e] = expf(acc[e] - mx); sum += p[e]; }
    float inv = 1.f / sum;
    for (int e = 0; e < 8; e++) {
      p[e] *= inv;
      stOut(outBase, kOutProbs + (long long)t * 8 + e, p[e], f32in);
    }
    int e0 = 0; for (int e = 1; e < 8; e++) if (p[e] > p[e0]) e0 = e;
    int e1 = -1; for (int e = 0; e < 8; e++) { if (e == e0) continue; if (e1 < 0 || p[e] > p[e1]) e1 = e; }
    float s2 = p[e0] + p[e1];
    sel[t * 2] = e0; sel[t * 2 + 1] = e1;
    wsel[t * 2] = p[e0] / s2; wsel[t * 2 + 1] = p[e1] / s2;
    atomicAdd(&counts[e0], 1); atomicAdd(&counts[e1], 1);
  }
}

__global__ void offsets_k(const int* counts, int* offsets) {
  if (threadIdx.x == 0) {
    int s = 0;
    for (int e = 0; e < kE; e++) { offsets[e] = s; s += counts[e]; }
    offsets[kE] = s;
  }
}

__global__ void place_k(const int* sel, const float* wsel, const int* offsets, int* fill,
                        int* aidxArr, int* slotArr, float* wgtArr) {
  int t = blockIdx.x * 256 + threadIdx.x;
  if (t >= kTok) return;
  for (int s = 0; s < 2; s++) {
    int e = sel[t * 2 + s];
    int pos = offsets[e] + atomicAdd(&fill[e], 1);
    aidxArr[pos] = t; slotArr[pos] = s; wgtArr[pos] = wsel[t * 2 + s];
  }
}

__global__ void meanacc_k(const int* counts, const int* offsets, const int* aidxArr,
                          const int* slotArr, const float* keepf, const float* contrib,
                          float* meanAcc) {
  int e = blockIdx.x, dc = blockIdx.y, ch = blockIdx.z;
  int d = dc * 128 + threadIdx.x;
  int cnt = counts[e], off = offsets[e];
  int per = (cnt + 15) / 16;
  int i0 = ch * per, i1 = i0 + per; if (i1 > cnt) i1 = cnt;
  float a0 = 0, a1 = 0;
  for (int i = i0; i < i1; i++) {
    int a = off + i; int t = aidxArr[a];
    if (keepf[t] != 0.f) {
      float v = contrib[((long long)slotArr[a] * kTok + t) * kD + d];
      if (t < kS) a0 += v; else a1 += v;
    }
  }
  if (a0 != 0.f) atomicAdd(&meanAcc[(e * 2 + 0) * kD + d], a0);
  if (a1 != 0.f) atomicAdd(&meanAcc[(e * 2 + 1) * kD + d], a1);
}

__global__ __launch_bounds__(256) void dots_k(const float* meanAcc, const void* cls_w,
                                              const float* denom, float* dots,
                                              const int* dflag) {
  const int f32in = dflag[0];
  int eb = blockIdx.x;
  int b = eb & 1;
  float s = 0;
  for (int d = threadIdx.x; d < kD; d += 256)
    s += meanAcc[(long long)eb * kD + d] * ldIn(cls_w, d, f32in);
  s = blockReduceSum(s);
  if (threadIdx.x == 0) dots[eb] = s / denom[b];
}

__global__ void final_logits_k(const float* dots, const void* cls_b, void* outBase,
                               const int* dflag) {
  const int f32in = dflag[0];
  int i = threadIdx.x;
  if (i < kE * kB) {
    int e = i >> 1, b = i & 1;
    float s = ldIn(cls_b, 0, f32in);
    for (int e2 = 0; e2 <= e; e2++) s += dots[e2 * 2 + b];
    stOut(outBase, kOutLogits + e * kB + b, s, f32in);
  }
}

// ------------------------------------------------------------------ host ----
extern "C" void kernel_launch(void* const* d_in, const int* in_sizes, int n_in,
                              void* d_out, int out_size, void* d_ws, size_t ws_size,
                              hipStream_t stream) {
  (void)in_sizes; (void)n_in; (void)out_size; (void)ws_size;

  const void* x_in  = d_in[0];
  const void* enc   = d_in[1];
  const void* srcm = d_in[2];
  const void* tgtm = d_in[3];
  const void* midm = d_in[4];
  const void* ln1g = d_in[5];  const void* ln1b = d_in[6];
  const void* ln2g = d_in[7];  const void* ln2b = d_in[8];
  const void* ln3g = d_in[9];  const void* ln3b = d_in[10];
  const void* sa_wq = d_in[11]; const void* sa_wk = d_in[12];
  const void* sa_wv = d_in[13]; const void* sa_wo = d_in[14];
  const void* sa_bo = d_in[15];
  const void* ca_wq = d_in[16]; const void* ca_wk = d_in[17];
  const void* ca_wv = d_in[18]; const void* ca_wo = d_in[19];
  const void* ca_bo = d_in[20];
  const void* gate_w = d_in[21];
  const void* cls_w  = d_in[22]; const void* cls_b = d_in[23];
  const void* moe_w1 = d_in[24];
  const void* moe_w2 = d_in[25];
  const void* moe_w3 = d_in[26];

  char* wp = (char*)d_ws;
  size_t off = 0;
  auto alloc = [&](size_t bytes) -> void* {
    void* p = wp + off; off = (off + bytes + 255) & ~(size_t)255; return p;
  };
  float* scFP = (float*)alloc((size_t)16 * kS * kS * 4);          // 64 MiB
  u16*   Hbuf = (u16*)scFP;                                        // [0,16) MiB (MoE phase)
  float* contrib = (float*)((char*)scFP + (size_t)2 * kTok * kHID * 2); // [16,32) MiB
  float* qf    = (float*)alloc((size_t)kTok * kD * 4);
  float* kf    = (float*)alloc((size_t)kTok * kD * 4);
  float* vf    = (float*)alloc((size_t)kTok * kD * 4);
  float* attnof= (float*)alloc((size_t)kTok * kD * 4);
  float* obuf  = (float*)alloc((size_t)kTok * kD * 4);
  float* x1f   = (float*)alloc((size_t)kTok * kD * 4);
  float* x2f   = (float*)alloc((size_t)kTok * kD * 4);
  float* meanAcc = (float*)alloc((size_t)kE * kB * kD * 4);
  float* srcf = (float*)alloc(kTok * 4);
  float* padf = (float*)alloc(kTok * 4);
  float* keepf = (float*)alloc(kTok * 4);
  float* denom = (float*)alloc(2 * 4);
  int* counts = (int*)alloc(256); int* fill = counts + 8;
  int* offsets = (int*)alloc(256);
  int* sel = (int*)alloc(kTok * 2 * 4);
  float* wsel = (float*)alloc(kTok * 2 * 4);
  int* aidxArr = (int*)alloc(2 * kTok * 4);
  int* slotArr = (int*)alloc(2 * kTok * 4);
  float* wgtArr = (float*)alloc(2 * kTok * 4);
  float* dots = (float*)alloc(256);
  int* dflag = (int*)alloc(256);

  // Split scratch (all in dead-at-the-time regions):
  //   WH0/WL0/WH1/WL1: x2f (8 MiB)  — dead until ln2 writes it
  //   WH2/WL2:         x1f[0:4MiB]  — dead during self-attn only (NB3 only there)
  //   AH/AL:           scFP[0:8MiB] — used before QK^T writes scores / after PV
  u16* WH0 = (u16*)x2f;
  u16* WL0 = WH0 + (1 << 20);
  u16* WH1 = WL0 + (1 << 20);
  u16* WL1 = WH1 + (1 << 20);
  u16* WH2 = (u16*)x1f;
  u16* WL2 = WH2 + (1 << 20);
  u16* AH  = (u16*)scFP;
  u16* AL  = AH + (2 << 20);

  // MoE repack buffers (dead regions during MoE):
  u16* W1c = (u16*)qf;                                     // qf..attnof 32 MiB
  u16* W2c = (u16*)qf;
  u16* W3c = (u16*)((char*)scFP + ((size_t)32 << 20));
  u16* Xb  = (u16*)obuf;

  auto g3 = [&](const void* A, const void* Bmat, float* C, int M, int N, int K,
                int lda, int ldb, int ldc, int bT, int aF, int bF,
                long long a0, long long a1, long long b0, long long b1,
                long long c0, long long c1, int zdiv, int zA, int zB, int zC,
                int nz, const void* bias) {
    G3P p;
    p.A = A; p.Bm = Bmat; p.C = C;
    p.a0 = a0; p.a1 = a1; p.b0 = b0; p.b1 = b1; p.c0 = c0; p.c1 = c1;
    p.zdiv = zdiv; p.zA = zA; p.zB = zB; p.zC = zC;
    p.lda = lda; p.ldb = ldb; p.ldc = ldc; p.M = M; p.N = N; p.K = K;
    p.bT = bT; p.aF = aF; p.bF = bF; p.dflag = dflag; p.bias = bias;
    dim3 grid(N / 64, M / 64, nz);
    gemm3_k<<<grid, dim3(256), 0, stream>>>(p);
  };

  hipMemsetAsync(counts, 0, 64, stream);
  hipMemsetAsync(meanAcc, 0, (size_t)kE * kB * kD * 4, stream);
  detect_k<<<1, 256, 0, stream>>>(x_in, dflag);
  maskprep_k<<<1, 256, 0, stream>>>(srcm, tgtm, midm, srcf, padf, keepf, denom);

  const long long SD = (long long)kS * kD;
  const long long SS = (long long)kS * kS;
  const dim3 gGrid(16, 32);

  auto scorePass = [&](const float* maskf) {
    for (int c = 0; c < 2; c++) {
      int zb = c * 16;
      g3(qf, kf, scFP, kS, kS, kDH, kD, kD, kS, 1, 2, 2,
         SD, 64, SD, 64, 0, SS, 16, zb, zb, 0, 16, nullptr);
      softmax_k<<<16 * kS, 256, 0, stream>>>(scFP, maskf, zb);
      g3(scFP, vf, attnof, kS, kDH, kS, kS, kD, kD, 0, 2, 2,
         0, SS, SD, 64, SD, 64, 16, 0, zb, zb, 16, nullptr);
    }
  };

  // ---- self attention ----
  splitA_k<<<1024, 256, 0, stream>>>(x_in, AH, AL, 0, dflag);
  splitW_k<<<dim3(512, 1, 3), 256, 0, stream>>>(sa_wq, sa_wk, sa_wv,
      WH0, WL0, WH1, WL1, WH2, WL2, dflag);
  gemmS_k<3><<<gGrid, 256, 0, stream>>>(AH, AL, WH0, WL0, WH1, WL1, WH2, WL2,
      qf, kf, vf, nullptr, dflag);
  scorePass(padf);
  splitA_k<<<1024, 256, 0, stream>>>(attnof, AH, AL, 1, dflag);
  splitW_k<<<dim3(512, 1, 1), 256, 0, stream>>>(sa_wo, nullptr, nullptr,
      WH0, WL0, nullptr, nullptr, nullptr, nullptr, dflag);
  gemmS_k<1><<<gGrid, 256, 0, stream>>>(AH, AL, WH0, WL0, WH0, WL0, WH0, WL0,
      obuf, obuf, obuf, sa_bo, dflag);
  ln_k<<<kTok, 256, 0, stream>>>(nullptr, x_in, dflag, 1, obuf, nullptr, ln1g, ln1b, x1f, nullptr);

  // ---- cross attention ----
  splitA_k<<<1024, 256, 0, stream>>>(x1f, AH, AL, 1, dflag);
  splitW_k<<<dim3(512, 1, 1), 256, 0, stream>>>(ca_wq, nullptr, nullptr,
      WH0, WL0, nullptr, nullptr, nullptr, nullptr, dflag);
  gemmS_k<1><<<gGrid, 256, 0, stream>>>(AH, AL, WH0, WL0, WH0, WL0, WH0, WL0,
      qf, qf, qf, nullptr, dflag);
  splitA_k<<<1024, 256, 0, stream>>>(enc, AH, AL, 0, dflag);
  splitW_k<<<dim3(512, 1, 2), 256, 0, stream>>>(ca_wk, ca_wv, nullptr,
      WH0, WL0, WH1, WL1, nullptr, nullptr, dflag);
  gemmS_k<2><<<gGrid, 256, 0, stream>>>(AH, AL, WH0, WL0, WH1, WL1, WH0, WL0,
      kf, vf, vf, nullptr, dflag);
  scorePass(srcf);
  splitA_k<<<1024, 256, 0, stream>>>(attnof, AH, AL, 1, dflag);
  splitW_k<<<dim3(512, 1, 1), 256, 0, stream>>>(ca_wo, nullptr, nullptr,
      WH0, WL0, nullptr, nullptr, nullptr, nullptr, dflag);
  gemmS_k<1><<<gGrid, 256, 0, stream>>>(AH, AL, WH0, WL0, WH0, WL0, WH0, WL0,
      obuf, obuf, obuf, ca_bo, dflag);
  ln_k<<<kTok, 256, 0, stream>>>(x1f, nullptr, dflag, 0, obuf, nullptr, ln2g, ln2b, x2f, nullptr);

  // ---- MoE ----
  router_k<<<kTok / 4, 256, 0, stream>>>(x2f, gate_w, d_out, sel, wsel, counts, dflag);
  offsets_k<<<1, 64, 0, stream>>>(counts, offsets);
  place_k<<<kTok / 256, 256, 0, stream>>>(sel, wsel, offsets, fill, aidxArr, slotArr, wgtArr);

  cvtX_k<<<kTok * kD / (8 * 256), 256, 0, stream>>>(x2f, Xb);
  const int wGrid = (kE * kD * kHID / 8) / 256;   // 8192
  cvtW_k<<<wGrid, 256, 0, stream>>>(moe_w1, W1c, 11, 5, dflag);  // K=1024,N=2048
  cvtW_k<<<wGrid, 256, 0, stream>>>(moe_w3, W3c, 11, 5, dflag);

  moe13_k<<<dim3(kHID / 128, kTok / 64, kE), 256, 0, stream>>>(
      Xb, W1c, W3c, counts, offsets, aidxArr, Hbuf);

  cvtW_k<<<wGrid, 256, 0, stream>>>(moe_w2, W2c, 10, 6, dflag);  // K=2048,N=1024

  w2_k<<<dim3(kD / 128, kTok / 64, kE), 256, 0, stream>>>(
      Hbuf, W2c, counts, offsets, aidxArr, slotArr, wgtArr, contrib);

  meanacc_k<<<dim3(kE, kD / 128, 16), 128, 0, stream>>>(counts, offsets, aidxArr, slotArr, keepf, contrib, meanAcc);
  dots_k<<<kE * kB, 256, 0, stream>>>(meanAcc, cls_w, denom, dots, dflag);
  final_logits_k<<<1, 64, 0, stream>>>(dots, cls_b, d_out, dflag);
  ln_k<<<kTok, 256, 0, stream>>>(x2f, nullptr, dflag, 0, contrib, contrib + (size_t)kTok * kD, ln3g, ln3b, nullptr, d_out);
}

// Round 5
// 931.437 us; speedup vs baseline: 1.4244x; 1.2146x over previous
//
#include <hip/hip_runtime.h>
#include <hip/hip_bf16.h>
#include <math.h>

constexpr int kB   = 2;
constexpr int kS   = 1024;
constexpr int kD   = 1024;
constexpr int kH   = 16;
constexpr int kDH  = 64;
constexpr int kHID = 2048;
constexpr int kE   = 8;
constexpr int kTok = kB * kS;         // 2048
constexpr float kScale = 0.125f;
constexpr long long kOutLogits = (long long)kTok * kD;
constexpr long long kOutProbs  = kOutLogits + kE * kB;

using u16 = unsigned short;
typedef __attribute__((ext_vector_type(8))) short short8;
typedef __attribute__((ext_vector_type(4))) float f32x4;

__device__ __forceinline__ float b2f(u16 u) {
  union { unsigned int i; float f; } c; c.i = ((unsigned int)u) << 16; return c.f;
}
__device__ __forceinline__ u16 f2b(float f) {
  __hip_bfloat16 h = __float2bfloat16(f);
  u16 u; __builtin_memcpy(&u, &h, 2); return u;
}
__device__ __forceinline__ float ldIn(const void* p, long long i, int f32) {
  return f32 ? ((const float*)p)[i] : b2f(((const u16*)p)[i]);
}
__device__ __forceinline__ void ld8f(const void* p, long long i, int f32, float v[8]) {
  if (f32) {
    const float* fp = (const float*)p + i;
    float4 a = *(const float4*)fp, b = *(const float4*)(fp + 4);
    v[0]=a.x; v[1]=a.y; v[2]=a.z; v[3]=a.w; v[4]=b.x; v[5]=b.y; v[6]=b.z; v[7]=b.w;
  } else {
    short8 s = *(const short8*)((const u16*)p + i);
#pragma unroll
    for (int j = 0; j < 8; j++) v[j] = b2f((u16)s[j]);
  }
}
__device__ __forceinline__ void stOut(void* base, long long i, float v, int f32) {
  if (f32) ((float*)base)[i] = v; else ((u16*)base)[i] = f2b(v);
}

// async global->LDS, 16B per lane. LDS dest is wave-uniform base + lane*16.
__device__ __forceinline__ void gll16(const void* g, void* l) {
  __builtin_amdgcn_global_load_lds(
      (__attribute__((address_space(1))) unsigned int*)(unsigned long long)g,
      (__attribute__((address_space(3))) unsigned int*)l, 16, 0, 0);
}

__device__ __forceinline__ float blockReduceSum(float v) {
  __shared__ float sh[4];
  int lane = threadIdx.x & 63, wv = threadIdx.x >> 6;
#pragma unroll
  for (int o = 32; o; o >>= 1) v += __shfl_down(v, o, 64);
  __syncthreads();
  if (lane == 0) sh[wv] = v;
  __syncthreads();
  return sh[0] + sh[1] + sh[2] + sh[3];
}
__device__ __forceinline__ float blockReduceMax(float v) {
  __shared__ float sh[4];
  int lane = threadIdx.x & 63, wv = threadIdx.x >> 6;
#pragma unroll
  for (int o = 32; o; o >>= 1) v = fmaxf(v, __shfl_down(v, o, 64));
  __syncthreads();
  if (lane == 0) sh[wv] = v;
  __syncthreads();
  return fmaxf(fmaxf(sh[0], sh[1]), fmaxf(sh[2], sh[3]));
}

// ------------------------------------------------------------- detect -------
__global__ void detect_k(const void* x, int* dflag) {
  __shared__ int sg, st;
  int tid = threadIdx.x;
  if (tid == 0) { sg = 0; st = 0; }
  __syncthreads();
  const unsigned int* w = (const unsigned int*)x;
  int good = 0, tot = 0;
  for (int i = tid; i < 1024; i += 256) {
    unsigned int lo = w[i] & 0xffffu;
    if (lo) {
      tot++;
      unsigned int e = (lo >> 7) & 0xffu;
      if (e >= 97 && e <= 159) good++;
    }
  }
  atomicAdd(&sg, good); atomicAdd(&st, tot);
  __syncthreads();
  if (tid == 0) dflag[0] = (sg * 10 < st * 9) ? 1 : 0;
}

// --------------------------------------------- fused flash attention --------
// O = softmax(Q K^T * scale, mask) V ; Q,K,V fp32 [2048][1024] head-major cols.
// Grid (Sq/64, 32 bh). 256 thr = 4 waves; wave owns 16 q-rows.
// Split hi/lo bf16, 3-term MFMA for both QK^T and PV (matches gemm3 numerics).
// LDS granule XOR-swizzle (G4) keeps all ds_read_b128 at <=2-way conflict.
// P handoff uses a plain __syncthreads (no inline-asm fence — rule #18 risk).
__global__ __launch_bounds__(256) void fattn_k(const float* Q, const float* K,
                                               const float* V, const float* maskf,
                                               float* O) {
  const int qt = blockIdx.x, bh = blockIdx.y;
  const int b = bh >> 4, hoff = (bh & 15) * 64;
  const int tid = threadIdx.x, wave = tid >> 6, lane = tid & 63;
  const int quad = lane >> 4, l16 = lane & 15, l7 = lane & 7;

  __shared__ __align__(16) u16 Ksh[64][64], Ksl[64][64];   // [kv][d] swizzled
  __shared__ __align__(16) u16 Vth[64][64], Vtl[64][64];   // [d][kv] swizzled
  __shared__ __align__(16) u16 PsArr[4][2][1024];          // per-wave P hi/lo

  const long long tok0 = (long long)b * kS;
  const long long q0 = tok0 + qt * 64;

  // Q A-frags: lane row = wave*16+l16, k = kt*32 + quad*8 + j
  short8 qh[2], qlo[2];
  {
    const float* qp = Q + (q0 + wave * 16 + l16) * kD + hoff + quad * 8;
#pragma unroll
    for (int kt = 0; kt < 2; kt++) {
      float4 x0 = *(const float4*)(qp + kt * 32);
      float4 x1 = *(const float4*)(qp + kt * 32 + 4);
      float vv[8] = {x0.x, x0.y, x0.z, x0.w, x1.x, x1.y, x1.z, x1.w};
#pragma unroll
      for (int j = 0; j < 8; j++) {
        u16 hh = f2b(vv[j]);
        qh[kt][j] = (short)hh;
        qlo[kt][j] = (short)f2b(vv[j] - b2f(hh));
      }
    }
  }

  f32x4 o[4];
  const f32x4 z4 = {0.f, 0.f, 0.f, 0.f};
  o[0] = z4; o[1] = z4; o[2] = z4; o[3] = z4;
  float mrow[4] = {-3e38f, -3e38f, -3e38f, -3e38f};
  float lrow[4] = {0.f, 0.f, 0.f, 0.f};

  const int srow = tid >> 2, sd = (tid & 3) * 2;   // staging: row, granule base
  const int sx = srow & 7;

#pragma unroll 1
  for (int t = 0; t < 16; t++) {
    if (t) __syncthreads();
    // ---- stage K tile hi/lo ----
    {
      const float* kp = K + (tok0 + t * 64 + srow) * kD + hoff + sd * 8;
      float4 a0 = *(const float4*)kp, a1 = *(const float4*)(kp + 4);
      float4 a2 = *(const float4*)(kp + 8), a3 = *(const float4*)(kp + 12);
      float vv[16] = {a0.x,a0.y,a0.z,a0.w, a1.x,a1.y,a1.z,a1.w,
                      a2.x,a2.y,a2.z,a2.w, a3.x,a3.y,a3.z,a3.w};
      short8 h0, l0, h1, l1;
#pragma unroll
      for (int j = 0; j < 8; j++) {
        u16 ha = f2b(vv[j]);     h0[j] = (short)ha; l0[j] = (short)f2b(vv[j] - b2f(ha));
        u16 hb = f2b(vv[8 + j]); h1[j] = (short)hb; l1[j] = (short)f2b(vv[8 + j] - b2f(hb));
      }
      *(short8*)&Ksh[srow][(sd ^ sx) << 3] = h0;
      *(short8*)&Ksl[srow][(sd ^ sx) << 3] = l0;
      *(short8*)&Ksh[srow][((sd + 1) ^ sx) << 3] = h1;
      *(short8*)&Ksl[srow][((sd + 1) ^ sx) << 3] = l1;
    }
    // ---- stage V tile transposed ----
    {
      const float* vp = V + (tok0 + t * 64 + srow) * kD + hoff + sd * 8;
      float4 a0 = *(const float4*)vp, a1 = *(const float4*)(vp + 4);
      float4 a2 = *(const float4*)(vp + 8), a3 = *(const float4*)(vp + 12);
      float vv[16] = {a0.x,a0.y,a0.z,a0.w, a1.x,a1.y,a1.z,a1.w,
                      a2.x,a2.y,a2.z,a2.w, a3.x,a3.y,a3.z,a3.w};
      const int kvg = srow >> 3, kvo = srow & 7;
#pragma unroll
      for (int j = 0; j < 16; j++) {
        const int d = sd * 8 + j;
        const int idx = ((kvg ^ (d & 7)) << 3) + kvo;
        u16 hh = f2b(vv[j]);
        Vth[d][idx] = hh;
        Vtl[d][idx] = f2b(vv[j] - b2f(hh));
      }
    }
    __syncthreads();
    // ---- QK^T (3-term split) ----
    f32x4 sa[4];
    sa[0] = z4; sa[1] = z4; sa[2] = z4; sa[3] = z4;
#pragma unroll
    for (int kt = 0; kt < 2; kt++) {
      const int g = ((kt * 4 + quad) ^ l7) << 3;
#pragma unroll
      for (int n = 0; n < 4; n++) {
        short8 bh = *(const short8*)&Ksh[n * 16 + l16][g];
        short8 bl = *(const short8*)&Ksl[n * 16 + l16][g];
        sa[n] = __builtin_amdgcn_mfma_f32_16x16x32_bf16(qlo[kt], bh, sa[n], 0, 0, 0);
        sa[n] = __builtin_amdgcn_mfma_f32_16x16x32_bf16(qh[kt], bl, sa[n], 0, 0, 0);
        sa[n] = __builtin_amdgcn_mfma_f32_16x16x32_bf16(qh[kt], bh, sa[n], 0, 0, 0);
      }
    }
    // ---- online softmax (rows quad*4+r, cols n*16+l16) ----
    float s_[4][4];
    float pm[4] = {-3e38f, -3e38f, -3e38f, -3e38f};
#pragma unroll
    for (int n = 0; n < 4; n++) {
      const bool mb = maskf[b * kS + t * 64 + n * 16 + l16] != 0.f;
#pragma unroll
      for (int r = 0; r < 4; r++) {
        float v = mb ? -1e30f : sa[n][r] * kScale;
        s_[n][r] = v;
        pm[r] = fmaxf(pm[r], v);
      }
    }
#pragma unroll
    for (int mo = 1; mo < 16; mo <<= 1) {
#pragma unroll
      for (int r = 0; r < 4; r++) pm[r] = fmaxf(pm[r], __shfl_xor(pm[r], mo, 64));
    }
    float alpha[4], rs[4];
#pragma unroll
    for (int r = 0; r < 4; r++) {
      float mn = fmaxf(mrow[r], pm[r]);
      alpha[r] = __expf(mrow[r] - mn);
      mrow[r] = mn;
      rs[r] = 0.f;
    }
#pragma unroll
    for (int n = 0; n < 4; n++) {
#pragma unroll
      for (int r = 0; r < 4; r++) {
        float p = __expf(s_[n][r] - mrow[r]);
        s_[n][r] = p;
        rs[r] += p;
      }
    }
#pragma unroll
    for (int mo = 1; mo < 16; mo <<= 1) {
#pragma unroll
      for (int r = 0; r < 4; r++) rs[r] += __shfl_xor(rs[r], mo, 64);
    }
#pragma unroll
    for (int r = 0; r < 4; r++) {
      lrow[r] = lrow[r] * alpha[r] + rs[r];
#pragma unroll
      for (int n = 0; n < 4; n++) o[n][r] *= alpha[r];
    }
    // ---- write P hi/lo (wave-local LDS) ----
#pragma unroll
    for (int n = 0; n < 4; n++) {
      const int cg = n * 2 + (l16 >> 3);
#pragma unroll
      for (int r = 0; r < 4; r++) {
        const int row = quad * 4 + r;
        const int idx = row * 64 + ((cg ^ (row & 7)) << 3) + l7;
        u16 hh = f2b(s_[n][r]);
        PsArr[wave][0][idx] = hh;
        PsArr[wave][1][idx] = f2b(s_[n][r] - b2f(hh));
      }
    }
    __syncthreads();   // drain P writes (plain barrier; no inline-asm fence)
    // ---- PV (3-term split) ----
#pragma unroll
    for (int ks = 0; ks < 2; ks++) {
      const int g = ((ks * 4 + quad) ^ l7) << 3;
      short8 ph = *(const short8*)&PsArr[wave][0][l16 * 64 + g];
      short8 pl = *(const short8*)&PsArr[wave][1][l16 * 64 + g];
#pragma unroll
      for (int n = 0; n < 4; n++) {
        short8 vh = *(const short8*)&Vth[n * 16 + l16][g];
        short8 vl = *(const short8*)&Vtl[n * 16 + l16][g];
        o[n] = __builtin_amdgcn_mfma_f32_16x16x32_bf16(pl, vh, o[n], 0, 0, 0);
        o[n] = __builtin_amdgcn_mfma_f32_16x16x32_bf16(ph, vl, o[n], 0, 0, 0);
        o[n] = __builtin_amdgcn_mfma_f32_16x16x32_bf16(ph, vh, o[n], 0, 0, 0);
      }
    }
  }
  // ---- epilogue ----
#pragma unroll
  for (int r = 0; r < 4; r++) {
    const float inv = 1.f / lrow[r];
    float* op = O + (q0 + wave * 16 + quad * 4 + r) * kD + hoff;
#pragma unroll
    for (int n = 0; n < 4; n++) op[n * 16 + l16] = o[n][r] * inv;
  }
}

// ---------------------------- split repack: W [1024][1024] -> hi/lo frag ----
__global__ __launch_bounds__(256) void splitW_k(const void* s0, const void* s1, const void* s2,
                                                u16* h0, u16* l0, u16* h1, u16* l1,
                                                u16* h2, u16* l2, const int* dflag) {
  const int f32 = dflag[0];
  const void* src = blockIdx.z == 0 ? s0 : (blockIdx.z == 1 ? s1 : s2);
  u16* hi = blockIdx.z == 0 ? h0 : (blockIdx.z == 1 ? h1 : h2);
  u16* lo = blockIdx.z == 0 ? l0 : (blockIdx.z == 1 ? l1 : l2);
  const int gid = blockIdx.x * 256 + threadIdx.x;     // < 131072
  const int n = gid & 1023;
  const int kb8 = gid >> 10;                          // k = kb8*8 + j
  const long long s0i = (long long)kb8 * 8 * 1024 + n;
  short8 h8, l8;
#pragma unroll
  for (int j = 0; j < 8; j++) {
    float v = ldIn(src, s0i + (long long)j * 1024, f32);
    u16 hh = f2b(v);
    h8[j] = (short)hh;
    l8[j] = (short)f2b(v - b2f(hh));
  }
  *(short8*)(hi + (long long)gid * 8) = h8;
  *(short8*)(lo + (long long)gid * 8) = l8;
}

// split repack: A [2048][1024] row-major -> hi/lo row-major bf16
__global__ __launch_bounds__(256) void splitA_k(const void* src, u16* hi, u16* lo,
                                                int forceF32, const int* dflag) {
  const int f32 = forceF32 ? 1 : dflag[0];
  const long long gid = (long long)blockIdx.x * 256 + threadIdx.x;   // < 262144
  float v[8];
  ld8f(src, gid * 8, f32, v);
  short8 h8, l8;
#pragma unroll
  for (int j = 0; j < 8; j++) {
    u16 hh = f2b(v[j]);
    h8[j] = (short)hh;
    l8[j] = (short)f2b(v[j] - b2f(hh));
  }
  *(short8*)(hi + gid * 8) = h8;
  *(short8*)(lo + gid * 8) = l8;
}

// ---------------- fast split-bf16 GEMM: C[2048,1024] = A @ B (NB outputs) ----
template <int NB>
__global__ __launch_bounds__(256) void gemmS_k(const u16* Ah, const u16* Al,
                                               const u16* Bh0, const u16* Bl0,
                                               const u16* Bh1, const u16* Bl1,
                                               const u16* Bh2, const u16* Bl2,
                                               float* C0, float* C1, float* C2,
                                               const void* bias, const int* dflag) {
  const int lin = blockIdx.y * gridDim.x + blockIdx.x;   // 512 blocks
  const int swz = (lin & 7) * 64 + (lin >> 3);           // XCD chunk (bijective)
  const int tx = swz >> 5, ty = swz & 31;                // x-major within chunk
  const int m0 = ty * 64, n0 = tx * 64;
  const int f32in = dflag[0];

  __shared__ __align__(16) u16 AhS[2][64][32], AlS[2][64][32];
  __shared__ __align__(16) u16 BhS[NB][2][4][64][8], BlS[NB][2][4][64][8];

  const int tid = threadIdx.x, wave = tid >> 6, lane = tid & 63;
  const int wr = wave >> 1, wc = wave & 1, quad = lane >> 4, l16 = lane & 15;

  const long long aOff = (long long)(m0 + (tid >> 2)) * kD + (tid & 3) * 8;
  const long long bOff = ((long long)(tid >> 6) * kD + n0 + (tid & 63)) * 8;
  const u16* pBh[3] = {Bh0, Bh1, Bh2};
  const u16* pBl[3] = {Bl0, Bl1, Bl2};
  float* pC[3] = {C0, C1, C2};

  f32x4 acc[NB][2][2];
  const f32x4 z4 = {0.f, 0.f, 0.f, 0.f};
#pragma unroll
  for (int i = 0; i < NB; i++) {
    acc[i][0][0] = z4; acc[i][0][1] = z4; acc[i][1][0] = z4; acc[i][1][1] = z4;
  }

  auto stage = [&](int buf, int kb) {
    gll16(Ah + aOff + kb * 32, (char*)&AhS[buf][0][0] + (wave << 10));
    gll16(Al + aOff + kb * 32, (char*)&AlS[buf][0][0] + (wave << 10));
    const long long bo = bOff + (long long)kb * (kD * 32);
#pragma unroll
    for (int i = 0; i < NB; i++) {
      gll16(pBh[i] + bo, (char*)&BhS[i][buf][0][0][0] + (wave << 10));
      gll16(pBl[i] + bo, (char*)&BlS[i][buf][0][0][0] + (wave << 10));
    }
  };

  stage(0, 0);
  __syncthreads();
  for (int kb = 0; kb < kD / 32; kb++) {
    const int cur = kb & 1;
    if (kb + 1 < kD / 32) stage(cur ^ 1, kb + 1);
    short8 ah0 = *(const short8*)&AhS[cur][wr * 32 + l16][quad * 8];
    short8 ah1 = *(const short8*)&AhS[cur][wr * 32 + 16 + l16][quad * 8];
    short8 al0 = *(const short8*)&AlS[cur][wr * 32 + l16][quad * 8];
    short8 al1 = *(const short8*)&AlS[cur][wr * 32 + 16 + l16][quad * 8];
#pragma unroll
    for (int i = 0; i < NB; i++) {
      short8 bh0 = *(const short8*)&BhS[i][cur][quad][wc * 32 + l16][0];
      short8 bh1 = *(const short8*)&BhS[i][cur][quad][wc * 32 + 16 + l16][0];
      short8 bl0 = *(const short8*)&BlS[i][cur][quad][wc * 32 + l16][0];
      short8 bl1 = *(const short8*)&BlS[i][cur][quad][wc * 32 + 16 + l16][0];
      acc[i][0][0] = __builtin_amdgcn_mfma_f32_16x16x32_bf16(al0, bh0, acc[i][0][0], 0, 0, 0);
      acc[i][0][1] = __builtin_amdgcn_mfma_f32_16x16x32_bf16(al0, bh1, acc[i][0][1], 0, 0, 0);
      acc[i][1][0] = __builtin_amdgcn_mfma_f32_16x16x32_bf16(al1, bh0, acc[i][1][0], 0, 0, 0);
      acc[i][1][1] = __builtin_amdgcn_mfma_f32_16x16x32_bf16(al1, bh1, acc[i][1][1], 0, 0, 0);
      acc[i][0][0] = __builtin_amdgcn_mfma_f32_16x16x32_bf16(ah0, bl0, acc[i][0][0], 0, 0, 0);
      acc[i][0][1] = __builtin_amdgcn_mfma_f32_16x16x32_bf16(ah0, bl1, acc[i][0][1], 0, 0, 0);
      acc[i][1][0] = __builtin_amdgcn_mfma_f32_16x16x32_bf16(ah1, bl0, acc[i][1][0], 0, 0, 0);
      acc[i][1][1] = __builtin_amdgcn_mfma_f32_16x16x32_bf16(ah1, bl1, acc[i][1][1], 0, 0, 0);
      acc[i][0][0] = __builtin_amdgcn_mfma_f32_16x16x32_bf16(ah0, bh0, acc[i][0][0], 0, 0, 0);
      acc[i][0][1] = __builtin_amdgcn_mfma_f32_16x16x32_bf16(ah0, bh1, acc[i][0][1], 0, 0, 0);
      acc[i][1][0] = __builtin_amdgcn_mfma_f32_16x16x32_bf16(ah1, bh0, acc[i][1][0], 0, 0, 0);
      acc[i][1][1] = __builtin_amdgcn_mfma_f32_16x16x32_bf16(ah1, bh1, acc[i][1][1], 0, 0, 0);
    }
    __syncthreads();
  }

#pragma unroll
  for (int i = 0; i < NB; i++) {
#pragma unroll
    for (int sm = 0; sm < 2; sm++) {
#pragma unroll
      for (int r = 0; r < 4; r++) {
        int row = m0 + wr * 32 + sm * 16 + quad * 4 + r;
#pragma unroll
        for (int sn = 0; sn < 2; sn++) {
          int col = n0 + wc * 32 + sn * 16 + l16;
          float v = acc[i][sm][sn][r];
          if (bias && i == 0) v += ldIn(bias, col, f32in);
          pC[i][(long long)row * kD + col] = v;
        }
      }
    }
  }
}

// ------------------------------------- MoE weight repack fp32 -> bf16 -------
__global__ __launch_bounds__(256) void cvtW_k(const void* src, u16* dst,
                                              int nSh, int kbSh, const int* dflag) {
  const int f32 = dflag[0];
  const int gid = blockIdx.x * 256 + threadIdx.x;
  const int N = 1 << nSh;
  const int n = gid & (N - 1);
  const int rest = gid >> nSh;
  const int kg = rest & 3;
  const int kb = (rest >> 2) & ((1 << kbSh) - 1);
  const int e = rest >> (2 + kbSh);
  const long long src0 = ((long long)e << (5 + kbSh + nSh)) +
                         (long long)(kb * 32 + kg * 8) * N + n;
  short8 o;
#pragma unroll
  for (int j = 0; j < 8; j++) o[j] = (short)f2b(ldIn(src, src0 + (long long)j * N, f32));
  *(short8*)(dst + (long long)gid * 8) = o;
}

// x2f (fp32) -> bf16, linear layout
__global__ __launch_bounds__(256) void cvtX_k(const float* src, u16* dst) {
  const int gid = blockIdx.x * 256 + threadIdx.x;
  const float* s = src + (long long)gid * 8;
  float4 a = *(const float4*)s, b = *(const float4*)(s + 4);
  short8 o;
  o[0]=(short)f2b(a.x); o[1]=(short)f2b(a.y); o[2]=(short)f2b(a.z); o[3]=(short)f2b(a.w);
  o[4]=(short)f2b(b.x); o[5]=(short)f2b(b.y); o[6]=(short)f2b(b.z); o[7]=(short)f2b(b.w);
  *(short8*)(dst + (long long)gid * 8) = o;
}

// -------------------------------------------- fused MoE W1/W3 + SwiGLU ------
__global__ __launch_bounds__(256) void moe13_k(const u16* Xb, const u16* W1c, const u16* W3c,
                                               const int* counts, const int* offsets,
                                               const int* aidxArr, u16* Hbuf) {
  const int e = blockIdx.z;
  const int Meff = counts[e];
  const int m0 = blockIdx.y * 64;
  if (m0 >= Meff) return;
  const int n0 = blockIdx.x * 128;
  const int csr = offsets[e];

  __shared__ __align__(16) u16 As[2][64][32];
  __shared__ __align__(16) u16 B1s[2][4][128][8];
  __shared__ __align__(16) u16 B3s[2][4][128][8];

  const int tid = threadIdx.x, wave = tid >> 6, lane = tid & 63;
  const int wc = wave, quad = lane >> 4, l16 = lane & 15;

  int grow = m0 + (tid >> 2); if (grow >= Meff) grow = Meff - 1;
  const u16* pA = Xb + (long long)aidxArr[csr + grow] * kD + (tid & 3) * 8;

  const long long ebase = (long long)e * kD * kHID;
  const int g0 = tid, g1 = 256 + tid;
  const long long b0o = ebase + ((long long)(g0 >> 7) * kHID + n0 + (g0 & 127)) * 8;
  const long long b1o = ebase + ((long long)(g1 >> 7) * kHID + n0 + (g1 & 127)) * 8;

  f32x4 acc1[4][2], acc3[4][2];
  const f32x4 z4 = {0.f, 0.f, 0.f, 0.f};
#pragma unroll
  for (int i = 0; i < 4; i++) { acc1[i][0]=z4; acc1[i][1]=z4; acc3[i][0]=z4; acc3[i][1]=z4; }

  auto stage = [&](int buf, int kb) {
    gll16(pA + kb * 32, (char*)&As[buf][0][0] + (wave << 10));
    const long long ko = (long long)kb * (4 * kHID * 8);
    gll16(W1c + b0o + ko, (char*)&B1s[buf][0][0][0] + (wave << 10));
    gll16(W1c + b1o + ko, (char*)&B1s[buf][0][0][0] + 4096 + (wave << 10));
    gll16(W3c + b0o + ko, (char*)&B3s[buf][0][0][0] + (wave << 10));
    gll16(W3c + b1o + ko, (char*)&B3s[buf][0][0][0] + 4096 + (wave << 10));
  };

  stage(0, 0);
  __syncthreads();
  for (int kb = 0; kb < kD / 32; kb++) {
    const int cur = kb & 1;
    if (kb + 1 < kD / 32) stage(cur ^ 1, kb + 1);
    short8 af[4];
#pragma unroll
    for (int sm = 0; sm < 4; sm++)
      af[sm] = *(const short8*)&As[cur][sm * 16 + l16][quad * 8];
    short8 b1f[2], b3f[2];
#pragma unroll
    for (int sn = 0; sn < 2; sn++) {
      b1f[sn] = *(const short8*)&B1s[cur][quad][wc * 32 + sn * 16 + l16][0];
      b3f[sn] = *(const short8*)&B3s[cur][quad][wc * 32 + sn * 16 + l16][0];
    }
#pragma unroll
    for (int sm = 0; sm < 4; sm++) {
#pragma unroll
      for (int sn = 0; sn < 2; sn++) {
        acc1[sm][sn] = __builtin_amdgcn_mfma_f32_16x16x32_bf16(af[sm], b1f[sn], acc1[sm][sn], 0, 0, 0);
        acc3[sm][sn] = __builtin_amdgcn_mfma_f32_16x16x32_bf16(af[sm], b3f[sn], acc3[sm][sn], 0, 0, 0);
      }
    }
    __syncthreads();
  }

#pragma unroll
  for (int sm = 0; sm < 4; sm++) {
#pragma unroll
    for (int r = 0; r < 4; r++) {
      int row = m0 + sm * 16 + quad * 4 + r;
      if (row >= Meff) continue;
#pragma unroll
      for (int sn = 0; sn < 2; sn++) {
        int col = n0 + wc * 32 + sn * 16 + l16;
        float g1 = acc1[sm][sn][r], g3 = acc3[sm][sn][r];
        float h = (g1 / (1.f + __expf(-g1))) * g3;
        Hbuf[(long long)(csr + row) * kHID + col] = f2b(h);
      }
    }
  }
}

// ------------------------------------------------ MoE W2 + scatter ---------
__global__ __launch_bounds__(256) void w2_k(const u16* Hbuf, const u16* W2c,
                                            const int* counts, const int* offsets,
                                            const int* aidxArr, const int* slotArr,
                                            const float* wgtArr, float* contrib) {
  const int e = blockIdx.z;
  const int Meff = counts[e];
  const int m0 = blockIdx.y * 64;
  if (m0 >= Meff) return;
  const int n0 = blockIdx.x * 128;
  const int csr = offsets[e];

  __shared__ __align__(16) u16 As[2][64][32];
  __shared__ __align__(16) u16 Bs[2][4][128][8];

  const int tid = threadIdx.x, wave = tid >> 6, lane = tid & 63;
  const int wc = wave, quad = lane >> 4, l16 = lane & 15;

  int grow = m0 + (tid >> 2); if (grow >= Meff) grow = Meff - 1;
  const u16* pA = Hbuf + (long long)(csr + grow) * kHID + (tid & 3) * 8;

  const long long ebase = (long long)e * kHID * kD;
  const int g0 = tid, g1 = 256 + tid;
  const long long b0o = ebase + ((long long)(g0 >> 7) * kD + n0 + (g0 & 127)) * 8;
  const long long b1o = ebase + ((long long)(g1 >> 7) * kD + n0 + (g1 & 127)) * 8;

  f32x4 acc[4][2];
  const f32x4 z4 = {0.f, 0.f, 0.f, 0.f};
#pragma unroll
  for (int i = 0; i < 4; i++) { acc[i][0] = z4; acc[i][1] = z4; }

  auto stage = [&](int buf, int kb) {
    gll16(pA + kb * 32, (char*)&As[buf][0][0] + (wave << 10));
    const long long ko = (long long)kb * (4 * kD * 8);
    gll16(W2c + b0o + ko, (char*)&Bs[buf][0][0][0] + (wave << 10));
    gll16(W2c + b1o + ko, (char*)&Bs[buf][0][0][0] + 4096 + (wave << 10));
  };

  stage(0, 0);
  __syncthreads();
  for (int kb = 0; kb < kHID / 32; kb++) {
    const int cur = kb & 1;
    if (kb + 1 < kHID / 32) stage(cur ^ 1, kb + 1);
    short8 af[4];
#pragma unroll
    for (int sm = 0; sm < 4; sm++)
      af[sm] = *(const short8*)&As[cur][sm * 16 + l16][quad * 8];
    short8 bf[2];
#pragma unroll
    for (int sn = 0; sn < 2; sn++)
      bf[sn] = *(const short8*)&Bs[cur][quad][wc * 32 + sn * 16 + l16][0];
#pragma unroll
    for (int sm = 0; sm < 4; sm++) {
#pragma unroll
      for (int sn = 0; sn < 2; sn++)
        acc[sm][sn] = __builtin_amdgcn_mfma_f32_16x16x32_bf16(af[sm], bf[sn], acc[sm][sn], 0, 0, 0);
    }
    __syncthreads();
  }

#pragma unroll
  for (int sm = 0; sm < 4; sm++) {
#pragma unroll
    for (int r = 0; r < 4; r++) {
      int row = m0 + sm * 16 + quad * 4 + r;
      if (row >= Meff) continue;
      int a = csr + row;
      int t = aidxArr[a]; int s = slotArr[a]; float w = wgtArr[a];
#pragma unroll
      for (int sn = 0; sn < 2; sn++) {
        int col = n0 + wc * 32 + sn * 16 + l16;
        contrib[((long long)s * kTok + t) * kD + col] = acc[sm][sn][r] * w;
      }
    }
  }
}

// ------------------------------------------------------------ small ops -----
__global__ void maskprep_k(const void* srcm, const void* tgtm, const void* midm,
                           float* srcf, float* padf, float* keepf, float* denom) {
  __shared__ int okInt, okFloat, okBf16;
  int tid = threadIdx.x;
  if (tid == 0) { okInt = 1; okFloat = 1; okBf16 = 1; }
  __syncthreads();
  const unsigned int* wi = (const unsigned int*)tgtm;
  const float* wf = (const float*)tgtm;
  int badI = 0, badF = 0, badB = 0;
  for (int i = tid; i < 512; i += 256) {
    unsigned int w = wi[i];
    if (w > 1u) badI = 1;
    float f = wf[i];
    if (!(f == 0.f || f == 1.f)) badF = 1;
    unsigned int lo = w & 0xffffu, hi = w >> 16;
    if (!((lo == 0 || lo == 0x3f80u) && (hi == 0 || hi == 0x3f80u))) badB = 1;
  }
  if (badI) atomicExch(&okInt, 0);
  if (badF) atomicExch(&okFloat, 0);
  if (badB) atomicExch(&okBf16, 0);
  __syncthreads();
  int mode = okInt ? 0 : (okFloat ? 2 : (okBf16 ? 3 : 1));
  for (int i = tid; i < kTok; i += 256) {
    bool sv, pv, mv;
    if (mode == 0) {
      sv = ((const int*)srcm)[i] != 0; pv = ((const int*)tgtm)[i] != 0; mv = ((const int*)midm)[i] != 0;
    } else if (mode == 2) {
      sv = ((const float*)srcm)[i] != 0.f; pv = ((const float*)tgtm)[i] != 0.f; mv = ((const float*)midm)[i] != 0.f;
    } else if (mode == 3) {
      sv = ((const u16*)srcm)[i] != 0; pv = ((const u16*)tgtm)[i] != 0; mv = ((const u16*)midm)[i] != 0;
    } else {
      sv = ((const unsigned char*)srcm)[i] != 0; pv = ((const unsigned char*)tgtm)[i] != 0; mv = ((const unsigned char*)midm)[i] != 0;
    }
    srcf[i] = sv ? 1.f : 0.f;
    padf[i] = pv ? 1.f : 0.f;
    keepf[i] = (pv || mv) ? 0.f : 1.f;
  }
  __syncthreads();
  if (tid < 2) {
    float s = 0;
    for (int j = 0; j < kS; j++) s += keepf[tid * kS + j];
    denom[tid] = fmaxf(s, 1.f);
  }
}

__global__ __launch_bounds__(256) void ln_k(const float* basef, const void* baseb,
                                            const int* dflag, int baseIsIn,
                                            const float* add1, const float* add2,
                                            const void* g, const void* bb,
                                            float* outf, void* outFinal) {
  const int f32in = dflag[0];
  const int baseF32 = baseIsIn && f32in;
  long long base = (long long)blockIdx.x * kD;
  int tid = threadIdx.x;
  float v[4]; float s = 0;
#pragma unroll
  for (int i = 0; i < 4; i++) {
    int d = tid + i * 256;
    float x = basef ? basef[base + d] : ldIn(baseb, base + d, baseF32);
    if (add1) x += add1[base + d];
    if (add2) x += add2[base + d];
    v[i] = x; s += x;
  }
  float mean = blockReduceSum(s) * (1.f / kD);
  float q = 0;
#pragma unroll
  for (int i = 0; i < 4; i++) { float d0 = v[i] - mean; q += d0 * d0; }
  float var = blockReduceSum(q) * (1.f / kD);
  float rstd = rsqrtf(var + 1e-5f);
#pragma unroll
  for (int i = 0; i < 4; i++) {
    int d = tid + i * 256;
    float y = (v[i] - mean) * rstd * ldIn(g, d, f32in) + ldIn(bb, d, f32in);
    if (outf) outf[base + d] = y;
    if (outFinal) stOut(outFinal, base + d, y, f32in);
  }
}

__global__ __launch_bounds__(256) void router_k(const float* xf, const void* gw, void* outBase,
                                                int* sel, float* wsel, int* counts,
                                                const int* dflag) {
  const int f32in = dflag[0];
  int wv = threadIdx.x >> 6, lane = threadIdx.x & 63;
  int t = blockIdx.x * 4 + wv;
  const float* xr = xf + (long long)t * kD;
  float acc[8];
#pragma unroll
  for (int e = 0; e < 8; e++) acc[e] = 0.f;
  for (int d = lane; d < kD; d += 64) {
    float xv = xr[d];
    float gv[8];
    ld8f(gw, (long long)d * 8, f32in, gv);
#pragma unroll
    for (int e = 0; e < 8; e++) acc[e] += xv * gv[e];
  }
#pragma unroll
  for (int o = 32; o; o >>= 1) {
#pragma unroll
    for (int e = 0; e < 8; e++) acc[e] += __shfl_down(acc[e], o, 64);
  }
  if (lane == 0) {
    float mx = acc[0];
    for (int e = 1; e < 8; e++) mx = fmaxf(mx, acc[e]);
    float p[8], sum = 0;
    for (int e = 0; e < 8; e++) { p[e] = expf(acc[e] - mx); sum += p[e]; }
    float inv = 1.f / sum;
    for (int e = 0; e < 8; e++) {
      p[e] *= inv;
      stOut(outBase, kOutProbs + (long long)t * 8 + e, p[e], f32in);
    }
    int e0 = 0; for (int e = 1; e < 8; e++) if (p[e] > p[e0]) e0 = e;
    int e1 = -1; for (int e = 0; e < 8; e++) { if (e == e0) continue; if (e1 < 0 || p[e] > p[e1]) e1 = e; }
    float s2 = p[e0] + p[e1];
    sel[t * 2] = e0; sel[t * 2 + 1] = e1;
    wsel[t * 2] = p[e0] / s2; wsel[t * 2 + 1] = p[e1] / s2;
    atomicAdd(&counts[e0], 1); atomicAdd(&counts[e1], 1);
  }
}

__global__ void offsets_k(const int* counts, int* offsets) {
  if (threadIdx.x == 0) {
    int s = 0;
    for (int e = 0; e < kE; e++) { offsets[e] = s; s += counts[e]; }
    offsets[kE] = s;
  }
}

__global__ void place_k(const int* sel, const float* wsel, const int* offsets, int* fill,
                        int* aidxArr, int* slotArr, float* wgtArr) {
  int t = blockIdx.x * 256 + threadIdx.x;
  if (t >= kTok) return;
  for (int s = 0; s < 2; s++) {
    int e = sel[t * 2 + s];
    int pos = offsets[e] + atomicAdd(&fill[e], 1);
    aidxArr[pos] = t; slotArr[pos] = s; wgtArr[pos] = wsel[t * 2 + s];
  }
}

__global__ void meanacc_k(const int* counts, const int* offsets, const int* aidxArr,
                          const int* slotArr, const float* keepf, const float* contrib,
                          float* meanAcc) {
  int e = blockIdx.x, dc = blockIdx.y, ch = blockIdx.z;
  int d = dc * 128 + threadIdx.x;
  int cnt = counts[e], off = offsets[e];
  int per = (cnt + 15) / 16;
  int i0 = ch * per, i1 = i0 + per; if (i1 > cnt) i1 = cnt;
  float a0 = 0, a1 = 0;
  for (int i = i0; i < i1; i++) {
    int a = off + i; int t = aidxArr[a];
    if (keepf[t] != 0.f) {
      float v = contrib[((long long)slotArr[a] * kTok + t) * kD + d];
      if (t < kS) a0 += v; else a1 += v;
    }
  }
  if (a0 != 0.f) atomicAdd(&meanAcc[(e * 2 + 0) * kD + d], a0);
  if (a1 != 0.f) atomicAdd(&meanAcc[(e * 2 + 1) * kD + d], a1);
}

__global__ __launch_bounds__(256) void dots_k(const float* meanAcc, const void* cls_w,
                                              const float* denom, float* dots,
                                              const int* dflag) {
  const int f32in = dflag[0];
  int eb = blockIdx.x;
  int b = eb & 1;
  float s = 0;
  for (int d = threadIdx.x; d < kD; d += 256)
    s += meanAcc[(long long)eb * kD + d] * ldIn(cls_w, d, f32in);
  s = blockReduceSum(s);
  if (threadIdx.x == 0) dots[eb] = s / denom[b];
}

__global__ void final_logits_k(const float* dots, const void* cls_b, void* outBase,
                               const int* dflag) {
  const int f32in = dflag[0];
  int i = threadIdx.x;
  if (i < kE * kB) {
    int e = i >> 1, b = i & 1;
    float s = ldIn(cls_b, 0, f32in);
    for (int e2 = 0; e2 <= e; e2++) s += dots[e2 * 2 + b];
    stOut(outBase, kOutLogits + e * kB + b, s, f32in);
  }
}

// ------------------------------------------------------------------ host ----
extern "C" void kernel_launch(void* const* d_in, const int* in_sizes, int n_in,
                              void* d_out, int out_size, void* d_ws, size_t ws_size,
                              hipStream_t stream) {
  (void)in_sizes; (void)n_in; (void)out_size; (void)ws_size;

  const void* x_in  = d_in[0];
  const void* enc   = d_in[1];
  const void* srcm = d_in[2];
  const void* tgtm = d_in[3];
  const void* midm = d_in[4];
  const void* ln1g = d_in[5];  const void* ln1b = d_in[6];
  const void* ln2g = d_in[7];  const void* ln2b = d_in[8];
  const void* ln3g = d_in[9];  const void* ln3b = d_in[10];
  const void* sa_wq = d_in[11]; const void* sa_wk = d_in[12];
  const void* sa_wv = d_in[13]; const void* sa_wo = d_in[14];
  const void* sa_bo = d_in[15];
  const void* ca_wq = d_in[16]; const void* ca_wk = d_in[17];
  const void* ca_wv = d_in[18]; const void* ca_wo = d_in[19];
  const void* ca_bo = d_in[20];
  const void* gate_w = d_in[21];
  const void* cls_w  = d_in[22]; const void* cls_b = d_in[23];
  const void* moe_w1 = d_in[24];
  const void* moe_w2 = d_in[25];
  const void* moe_w3 = d_in[26];

  char* wp = (char*)d_ws;
  size_t off = 0;
  auto alloc = [&](size_t bytes) -> void* {
    void* p = wp + off; off = (off + bytes + 255) & ~(size_t)255; return p;
  };
  float* scFP = (float*)alloc((size_t)16 * kS * kS * 4);          // 64 MiB scratch
  u16*   Hbuf = (u16*)scFP;                                        // [0,16) MiB (MoE)
  float* contrib = (float*)((char*)scFP + (size_t)2 * kTok * kHID * 2); // [16,32) MiB
  float* qf    = (float*)alloc((size_t)kTok * kD * 4);
  float* kf    = (float*)alloc((size_t)kTok * kD * 4);
  float* vf    = (float*)alloc((size_t)kTok * kD * 4);
  float* attnof= (float*)alloc((size_t)kTok * kD * 4);
  float* obuf  = (float*)alloc((size_t)kTok * kD * 4);
  float* x1f   = (float*)alloc((size_t)kTok * kD * 4);
  float* x2f   = (float*)alloc((size_t)kTok * kD * 4);
  float* meanAcc = (float*)alloc((size_t)kE * kB * kD * 4);
  float* srcf = (float*)alloc(kTok * 4);
  float* padf = (float*)alloc(kTok * 4);
  float* keepf = (float*)alloc(kTok * 4);
  float* denom = (float*)alloc(2 * 4);
  int* counts = (int*)alloc(256); int* fill = counts + 8;
  int* offsets = (int*)alloc(256);
  int* sel = (int*)alloc(kTok * 2 * 4);
  float* wsel = (float*)alloc(kTok * 2 * 4);
  int* aidxArr = (int*)alloc(2 * kTok * 4);
  int* slotArr = (int*)alloc(2 * kTok * 4);
  float* wgtArr = (float*)alloc(2 * kTok * 4);
  float* dots = (float*)alloc(256);
  int* dflag = (int*)alloc(256);

  // Split scratch (dead-at-the-time regions):
  u16* WH0 = (u16*)x2f;
  u16* WL0 = WH0 + (1 << 20);
  u16* WH1 = WL0 + (1 << 20);
  u16* WL1 = WH1 + (1 << 20);
  u16* WH2 = (u16*)x1f;
  u16* WL2 = WH2 + (1 << 20);
  u16* AH  = (u16*)scFP;
  u16* AL  = AH + (2 << 20);

  // MoE repack buffers:
  u16* W1c = (u16*)qf;                                     // qf..attnof 32 MiB
  u16* W2c = (u16*)qf;
  u16* W3c = (u16*)((char*)scFP + ((size_t)32 << 20));
  u16* Xb  = (u16*)obuf;

  hipMemsetAsync(counts, 0, 64, stream);
  hipMemsetAsync(meanAcc, 0, (size_t)kE * kB * kD * 4, stream);
  detect_k<<<1, 256, 0, stream>>>(x_in, dflag);
  maskprep_k<<<1, 256, 0, stream>>>(srcm, tgtm, midm, srcf, padf, keepf, denom);

  const dim3 gGrid(16, 32);
  const dim3 aGrid(kS / 64, 32);

  // ---- self attention ----
  splitA_k<<<1024, 256, 0, stream>>>(x_in, AH, AL, 0, dflag);
  splitW_k<<<dim3(512, 1, 3), 256, 0, stream>>>(sa_wq, sa_wk, sa_wv,
      WH0, WL0, WH1, WL1, WH2, WL2, dflag);
  gemmS_k<3><<<gGrid, 256, 0, stream>>>(AH, AL, WH0, WL0, WH1, WL1, WH2, WL2,
      qf, kf, vf, nullptr, dflag);
  fattn_k<<<aGrid, 256, 0, stream>>>(qf, kf, vf, padf, attnof);
  splitA_k<<<1024, 256, 0, stream>>>(attnof, AH, AL, 1, dflag);
  splitW_k<<<dim3(512, 1, 1), 256, 0, stream>>>(sa_wo, nullptr, nullptr,
      WH0, WL0, nullptr, nullptr, nullptr, nullptr, dflag);
  gemmS_k<1><<<gGrid, 256, 0, stream>>>(AH, AL, WH0, WL0, WH0, WL0, WH0, WL0,
      obuf, obuf, obuf, sa_bo, dflag);
  ln_k<<<kTok, 256, 0, stream>>>(nullptr, x_in, dflag, 1, obuf, nullptr, ln1g, ln1b, x1f, nullptr);

  // ---- cross attention ----
  splitA_k<<<1024, 256, 0, stream>>>(x1f, AH, AL, 1, dflag);
  splitW_k<<<dim3(512, 1, 1), 256, 0, stream>>>(ca_wq, nullptr, nullptr,
      WH0, WL0, nullptr, nullptr, nullptr, nullptr, dflag);
  gemmS_k<1><<<gGrid, 256, 0, stream>>>(AH, AL, WH0, WL0, WH0, WL0, WH0, WL0,
      qf, qf, qf, nullptr, dflag);
  splitA_k<<<1024, 256, 0, stream>>>(enc, AH, AL, 0, dflag);
  splitW_k<<<dim3(512, 1, 2), 256, 0, stream>>>(ca_wk, ca_wv, nullptr,
      WH0, WL0, WH1, WL1, nullptr, nullptr, dflag);
  gemmS_k<2><<<gGrid, 256, 0, stream>>>(AH, AL, WH0, WL0, WH1, WL1, WH0, WL0,
      kf, vf, vf, nullptr, dflag);
  fattn_k<<<aGrid, 256, 0, stream>>>(qf, kf, vf, srcf, attnof);
  splitA_k<<<1024, 256, 0, stream>>>(attnof, AH, AL, 1, dflag);
  splitW_k<<<dim3(512, 1, 1), 256, 0, stream>>>(ca_wo, nullptr, nullptr,
      WH0, WL0, nullptr, nullptr, nullptr, nullptr, dflag);
  gemmS_k<1><<<gGrid, 256, 0, stream>>>(AH, AL, WH0, WL0, WH0, WL0, WH0, WL0,
      obuf, obuf, obuf, ca_bo, dflag);
  ln_k<<<kTok, 256, 0, stream>>>(x1f, nullptr, dflag, 0, obuf, nullptr, ln2g, ln2b, x2f, nullptr);

  // ---- MoE ----
  router_k<<<kTok / 4, 256, 0, stream>>>(x2f, gate_w, d_out, sel, wsel, counts, dflag);
  offsets_k<<<1, 64, 0, stream>>>(counts, offsets);
  place_k<<<kTok / 256, 256, 0, stream>>>(sel, wsel, offsets, fill, aidxArr, slotArr, wgtArr);

  cvtX_k<<<kTok * kD / (8 * 256), 256, 0, stream>>>(x2f, Xb);
  const int wGrid = (kE * kD * kHID / 8) / 256;   // 8192
  cvtW_k<<<wGrid, 256, 0, stream>>>(moe_w1, W1c, 11, 5, dflag);  // K=1024,N=2048
  cvtW_k<<<wGrid, 256, 0, stream>>>(moe_w3, W3c, 11, 5, dflag);

  moe13_k<<<dim3(kHID / 128, kTok / 64, kE), 256, 0, stream>>>(
      Xb, W1c, W3c, counts, offsets, aidxArr, Hbuf);

  cvtW_k<<<wGrid, 256, 0, stream>>>(moe_w2, W2c, 10, 6, dflag);  // K=2048,N=1024

  w2_k<<<dim3(kD / 128, kTok / 64, kE), 256, 0, stream>>>(
      Hbuf, W2c, counts, offsets, aidxArr, slotArr, wgtArr, contrib);

  meanacc_k<<<dim3(kE, kD / 128, 16), 128, 0, stream>>>(counts, offsets, aidxArr, slotArr, keepf, contrib, meanAcc);
  dots_k<<<kE * kB, 256, 0, stream>>>(meanAcc, cls_w, denom, dots, dflag);
  final_logits_k<<<1, 64, 0, stream>>>(dots, cls_b, d_out, dflag);
  ln_k<<<kTok, 256, 0, stream>>>(x2f, nullptr, dflag, 0, contrib, contrib + (size_t)kTok * kD, ln3g, ln3b, nullptr, d_out);
}

// Round 6
// 899.462 us; speedup vs baseline: 1.4751x; 1.0355x over previous
//
#include <hip/hip_runtime.h>
#include <hip/hip_bf16.h>
#include <math.h>

constexpr int kB   = 2;
constexpr int kS   = 1024;
constexpr int kD   = 1024;
constexpr int kH   = 16;
constexpr int kDH  = 64;
constexpr int kHID = 2048;
constexpr int kE   = 8;
constexpr int kTok = kB * kS;         // 2048
constexpr float kScale = 0.125f;
constexpr long long kOutLogits = (long long)kTok * kD;
constexpr long long kOutProbs  = kOutLogits + kE * kB;

using u16 = unsigned short;
typedef __attribute__((ext_vector_type(8))) short short8;
typedef __attribute__((ext_vector_type(4))) float f32x4;

__device__ __forceinline__ float b2f(u16 u) {
  union { unsigned int i; float f; } c; c.i = ((unsigned int)u) << 16; return c.f;
}
__device__ __forceinline__ u16 f2b(float f) {
  __hip_bfloat16 h = __float2bfloat16(f);
  u16 u; __builtin_memcpy(&u, &h, 2); return u;
}
__device__ __forceinline__ float ldIn(const void* p, long long i, int f32) {
  return f32 ? ((const float*)p)[i] : b2f(((const u16*)p)[i]);
}
__device__ __forceinline__ void ld8f(const void* p, long long i, int f32, float v[8]) {
  if (f32) {
    const float* fp = (const float*)p + i;
    float4 a = *(const float4*)fp, b = *(const float4*)(fp + 4);
    v[0]=a.x; v[1]=a.y; v[2]=a.z; v[3]=a.w; v[4]=b.x; v[5]=b.y; v[6]=b.z; v[7]=b.w;
  } else {
    short8 s = *(const short8*)((const u16*)p + i);
#pragma unroll
    for (int j = 0; j < 8; j++) v[j] = b2f((u16)s[j]);
  }
}
__device__ __forceinline__ void stOut(void* base, long long i, float v, int f32) {
  if (f32) ((float*)base)[i] = v; else ((u16*)base)[i] = f2b(v);
}

// async global->LDS, 16B per lane. LDS dest is wave-uniform base + lane*16.
__device__ __forceinline__ void gll16(const void* g, void* l) {
  __builtin_amdgcn_global_load_lds(
      (__attribute__((address_space(1))) unsigned int*)(unsigned long long)g,
      (__attribute__((address_space(3))) unsigned int*)l, 16, 0, 0);
}

__device__ __forceinline__ float blockReduceSum(float v) {
  __shared__ float sh[4];
  int lane = threadIdx.x & 63, wv = threadIdx.x >> 6;
#pragma unroll
  for (int o = 32; o; o >>= 1) v += __shfl_down(v, o, 64);
  __syncthreads();
  if (lane == 0) sh[wv] = v;
  __syncthreads();
  return sh[0] + sh[1] + sh[2] + sh[3];
}
__device__ __forceinline__ float blockReduceMax(float v) {
  __shared__ float sh[4];
  int lane = threadIdx.x & 63, wv = threadIdx.x >> 6;
#pragma unroll
  for (int o = 32; o; o >>= 1) v = fmaxf(v, __shfl_down(v, o, 64));
  __syncthreads();
  if (lane == 0) sh[wv] = v;
  __syncthreads();
  return fmaxf(fmaxf(sh[0], sh[1]), fmaxf(sh[2], sh[3]));
}

// ------------------------------------------------------------- detect -------
__global__ void detect_k(const void* x, int* dflag) {
  __shared__ int sg, st;
  int tid = threadIdx.x;
  if (tid == 0) { sg = 0; st = 0; }
  __syncthreads();
  const unsigned int* w = (const unsigned int*)x;
  int good = 0, tot = 0;
  for (int i = tid; i < 1024; i += 256) {
    unsigned int lo = w[i] & 0xffffu;
    if (lo) {
      tot++;
      unsigned int e = (lo >> 7) & 0xffu;
      if (e >= 97 && e <= 159) good++;
    }
  }
  atomicAdd(&sg, good); atomicAdd(&st, tot);
  __syncthreads();
  if (tid == 0) dflag[0] = (sg * 10 < st * 9) ? 1 : 0;
}

// --------------------------------------------- fused flash attention --------
// O = softmax(Q K^T * scale, mask) V ; all operands pre-split hi/lo bf16.
// Grid (Sq/64, 32 bh). 256 thr = 4 waves; wave owns 16 q-rows.
// Swizzle key(r) = (r ^ (r>>3)) & 7 gives <=2 lanes/bank per 16-lane phase
// on every LDS path. K staged LINEAR (swizzle folded into global src addr,
// m173 pattern) so the b128 LDS writes are conflict-free by construction.
// T14: K/V regs for tile t+1 loaded during tile t compute; the mid-tile
// P-barrier's implicit vmcnt drain lands ~2000cy later -> latency hidden.
__device__ __forceinline__ int key8(int r) { return (r ^ (r >> 3)) & 7; }

__global__ __launch_bounds__(256) void fattn_k(const u16* Qh, const u16* Ql,
                                               const u16* Kh, const u16* Kl,
                                               const u16* Vh, const u16* Vl,
                                               const float* maskf,
                                               u16* Oh, u16* Ol) {
  const int qt = blockIdx.x, bh = blockIdx.y;
  const int b = bh >> 4, hoff = (bh & 15) * 64;
  const int tid = threadIdx.x, wave = tid >> 6, lane = tid & 63;
  const int quad = lane >> 4, l16 = lane & 15, l7 = lane & 7;

  __shared__ __align__(16) u16 Ksh[64][64], Ksl[64][64];   // [kv][d-swz]
  __shared__ __align__(16) u16 Vth[64][64], Vtl[64][64];   // [d][kv-swz]
  __shared__ __align__(16) u16 Ps[4][2][1024];             // per-wave P hi/lo

  const long long tok0 = (long long)b * kS;
  const long long q0 = tok0 + qt * 64;

  // Q fragments (direct split loads; zero conversion)
  short8 qh[2], qlo[2];
  {
    const long long qoff = (q0 + wave * 16 + l16) * kD + hoff;
#pragma unroll
    for (int kt = 0; kt < 2; kt++) {
      qh[kt]  = *(const short8*)(Qh + qoff + kt * 32 + quad * 8);
      qlo[kt] = *(const short8*)(Ql + qoff + kt * 32 + quad * 8);
    }
  }

  // K staging: LDS granule g (linear) <- global granule (g&7)^key8(g>>3)
  const int g0i = tid, g1i = 256 + tid;
  const int kr0 = g0i >> 3, kc0 = (g0i & 7) ^ key8(g0i >> 3);
  const int kr1 = g1i >> 3, kc1 = (g1i & 7) ^ key8(g1i >> 3);
  // V staging: thread owns row srow, d-granules sd, sd+1 (transposed write)
  const int srow = tid >> 2, sd = (tid & 3) * 2;
  const int kvg = srow >> 3, kvo = srow & 7;

  f32x4 o[4];
  const f32x4 z4 = {0.f, 0.f, 0.f, 0.f};
  o[0] = z4; o[1] = z4; o[2] = z4; o[3] = z4;
  float mrow[4] = {-3e38f, -3e38f, -3e38f, -3e38f};
  float lrow[4] = {0.f, 0.f, 0.f, 0.f};

  short8 pk0, pk1, pk2, pk3;   // K prefetch: Kh g0, Kh g1, Kl g0, Kl g1
  short8 pv0, pv1, pv2, pv3;   // V prefetch: Vh sd, Vh sd+1, Vl sd, Vl sd+1

  auto loadRegs = [&](int t) {
    const long long kb0 = (tok0 + t * 64 + kr0) * kD + hoff + kc0 * 8;
    const long long kb1 = (tok0 + t * 64 + kr1) * kD + hoff + kc1 * 8;
    pk0 = *(const short8*)(Kh + kb0);
    pk1 = *(const short8*)(Kh + kb1);
    pk2 = *(const short8*)(Kl + kb0);
    pk3 = *(const short8*)(Kl + kb1);
    const long long vb = (tok0 + t * 64 + srow) * kD + hoff + sd * 8;
    pv0 = *(const short8*)(Vh + vb);
    pv1 = *(const short8*)(Vh + vb + 8);
    pv2 = *(const short8*)(Vl + vb);
    pv3 = *(const short8*)(Vl + vb + 8);
  };

  loadRegs(0);

#pragma unroll 1
  for (int t = 0; t < 16; t++) {
    if (t) __syncthreads();            // prev tile's LDS reads done
    // K: linear b128 writes (conflict-free)
    *(short8*)((u16*)Ksh + g0i * 8) = pk0;
    *(short8*)((u16*)Ksh + g1i * 8) = pk1;
    *(short8*)((u16*)Ksl + g0i * 8) = pk2;
    *(short8*)((u16*)Ksl + g1i * 8) = pk3;
    // V: transposed scalar writes, key8 swizzle (<=2-way per phase)
#pragma unroll
    for (int j = 0; j < 16; j++) {
      const int d = sd * 8 + j;
      const int idx = ((kvg ^ key8(d)) << 3) + kvo;
      Vth[d][idx] = (u16)(j < 8 ? pv0[j] : pv1[j - 8]);
      Vtl[d][idx] = (u16)(j < 8 ? pv2[j] : pv3[j - 8]);
    }
    __syncthreads();                   // staging visible
    if (t + 1 < 16) loadRegs(t + 1);   // T14: prefetch next tile
    // ---- QK^T (3-term split) ----
    f32x4 sa[4];
    sa[0] = z4; sa[1] = z4; sa[2] = z4; sa[3] = z4;
#pragma unroll
    for (int kt = 0; kt < 2; kt++) {
#pragma unroll
      for (int n = 0; n < 4; n++) {
        const int row = n * 16 + l16;
        const int g = (((kt * 4 + quad) ^ key8(row)) << 3);
        short8 bh = *(const short8*)&Ksh[row][g];
        short8 bl = *(const short8*)&Ksl[row][g];
        sa[n] = __builtin_amdgcn_mfma_f32_16x16x32_bf16(qlo[kt], bh, sa[n], 0, 0, 0);
        sa[n] = __builtin_amdgcn_mfma_f32_16x16x32_bf16(qh[kt], bl, sa[n], 0, 0, 0);
        sa[n] = __builtin_amdgcn_mfma_f32_16x16x32_bf16(qh[kt], bh, sa[n], 0, 0, 0);
      }
    }
    // ---- online softmax (rows quad*4+r, cols n*16+l16) ----
    float s_[4][4];
    float pm[4] = {-3e38f, -3e38f, -3e38f, -3e38f};
#pragma unroll
    for (int n = 0; n < 4; n++) {
      const bool mb = maskf[b * kS + t * 64 + n * 16 + l16] != 0.f;
#pragma unroll
      for (int r = 0; r < 4; r++) {
        float v = mb ? -1e30f : sa[n][r] * kScale;
        s_[n][r] = v;
        pm[r] = fmaxf(pm[r], v);
      }
    }
#pragma unroll
    for (int mo = 1; mo < 16; mo <<= 1) {
#pragma unroll
      for (int r = 0; r < 4; r++) pm[r] = fmaxf(pm[r], __shfl_xor(pm[r], mo, 64));
    }
    float alpha[4], rs[4];
#pragma unroll
    for (int r = 0; r < 4; r++) {
      float mn = fmaxf(mrow[r], pm[r]);
      alpha[r] = __expf(mrow[r] - mn);
      mrow[r] = mn;
      rs[r] = 0.f;
    }
#pragma unroll
    for (int n = 0; n < 4; n++) {
#pragma unroll
      for (int r = 0; r < 4; r++) {
        float p = __expf(s_[n][r] - mrow[r]);
        s_[n][r] = p;
        rs[r] += p;
      }
    }
#pragma unroll
    for (int mo = 1; mo < 16; mo <<= 1) {
#pragma unroll
      for (int r = 0; r < 4; r++) rs[r] += __shfl_xor(rs[r], mo, 64);
    }
#pragma unroll
    for (int r = 0; r < 4; r++) {
      lrow[r] = lrow[r] * alpha[r] + rs[r];
#pragma unroll
      for (int n = 0; n < 4; n++) o[n][r] *= alpha[r];
    }
    // ---- write P hi/lo (swizzled, wave-local) ----
#pragma unroll
    for (int n = 0; n < 4; n++) {
      const int cg = n * 2 + (l16 >> 3);
#pragma unroll
      for (int r = 0; r < 4; r++) {
        const int row = quad * 4 + r;
        const int idx = row * 64 + ((cg ^ key8(row)) << 3) + l7;
        u16 hh = f2b(s_[n][r]);
        Ps[wave][0][idx] = hh;
        Ps[wave][1][idx] = f2b(s_[n][r] - b2f(hh));
      }
    }
    __syncthreads();   // drain P writes (+ drains t+1 prefetch, ~2000cy after issue)
    // ---- PV (3-term split) ----
#pragma unroll
    for (int ks = 0; ks < 2; ks++) {
      const int gp = (((ks * 4 + quad) ^ key8(l16)) << 3);
      short8 ph = *(const short8*)&Ps[wave][0][l16 * 64 + gp];
      short8 pl = *(const short8*)&Ps[wave][1][l16 * 64 + gp];
#pragma unroll
      for (int n = 0; n < 4; n++) {
        const int row = n * 16 + l16;
        const int g = (((ks * 4 + quad) ^ key8(row)) << 3);
        short8 vh = *(const short8*)&Vth[row][g];
        short8 vl = *(const short8*)&Vtl[row][g];
        o[n] = __builtin_amdgcn_mfma_f32_16x16x32_bf16(pl, vh, o[n], 0, 0, 0);
        o[n] = __builtin_amdgcn_mfma_f32_16x16x32_bf16(ph, vl, o[n], 0, 0, 0);
        o[n] = __builtin_amdgcn_mfma_f32_16x16x32_bf16(ph, vh, o[n], 0, 0, 0);
      }
    }
  }
  // ---- epilogue: split O write ----
#pragma unroll
  for (int r = 0; r < 4; r++) {
    const float inv = 1.f / lrow[r];
    const long long ob = (q0 + wave * 16 + quad * 4 + r) * kD + hoff;
#pragma unroll
    for (int n = 0; n < 4; n++) {
      float val = o[n][r] * inv;
      u16 hh = f2b(val);
      Oh[ob + n * 16 + l16] = hh;
      Ol[ob + n * 16 + l16] = f2b(val - b2f(hh));
    }
  }
}

// ---------------------------- split repack: W [1024][1024] -> hi/lo frag ----
__global__ __launch_bounds__(256) void splitW_k(const void* s0, const void* s1, const void* s2,
                                                u16* h0, u16* l0, u16* h1, u16* l1,
                                                u16* h2, u16* l2, const int* dflag) {
  const int f32 = dflag[0];
  const void* src = blockIdx.z == 0 ? s0 : (blockIdx.z == 1 ? s1 : s2);
  u16* hi = blockIdx.z == 0 ? h0 : (blockIdx.z == 1 ? h1 : h2);
  u16* lo = blockIdx.z == 0 ? l0 : (blockIdx.z == 1 ? l1 : l2);
  const int gid = blockIdx.x * 256 + threadIdx.x;     // < 131072
  const int n = gid & 1023;
  const int kb8 = gid >> 10;                          // k = kb8*8 + j
  const long long s0i = (long long)kb8 * 8 * 1024 + n;
  short8 h8, l8;
#pragma unroll
  for (int j = 0; j < 8; j++) {
    float v = ldIn(src, s0i + (long long)j * 1024, f32);
    u16 hh = f2b(v);
    h8[j] = (short)hh;
    l8[j] = (short)f2b(v - b2f(hh));
  }
  *(short8*)(hi + (long long)gid * 8) = h8;
  *(short8*)(lo + (long long)gid * 8) = l8;
}

// split repack: A [2048][1024] row-major -> hi/lo row-major bf16
__global__ __launch_bounds__(256) void splitA_k(const void* src, u16* hi, u16* lo,
                                                int forceF32, const int* dflag) {
  const int f32 = forceF32 ? 1 : dflag[0];
  const long long gid = (long long)blockIdx.x * 256 + threadIdx.x;   // < 262144
  float v[8];
  ld8f(src, gid * 8, f32, v);
  short8 h8, l8;
#pragma unroll
  for (int j = 0; j < 8; j++) {
    u16 hh = f2b(v[j]);
    h8[j] = (short)hh;
    l8[j] = (short)f2b(v[j] - b2f(hh));
  }
  *(short8*)(hi + gid * 8) = h8;
  *(short8*)(lo + gid * 8) = l8;
}

// ---------------- fast split-bf16 GEMM: C[2048,1024] = A @ B (NB outputs) ----
// OS=1: write split hi/lo bf16 outputs (C* = hi base, Cl* = lo base).
template <int NB, int OS>
__global__ __launch_bounds__(256) void gemmS_k(const u16* Ah, const u16* Al,
                                               const u16* Bh0, const u16* Bl0,
                                               const u16* Bh1, const u16* Bl1,
                                               const u16* Bh2, const u16* Bl2,
                                               void* C0, void* C1, void* C2,
                                               u16* Cl0, u16* Cl1, u16* Cl2,
                                               const void* bias, const int* dflag) {
  const int lin = blockIdx.y * gridDim.x + blockIdx.x;   // 512 blocks
  const int swz = (lin & 7) * 64 + (lin >> 3);           // XCD chunk (bijective)
  const int tx = swz >> 5, ty = swz & 31;                // x-major within chunk
  const int m0 = ty * 64, n0 = tx * 64;
  const int f32in = dflag[0];

  __shared__ __align__(16) u16 AhS[2][64][32], AlS[2][64][32];
  __shared__ __align__(16) u16 BhS[NB][2][4][64][8], BlS[NB][2][4][64][8];

  const int tid = threadIdx.x, wave = tid >> 6, lane = tid & 63;
  const int wr = wave >> 1, wc = wave & 1, quad = lane >> 4, l16 = lane & 15;

  const long long aOff = (long long)(m0 + (tid >> 2)) * kD + (tid & 3) * 8;
  const long long bOff = ((long long)(tid >> 6) * kD + n0 + (tid & 63)) * 8;
  const u16* pBh[3] = {Bh0, Bh1, Bh2};
  const u16* pBl[3] = {Bl0, Bl1, Bl2};
  void* pC[3] = {C0, C1, C2};
  u16* pCl[3] = {Cl0, Cl1, Cl2};

  f32x4 acc[NB][2][2];
  const f32x4 z4 = {0.f, 0.f, 0.f, 0.f};
#pragma unroll
  for (int i = 0; i < NB; i++) {
    acc[i][0][0] = z4; acc[i][0][1] = z4; acc[i][1][0] = z4; acc[i][1][1] = z4;
  }

  auto stage = [&](int buf, int kb) {
    gll16(Ah + aOff + kb * 32, (char*)&AhS[buf][0][0] + (wave << 10));
    gll16(Al + aOff + kb * 32, (char*)&AlS[buf][0][0] + (wave << 10));
    const long long bo = bOff + (long long)kb * (kD * 32);
#pragma unroll
    for (int i = 0; i < NB; i++) {
      gll16(pBh[i] + bo, (char*)&BhS[i][buf][0][0][0] + (wave << 10));
      gll16(pBl[i] + bo, (char*)&BlS[i][buf][0][0][0] + (wave << 10));
    }
  };

  stage(0, 0);
  __syncthreads();
  for (int kb = 0; kb < kD / 32; kb++) {
    const int cur = kb & 1;
    if (kb + 1 < kD / 32) stage(cur ^ 1, kb + 1);
    short8 ah0 = *(const short8*)&AhS[cur][wr * 32 + l16][quad * 8];
    short8 ah1 = *(const short8*)&AhS[cur][wr * 32 + 16 + l16][quad * 8];
    short8 al0 = *(const short8*)&AlS[cur][wr * 32 + l16][quad * 8];
    short8 al1 = *(const short8*)&AlS[cur][wr * 32 + 16 + l16][quad * 8];
#pragma unroll
    for (int i = 0; i < NB; i++) {
      short8 bh0 = *(const short8*)&BhS[i][cur][quad][wc * 32 + l16][0];
      short8 bh1 = *(const short8*)&BhS[i][cur][quad][wc * 32 + 16 + l16][0];
      short8 bl0 = *(const short8*)&BlS[i][cur][quad][wc * 32 + l16][0];
      short8 bl1 = *(const short8*)&BlS[i][cur][quad][wc * 32 + 16 + l16][0];
      acc[i][0][0] = __builtin_amdgcn_mfma_f32_16x16x32_bf16(al0, bh0, acc[i][0][0], 0, 0, 0);
      acc[i][0][1] = __builtin_amdgcn_mfma_f32_16x16x32_bf16(al0, bh1, acc[i][0][1], 0, 0, 0);
      acc[i][1][0] = __builtin_amdgcn_mfma_f32_16x16x32_bf16(al1, bh0, acc[i][1][0], 0, 0, 0);
      acc[i][1][1] = __builtin_amdgcn_mfma_f32_16x16x32_bf16(al1, bh1, acc[i][1][1], 0, 0, 0);
      acc[i][0][0] = __builtin_amdgcn_mfma_f32_16x16x32_bf16(ah0, bl0, acc[i][0][0], 0, 0, 0);
      acc[i][0][1] = __builtin_amdgcn_mfma_f32_16x16x32_bf16(ah0, bl1, acc[i][0][1], 0, 0, 0);
      acc[i][1][0] = __builtin_amdgcn_mfma_f32_16x16x32_bf16(ah1, bl0, acc[i][1][0], 0, 0, 0);
      acc[i][1][1] = __builtin_amdgcn_mfma_f32_16x16x32_bf16(ah1, bl1, acc[i][1][1], 0, 0, 0);
      acc[i][0][0] = __builtin_amdgcn_mfma_f32_16x16x32_bf16(ah0, bh0, acc[i][0][0], 0, 0, 0);
      acc[i][0][1] = __builtin_amdgcn_mfma_f32_16x16x32_bf16(ah0, bh1, acc[i][0][1], 0, 0, 0);
      acc[i][1][0] = __builtin_amdgcn_mfma_f32_16x16x32_bf16(ah1, bh0, acc[i][1][0], 0, 0, 0);
      acc[i][1][1] = __builtin_amdgcn_mfma_f32_16x16x32_bf16(ah1, bh1, acc[i][1][1], 0, 0, 0);
    }
    __syncthreads();
  }

#pragma unroll
  for (int i = 0; i < NB; i++) {
#pragma unroll
    for (int sm = 0; sm < 2; sm++) {
#pragma unroll
      for (int r = 0; r < 4; r++) {
        int row = m0 + wr * 32 + sm * 16 + quad * 4 + r;
#pragma unroll
        for (int sn = 0; sn < 2; sn++) {
          int col = n0 + wc * 32 + sn * 16 + l16;
          float v = acc[i][sm][sn][r];
          const long long idx = (long long)row * kD + col;
          if (OS) {
            u16 hh = f2b(v);
            ((u16*)pC[i])[idx] = hh;
            pCl[i][idx] = f2b(v - b2f(hh));
          } else {
            if (bias && i == 0) v += ldIn(bias, col, f32in);
            ((float*)pC[i])[idx] = v;
          }
        }
      }
    }
  }
}

// ------------------------------------- MoE weight repack fp32 -> bf16 -------
__global__ __launch_bounds__(256) void cvtW_k(const void* src, u16* dst,
                                              int nSh, int kbSh, const int* dflag) {
  const int f32 = dflag[0];
  const int gid = blockIdx.x * 256 + threadIdx.x;
  const int N = 1 << nSh;
  const int n = gid & (N - 1);
  const int rest = gid >> nSh;
  const int kg = rest & 3;
  const int kb = (rest >> 2) & ((1 << kbSh) - 1);
  const int e = rest >> (2 + kbSh);
  const long long src0 = ((long long)e << (5 + kbSh + nSh)) +
                         (long long)(kb * 32 + kg * 8) * N + n;
  short8 o;
#pragma unroll
  for (int j = 0; j < 8; j++) o[j] = (short)f2b(ldIn(src, src0 + (long long)j * N, f32));
  *(short8*)(dst + (long long)gid * 8) = o;
}

// x2f (fp32) -> bf16, linear layout
__global__ __launch_bounds__(256) void cvtX_k(const float* src, u16* dst) {
  const int gid = blockIdx.x * 256 + threadIdx.x;
  const float* s = src + (long long)gid * 8;
  float4 a = *(const float4*)s, b = *(const float4*)(s + 4);
  short8 o;
  o[0]=(short)f2b(a.x); o[1]=(short)f2b(a.y); o[2]=(short)f2b(a.z); o[3]=(short)f2b(a.w);
  o[4]=(short)f2b(b.x); o[5]=(short)f2b(b.y); o[6]=(short)f2b(b.z); o[7]=(short)f2b(b.w);
  *(short8*)(dst + (long long)gid * 8) = o;
}

// -------------------------------------------- fused MoE W1/W3 + SwiGLU ------
__global__ __launch_bounds__(256) void moe13_k(const u16* Xb, const u16* W1c, const u16* W3c,
                                               const int* counts, const int* offsets,
                                               const int* aidxArr, u16* Hbuf) {
  const int e = blockIdx.z;
  const int Meff = counts[e];
  const int m0 = blockIdx.y * 64;
  if (m0 >= Meff) return;
  const int n0 = blockIdx.x * 128;
  const int csr = offsets[e];

  __shared__ __align__(16) u16 As[2][64][32];
  __shared__ __align__(16) u16 B1s[2][4][128][8];
  __shared__ __align__(16) u16 B3s[2][4][128][8];

  const int tid = threadIdx.x, wave = tid >> 6, lane = tid & 63;
  const int wc = wave, quad = lane >> 4, l16 = lane & 15;

  int grow = m0 + (tid >> 2); if (grow >= Meff) grow = Meff - 1;
  const u16* pA = Xb + (long long)aidxArr[csr + grow] * kD + (tid & 3) * 8;

  const long long ebase = (long long)e * kD * kHID;
  const int g0 = tid, g1 = 256 + tid;
  const long long b0o = ebase + ((long long)(g0 >> 7) * kHID + n0 + (g0 & 127)) * 8;
  const long long b1o = ebase + ((long long)(g1 >> 7) * kHID + n0 + (g1 & 127)) * 8;

  f32x4 acc1[4][2], acc3[4][2];
  const f32x4 z4 = {0.f, 0.f, 0.f, 0.f};
#pragma unroll
  for (int i = 0; i < 4; i++) { acc1[i][0]=z4; acc1[i][1]=z4; acc3[i][0]=z4; acc3[i][1]=z4; }

  auto stage = [&](int buf, int kb) {
    gll16(pA + kb * 32, (char*)&As[buf][0][0] + (wave << 10));
    const long long ko = (long long)kb * (4 * kHID * 8);
    gll16(W1c + b0o + ko, (char*)&B1s[buf][0][0][0] + (wave << 10));
    gll16(W1c + b1o + ko, (char*)&B1s[buf][0][0][0] + 4096 + (wave << 10));
    gll16(W3c + b0o + ko, (char*)&B3s[buf][0][0][0] + (wave << 10));
    gll16(W3c + b1o + ko, (char*)&B3s[buf][0][0][0] + 4096 + (wave << 10));
  };

  stage(0, 0);
  __syncthreads();
  for (int kb = 0; kb < kD / 32; kb++) {
    const int cur = kb & 1;
    if (kb + 1 < kD / 32) stage(cur ^ 1, kb + 1);
    short8 af[4];
#pragma unroll
    for (int sm = 0; sm < 4; sm++)
      af[sm] = *(const short8*)&As[cur][sm * 16 + l16][quad * 8];
    short8 b1f[2], b3f[2];
#pragma unroll
    for (int sn = 0; sn < 2; sn++) {
      b1f[sn] = *(const short8*)&B1s[cur][quad][wc * 32 + sn * 16 + l16][0];
      b3f[sn] = *(const short8*)&B3s[cur][quad][wc * 32 + sn * 16 + l16][0];
    }
#pragma unroll
    for (int sm = 0; sm < 4; sm++) {
#pragma unroll
      for (int sn = 0; sn < 2; sn++) {
        acc1[sm][sn] = __builtin_amdgcn_mfma_f32_16x16x32_bf16(af[sm], b1f[sn], acc1[sm][sn], 0, 0, 0);
        acc3[sm][sn] = __builtin_amdgcn_mfma_f32_16x16x32_bf16(af[sm], b3f[sn], acc3[sm][sn], 0, 0, 0);
      }
    }
    __syncthreads();
  }

#pragma unroll
  for (int sm = 0; sm < 4; sm++) {
#pragma unroll
    for (int r = 0; r < 4; r++) {
      int row = m0 + sm * 16 + quad * 4 + r;
      if (row >= Meff) continue;
#pragma unroll
      for (int sn = 0; sn < 2; sn++) {
        int col = n0 + wc * 32 + sn * 16 + l16;
        float g1 = acc1[sm][sn][r], g3 = acc3[sm][sn][r];
        float h = (g1 / (1.f + __expf(-g1))) * g3;
        Hbuf[(long long)(csr + row) * kHID + col] = f2b(h);
      }
    }
  }
}

// ------------------------------------------------ MoE W2 + scatter ---------
__global__ __launch_bounds__(256) void w2_k(const u16* Hbuf, const u16* W2c,
                                            const int* counts, const int* offsets,
                                            const int* aidxArr, const int* slotArr,
                                            const float* wgtArr, float* contrib) {
  const int e = blockIdx.z;
  const int Meff = counts[e];
  const int m0 = blockIdx.y * 64;
  if (m0 >= Meff) return;
  const int n0 = blockIdx.x * 128;
  const int csr = offsets[e];

  __shared__ __align__(16) u16 As[2][64][32];
  __shared__ __align__(16) u16 Bs[2][4][128][8];

  const int tid = threadIdx.x, wave = tid >> 6, lane = tid & 63;
  const int wc = wave, quad = lane >> 4, l16 = lane & 15;

  int grow = m0 + (tid >> 2); if (grow >= Meff) grow = Meff - 1;
  const u16* pA = Hbuf + (long long)(csr + grow) * kHID + (tid & 3) * 8;

  const long long ebase = (long long)e * kHID * kD;
  const int g0 = tid, g1 = 256 + tid;
  const long long b0o = ebase + ((long long)(g0 >> 7) * kD + n0 + (g0 & 127)) * 8;
  const long long b1o = ebase + ((long long)(g1 >> 7) * kD + n0 + (g1 & 127)) * 8;

  f32x4 acc[4][2];
  const f32x4 z4 = {0.f, 0.f, 0.f, 0.f};
#pragma unroll
  for (int i = 0; i < 4; i++) { acc[i][0] = z4; acc[i][1] = z4; }

  auto stage = [&](int buf, int kb) {
    gll16(pA + kb * 32, (char*)&As[buf][0][0] + (wave << 10));
    const long long ko = (long long)kb * (4 * kD * 8);
    gll16(W2c + b0o + ko, (char*)&Bs[buf][0][0][0] + (wave << 10));
    gll16(W2c + b1o + ko, (char*)&Bs[buf][0][0][0] + 4096 + (wave << 10));
  };

  stage(0, 0);
  __syncthreads();
  for (int kb = 0; kb < kHID / 32; kb++) {
    const int cur = kb & 1;
    if (kb + 1 < kHID / 32) stage(cur ^ 1, kb + 1);
    short8 af[4];
#pragma unroll
    for (int sm = 0; sm < 4; sm++)
      af[sm] = *(const short8*)&As[cur][sm * 16 + l16][quad * 8];
    short8 bf[2];
#pragma unroll
    for (int sn = 0; sn < 2; sn++)
      bf[sn] = *(const short8*)&Bs[cur][quad][wc * 32 + sn * 16 + l16][0];
#pragma unroll
    for (int sm = 0; sm < 4; sm++) {
#pragma unroll
      for (int sn = 0; sn < 2; sn++)
        acc[sm][sn] = __builtin_amdgcn_mfma_f32_16x16x32_bf16(af[sm], bf[sn], acc[sm][sn], 0, 0, 0);
    }
    __syncthreads();
  }

#pragma unroll
  for (int sm = 0; sm < 4; sm++) {
#pragma unroll
    for (int r = 0; r < 4; r++) {
      int row = m0 + sm * 16 + quad * 4 + r;
      if (row >= Meff) continue;
      int a = csr + row;
      int t = aidxArr[a]; int s = slotArr[a]; float w = wgtArr[a];
#pragma unroll
      for (int sn = 0; sn < 2; sn++) {
        int col = n0 + wc * 32 + sn * 16 + l16;
        contrib[((long long)s * kTok + t) * kD + col] = acc[sm][sn][r] * w;
      }
    }
  }
}

// ------------------------------------------------------------ small ops -----
__global__ void maskprep_k(const void* srcm, const void* tgtm, const void* midm,
                           float* srcf, float* padf, float* keepf, float* denom) {
  __shared__ int okInt, okFloat, okBf16;
  int tid = threadIdx.x;
  if (tid == 0) { okInt = 1; okFloat = 1; okBf16 = 1; }
  __syncthreads();
  const unsigned int* wi = (const unsigned int*)tgtm;
  const float* wf = (const float*)tgtm;
  int badI = 0, badF = 0, badB = 0;
  for (int i = tid; i < 512; i += 256) {
    unsigned int w = wi[i];
    if (w > 1u) badI = 1;
    float f = wf[i];
    if (!(f == 0.f || f == 1.f)) badF = 1;
    unsigned int lo = w & 0xffffu, hi = w >> 16;
    if (!((lo == 0 || lo == 0x3f80u) && (hi == 0 || hi == 0x3f80u))) badB = 1;
  }
  if (badI) atomicExch(&okInt, 0);
  if (badF) atomicExch(&okFloat, 0);
  if (badB) atomicExch(&okBf16, 0);
  __syncthreads();
  int mode = okInt ? 0 : (okFloat ? 2 : (okBf16 ? 3 : 1));
  for (int i = tid; i < kTok; i += 256) {
    bool sv, pv, mv;
    if (mode == 0) {
      sv = ((const int*)srcm)[i] != 0; pv = ((const int*)tgtm)[i] != 0; mv = ((const int*)midm)[i] != 0;
    } else if (mode == 2) {
      sv = ((const float*)srcm)[i] != 0.f; pv = ((const float*)tgtm)[i] != 0.f; mv = ((const float*)midm)[i] != 0.f;
    } else if (mode == 3) {
      sv = ((const u16*)srcm)[i] != 0; pv = ((const u16*)tgtm)[i] != 0; mv = ((const u16*)midm)[i] != 0;
    } else {
      sv = ((const unsigned char*)srcm)[i] != 0; pv = ((const unsigned char*)tgtm)[i] != 0; mv = ((const unsigned char*)midm)[i] != 0;
    }
    srcf[i] = sv ? 1.f : 0.f;
    padf[i] = pv ? 1.f : 0.f;
    keepf[i] = (pv || mv) ? 0.f : 1.f;
  }
  __syncthreads();
  if (tid < 2) {
    float s = 0;
    for (int j = 0; j < kS; j++) s += keepf[tid * kS + j];
    denom[tid] = fmaxf(s, 1.f);
  }
}

__global__ __launch_bounds__(256) void ln_k(const float* basef, const void* baseb,
                                            const int* dflag, int baseIsIn,
                                            const float* add1, const float* add2,
                                            const void* g, const void* bb,
                                            float* outf, void* outFinal) {
  const int f32in = dflag[0];
  const int baseF32 = baseIsIn && f32in;
  long long base = (long long)blockIdx.x * kD;
  int tid = threadIdx.x;
  float v[4]; float s = 0;
#pragma unroll
  for (int i = 0; i < 4; i++) {
    int d = tid + i * 256;
    float x = basef ? basef[base + d] : ldIn(baseb, base + d, baseF32);
    if (add1) x += add1[base + d];
    if (add2) x += add2[base + d];
    v[i] = x; s += x;
  }
  float mean = blockReduceSum(s) * (1.f / kD);
  float q = 0;
#pragma unroll
  for (int i = 0; i < 4; i++) { float d0 = v[i] - mean; q += d0 * d0; }
  float var = blockReduceSum(q) * (1.f / kD);
  float rstd = rsqrtf(var + 1e-5f);
#pragma unroll
  for (int i = 0; i < 4; i++) {
    int d = tid + i * 256;
    float y = (v[i] - mean) * rstd * ldIn(g, d, f32in) + ldIn(bb, d, f32in);
    if (outf) outf[base + d] = y;
    if (outFinal) stOut(outFinal, base + d, y, f32in);
  }
}

__global__ __launch_bounds__(256) void router_k(const float* xf, const void* gw, void* outBase,
                                                int* sel, float* wsel, int* counts,
                                                const int* dflag) {
  const int f32in = dflag[0];
  int wv = threadIdx.x >> 6, lane = threadIdx.x & 63;
  int t = blockIdx.x * 4 + wv;
  const float* xr = xf + (long long)t * kD;
  float acc[8];
#pragma unroll
  for (int e = 0; e < 8; e++) acc[e] = 0.f;
  for (int d = lane; d < kD; d += 64) {
    float xv = xr[d];
    float gv[8];
    ld8f(gw, (long long)d * 8, f32in, gv);
#pragma unroll
    for (int e = 0; e < 8; e++) acc[e] += xv * gv[e];
  }
#pragma unroll
  for (int o = 32; o; o >>= 1) {
#pragma unroll
    for (int e = 0; e < 8; e++) acc[e] += __shfl_down(acc[e], o, 64);
  }
  if (lane == 0) {
    float mx = acc[0];
    for (int e = 1; e < 8; e++) mx = fmaxf(mx, acc[e]);
    float p[8], sum = 0;
    for (int e = 0; e < 8; e++) { p[e] = expf(acc[e] - mx); sum += p[e]; }
    float inv = 1.f / sum;
    for (int e = 0; e < 8; e++) {
      p[e] *= inv;
      stOut(outBase, kOutProbs + (long long)t * 8 + e, p[e], f32in);
    }
    int e0 = 0; for (int e = 1; e < 8; e++) if (p[e] > p[e0]) e0 = e;
    int e1 = -1; for (int e = 0; e < 8; e++) { if (e == e0) continue; if (e1 < 0 || p[e] > p[e1]) e1 = e; }
    float s2 = p[e0] + p[e1];
    sel[t * 2] = e0; sel[t * 2 + 1] = e1;
    wsel[t * 2] = p[e0] / s2; wsel[t * 2 + 1] = p[e1] / s2;
    atomicAdd(&counts[e0], 1); atomicAdd(&counts[e1], 1);
  }
}

__global__ void offsets_k(const int* counts, int* offsets) {
  if (threadIdx.x == 0) {
    int s = 0;
    for (int e = 0; e < kE; e++) { offsets[e] = s; s += counts[e]; }
    offsets[kE] = s;
  }
}

__global__ void place_k(const int* sel, const float* wsel, const int* offsets, int* fill,
                        int* aidxArr, int* slotArr, float* wgtArr) {
  int t = blockIdx.x * 256 + threadIdx.x;
  if (t >= kTok) return;
  for (int s = 0; s < 2; s++) {
    int e = sel[t * 2 + s];
    int pos = offsets[e] + atomicAdd(&fill[e], 1);
    aidxArr[pos] = t; slotArr[pos] = s; wgtArr[pos] = wsel[t * 2 + s];
  }
}

__global__ void meanacc_k(const int* counts, const int* offsets, const int* aidxArr,
                          const int* slotArr, const float* keepf, const float* contrib,
                          float* meanAcc) {
  int e = blockIdx.x, dc = blockIdx.y, ch = blockIdx.z;
  int d = dc * 128 + threadIdx.x;
  int cnt = counts[e], off = offsets[e];
  int per = (cnt + 15) / 16;
  int i0 = ch * per, i1 = i0 + per; if (i1 > cnt) i1 = cnt;
  float a0 = 0, a1 = 0;
  for (int i = i0; i < i1; i++) {
    int a = off + i; int t = aidxArr[a];
    if (keepf[t] != 0.f) {
      float v = contrib[((long long)slotArr[a] * kTok + t) * kD + d];
      if (t < kS) a0 += v; else a1 += v;
    }
  }
  if (a0 != 0.f) atomicAdd(&meanAcc[(e * 2 + 0) * kD + d], a0);
  if (a1 != 0.f) atomicAdd(&meanAcc[(e * 2 + 1) * kD + d], a1);
}

__global__ __launch_bounds__(256) void dots_k(const float* meanAcc, const void* cls_w,
                                              const float* denom, float* dots,
                                              const int* dflag) {
  const int f32in = dflag[0];
  int eb = blockIdx.x;
  int b = eb & 1;
  float s = 0;
  for (int d = threadIdx.x; d < kD; d += 256)
    s += meanAcc[(long long)eb * kD + d] * ldIn(cls_w, d, f32in);
  s = blockReduceSum(s);
  if (threadIdx.x == 0) dots[eb] = s / denom[b];
}

__global__ void final_logits_k(const float* dots, const void* cls_b, void* outBase,
                               const int* dflag) {
  const int f32in = dflag[0];
  int i = threadIdx.x;
  if (i < kE * kB) {
    int e = i >> 1, b = i & 1;
    float s = ldIn(cls_b, 0, f32in);
    for (int e2 = 0; e2 <= e; e2++) s += dots[e2 * 2 + b];
    stOut(outBase, kOutLogits + e * kB + b, s, f32in);
  }
}

// ------------------------------------------------------------------ host ----
extern "C" void kernel_launch(void* const* d_in, const int* in_sizes, int n_in,
                              void* d_out, int out_size, void* d_ws, size_t ws_size,
                              hipStream_t stream) {
  (void)in_sizes; (void)n_in; (void)out_size; (void)ws_size;

  const void* x_in  = d_in[0];
  const void* enc   = d_in[1];
  const void* srcm = d_in[2];
  const void* tgtm = d_in[3];
  const void* midm = d_in[4];
  const void* ln1g = d_in[5];  const void* ln1b = d_in[6];
  const void* ln2g = d_in[7];  const void* ln2b = d_in[8];
  const void* ln3g = d_in[9];  const void* ln3b = d_in[10];
  const void* sa_wq = d_in[11]; const void* sa_wk = d_in[12];
  const void* sa_wv = d_in[13]; const void* sa_wo = d_in[14];
  const void* sa_bo = d_in[15];
  const void* ca_wq = d_in[16]; const void* ca_wk = d_in[17];
  const void* ca_wv = d_in[18]; const void* ca_wo = d_in[19];
  const void* ca_bo = d_in[20];
  const void* gate_w = d_in[21];
  const void* cls_w  = d_in[22]; const void* cls_b = d_in[23];
  const void* moe_w1 = d_in[24];
  const void* moe_w2 = d_in[25];
  const void* moe_w3 = d_in[26];

  char* wp = (char*)d_ws;
  size_t off = 0;
  auto alloc = [&](size_t bytes) -> void* {
    void* p = wp + off; off = (off + bytes + 255) & ~(size_t)255; return p;
  };
  float* scFP = (float*)alloc((size_t)16 * kS * kS * 4);          // 64 MiB scratch
  u16*   Hbuf = (u16*)scFP;                                        // [0,16) MiB (MoE)
  float* contrib = (float*)((char*)scFP + (size_t)2 * kTok * kHID * 2); // [16,32) MiB
  float* qf    = (float*)alloc((size_t)kTok * kD * 4);
  float* kf    = (float*)alloc((size_t)kTok * kD * 4);
  float* vf    = (float*)alloc((size_t)kTok * kD * 4);
  float* attnof= (float*)alloc((size_t)kTok * kD * 4);
  float* obuf  = (float*)alloc((size_t)kTok * kD * 4);
  float* x1f   = (float*)alloc((size_t)kTok * kD * 4);
  float* x2f   = (float*)alloc((size_t)kTok * kD * 4);
  float* meanAcc = (float*)alloc((size_t)kE * kB * kD * 4);
  float* srcf = (float*)alloc(kTok * 4);
  float* padf = (float*)alloc(kTok * 4);
  float* keepf = (float*)alloc(kTok * 4);
  float* denom = (float*)alloc(2 * 4);
  int* counts = (int*)alloc(256); int* fill = counts + 8;
  int* offsets = (int*)alloc(256);
  int* sel = (int*)alloc(kTok * 2 * 4);
  float* wsel = (float*)alloc(kTok * 2 * 4);
  int* aidxArr = (int*)alloc(2 * kTok * 4);
  int* slotArr = (int*)alloc(2 * kTok * 4);
  float* wgtArr = (float*)alloc(2 * kTok * 4);
  float* dots = (float*)alloc(256);
  int* dflag = (int*)alloc(256);

  // Split scratch (dead-at-the-time regions):
  u16* WH0 = (u16*)x2f;
  u16* WL0 = WH0 + (1 << 20);
  u16* WH1 = WL0 + (1 << 20);
  u16* WL1 = WH1 + (1 << 20);
  u16* WH2 = (u16*)x1f;
  u16* WL2 = WH2 + (1 << 20);
  u16* AH  = (u16*)scFP;
  u16* AL  = AH + (2 << 20);

  // Split Q/K/V/O (live in qf/kf/vf/attnof; hi then lo, 4 MiB each):
  u16* Qh = (u16*)qf;     u16* Ql = Qh + (2 << 20);
  u16* Kh = (u16*)kf;     u16* Kl = Kh + (2 << 20);
  u16* Vh = (u16*)vf;     u16* Vl = Vh + (2 << 20);
  u16* Oh = (u16*)attnof; u16* Ol = Oh + (2 << 20);

  // MoE repack buffers:
  u16* W1c = (u16*)qf;                                     // qf..attnof 32 MiB
  u16* W2c = (u16*)qf;
  u16* W3c = (u16*)((char*)scFP + ((size_t)32 << 20));
  u16* Xb  = (u16*)obuf;

  hipMemsetAsync(counts, 0, 64, stream);
  hipMemsetAsync(meanAcc, 0, (size_t)kE * kB * kD * 4, stream);
  detect_k<<<1, 256, 0, stream>>>(x_in, dflag);
  maskprep_k<<<1, 256, 0, stream>>>(srcm, tgtm, midm, srcf, padf, keepf, denom);

  const dim3 gGrid(16, 32);
  const dim3 aGrid(kS / 64, 32);

  // ---- self attention ----
  splitA_k<<<1024, 256, 0, stream>>>(x_in, AH, AL, 0, dflag);
  splitW_k<<<dim3(512, 1, 3), 256, 0, stream>>>(sa_wq, sa_wk, sa_wv,
      WH0, WL0, WH1, WL1, WH2, WL2, dflag);
  gemmS_k<3, 1><<<gGrid, 256, 0, stream>>>(AH, AL, WH0, WL0, WH1, WL1, WH2, WL2,
      Qh, Kh, Vh, Ql, Kl, Vl, nullptr, dflag);
  fattn_k<<<aGrid, 256, 0, stream>>>(Qh, Ql, Kh, Kl, Vh, Vl, padf, Oh, Ol);
  splitW_k<<<dim3(512, 1, 1), 256, 0, stream>>>(sa_wo, nullptr, nullptr,
      WH0, WL0, nullptr, nullptr, nullptr, nullptr, dflag);
  gemmS_k<1, 0><<<gGrid, 256, 0, stream>>>(Oh, Ol, WH0, WL0, WH0, WL0, WH0, WL0,
      obuf, obuf, obuf, nullptr, nullptr, nullptr, sa_bo, dflag);
  ln_k<<<kTok, 256, 0, stream>>>(nullptr, x_in, dflag, 1, obuf, nullptr, ln1g, ln1b, x1f, nullptr);

  // ---- cross attention ----
  splitA_k<<<1024, 256, 0, stream>>>(x1f, AH, AL, 1, dflag);
  splitW_k<<<dim3(512, 1, 1), 256, 0, stream>>>(ca_wq, nullptr, nullptr,
      WH0, WL0, nullptr, nullptr, nullptr, nullptr, dflag);
  gemmS_k<1, 1><<<gGrid, 256, 0, stream>>>(AH, AL, WH0, WL0, WH0, WL0, WH0, WL0,
      Qh, Qh, Qh, Ql, Ql, Ql, nullptr, dflag);
  splitA_k<<<1024, 256, 0, stream>>>(enc, AH, AL, 0, dflag);
  splitW_k<<<dim3(512, 1, 2), 256, 0, stream>>>(ca_wk, ca_wv, nullptr,
      WH0, WL0, WH1, WL1, nullptr, nullptr, dflag);
  gemmS_k<2, 1><<<gGrid, 256, 0, stream>>>(AH, AL, WH0, WL0, WH1, WL1, WH0, WL0,
      Kh, Vh, Vh, Kl, Vl, Vl, nullptr, dflag);
  fattn_k<<<aGrid, 256, 0, stream>>>(Qh, Ql, Kh, Kl, Vh, Vl, srcf, Oh, Ol);
  splitW_k<<<dim3(512, 1, 1), 256, 0, stream>>>(ca_wo, nullptr, nullptr,
      WH0, WL0, nullptr, nullptr, nullptr, nullptr, dflag);
  gemmS_k<1, 0><<<gGrid, 256, 0, stream>>>(Oh, Ol, WH0, WL0, WH0, WL0, WH0, WL0,
      obuf, obuf, obuf, nullptr, nullptr, nullptr, ca_bo, dflag);
  ln_k<<<kTok, 256, 0, stream>>>(x1f, nullptr, dflag, 0, obuf, nullptr, ln2g, ln2b, x2f, nullptr);

  // ---- MoE ----
  router_k<<<kTok / 4, 256, 0, stream>>>(x2f, gate_w, d_out, sel, wsel, counts, dflag);
  offsets_k<<<1, 64, 0, stream>>>(counts, offsets);
  place_k<<<kTok / 256, 256, 0, stream>>>(sel, wsel, offsets, fill, aidxArr, slotArr, wgtArr);

  cvtX_k<<<kTok * kD / (8 * 256), 256, 0, stream>>>(x2f, Xb);
  const int wGrid = (kE * kD * kHID / 8) / 256;   // 8192
  cvtW_k<<<wGrid, 256, 0, stream>>>(moe_w1, W1c, 11, 5, dflag);  // K=1024,N=2048
  cvtW_k<<<wGrid, 256, 0, stream>>>(moe_w3, W3c, 11, 5, dflag);

  moe13_k<<<dim3(kHID / 128, kTok / 64, kE), 256, 0, stream>>>(
      Xb, W1c, W3c, counts, offsets, aidxArr, Hbuf);

  cvtW_k<<<wGrid, 256, 0, stream>>>(moe_w2, W2c, 10, 6, dflag);  // K=2048,N=1024

  w2_k<<<dim3(kD / 128, kTok / 64, kE), 256, 0, stream>>>(
      Hbuf, W2c, counts, offsets, aidxArr, slotArr, wgtArr, contrib);

  meanacc_k<<<dim3(kE, kD / 128, 16), 128, 0, stream>>>(counts, offsets, aidxArr, slotArr, keepf, contrib, meanAcc);
  dots_k<<<kE * kB, 256, 0, stream>>>(meanAcc, cls_w, denom, dots, dflag);
  final_logits_k<<<1, 64, 0, stream>>>(dots, cls_b, d_out, dflag);
  ln_k<<<kTok, 256, 0, stream>>>(x2f, nullptr, dflag, 0, contrib, contrib + (size_t)kTok * kD, ln3g, ln3b, nullptr, d_out);
}

// Round 7
// 880.564 us; speedup vs baseline: 1.5067x; 1.0215x over previous
//
#include <hip/hip_runtime.h>
#include <hip/hip_bf16.h>
#include <math.h>

constexpr int kB   = 2;
constexpr int kS   = 1024;
constexpr int kD   = 1024;
constexpr int kH   = 16;
constexpr int kDH  = 64;
constexpr int kHID = 2048;
constexpr int kE   = 8;
constexpr int kTok = kB * kS;         // 2048
constexpr float kScale = 0.125f;
constexpr long long kOutLogits = (long long)kTok * kD;
constexpr long long kOutProbs  = kOutLogits + kE * kB;

using u16 = unsigned short;
typedef __attribute__((ext_vector_type(8))) short short8;
typedef __attribute__((ext_vector_type(4))) float f32x4;

__device__ __forceinline__ float b2f(u16 u) {
  union { unsigned int i; float f; } c; c.i = ((unsigned int)u) << 16; return c.f;
}
__device__ __forceinline__ u16 f2b(float f) {
  __hip_bfloat16 h = __float2bfloat16(f);
  u16 u; __builtin_memcpy(&u, &h, 2); return u;
}
__device__ __forceinline__ float ldIn(const void* p, long long i, int f32) {
  return f32 ? ((const float*)p)[i] : b2f(((const u16*)p)[i]);
}
__device__ __forceinline__ void ld8f(const void* p, long long i, int f32, float v[8]) {
  if (f32) {
    const float* fp = (const float*)p + i;
    float4 a = *(const float4*)fp, b = *(const float4*)(fp + 4);
    v[0]=a.x; v[1]=a.y; v[2]=a.z; v[3]=a.w; v[4]=b.x; v[5]=b.y; v[6]=b.z; v[7]=b.w;
  } else {
    short8 s = *(const short8*)((const u16*)p + i);
#pragma unroll
    for (int j = 0; j < 8; j++) v[j] = b2f((u16)s[j]);
  }
}
__device__ __forceinline__ void stOut(void* base, long long i, float v, int f32) {
  if (f32) ((float*)base)[i] = v; else ((u16*)base)[i] = f2b(v);
}

// async global->LDS, 16B per lane. LDS dest is wave-uniform base + lane*16.
__device__ __forceinline__ void gll16(const void* g, void* l) {
  __builtin_amdgcn_global_load_lds(
      (__attribute__((address_space(1))) unsigned int*)(unsigned long long)g,
      (__attribute__((address_space(3))) unsigned int*)l, 16, 0, 0);
}

__device__ __forceinline__ float blockReduceSum(float v) {
  __shared__ float sh[4];
  int lane = threadIdx.x & 63, wv = threadIdx.x >> 6;
#pragma unroll
  for (int o = 32; o; o >>= 1) v += __shfl_down(v, o, 64);
  __syncthreads();
  if (lane == 0) sh[wv] = v;
  __syncthreads();
  return sh[0] + sh[1] + sh[2] + sh[3];
}
__device__ __forceinline__ float blockReduceMax(float v) {
  __shared__ float sh[4];
  int lane = threadIdx.x & 63, wv = threadIdx.x >> 6;
#pragma unroll
  for (int o = 32; o; o >>= 1) v = fmaxf(v, __shfl_down(v, o, 64));
  __syncthreads();
  if (lane == 0) sh[wv] = v;
  __syncthreads();
  return fmaxf(fmaxf(sh[0], sh[1]), fmaxf(sh[2], sh[3]));
}

// ------------------------------------------------------------- detect -------
__global__ void detect_k(const void* x, int* dflag) {
  __shared__ int sg, st;
  int tid = threadIdx.x;
  if (tid == 0) { sg = 0; st = 0; }
  __syncthreads();
  const unsigned int* w = (const unsigned int*)x;
  int good = 0, tot = 0;
  for (int i = tid; i < 1024; i += 256) {
    unsigned int lo = w[i] & 0xffffu;
    if (lo) {
      tot++;
      unsigned int e = (lo >> 7) & 0xffu;
      if (e >= 97 && e <= 159) good++;
    }
  }
  atomicAdd(&sg, good); atomicAdd(&st, tot);
  __syncthreads();
  if (tid == 0) dflag[0] = (sg * 10 < st * 9) ? 1 : 0;
}

// --------------------------------------------- fused flash attention --------
// O = softmax(Q K^T * scale, mask) V ; all operands pre-split hi/lo bf16.
// 1D grid 512; decode so each XCD (lin&7) owns 4 heads x all 16 q-tiles:
// K/V slice (4 x 512KB = 2MB) stays L2-resident -> L3 traffic 131MB -> ~16MB.
__device__ __forceinline__ int key8(int r) { return (r ^ (r >> 3)) & 7; }

__global__ __launch_bounds__(256) void fattn_k(const u16* Qh, const u16* Ql,
                                               const u16* Kh, const u16* Kl,
                                               const u16* Vh, const u16* Vl,
                                               const float* maskf,
                                               u16* Oh, u16* Ol) {
  const int lin = blockIdx.x;
  const int xc = lin & 7, li = lin >> 3;          // li in [0,64)
  const int bh = xc * 4 + (li >> 4);              // 4 heads per XCD
  const int qt = li & 15;
  const int b = bh >> 4, hoff = (bh & 15) * 64;
  const int tid = threadIdx.x, wave = tid >> 6, lane = tid & 63;
  const int quad = lane >> 4, l16 = lane & 15, l7 = lane & 7;

  __shared__ __align__(16) u16 Ksh[64][64], Ksl[64][64];   // [kv][d-swz]
  __shared__ __align__(16) u16 Vth[64][64], Vtl[64][64];   // [d][kv-swz]
  __shared__ __align__(16) u16 Ps[4][2][1024];             // per-wave P hi/lo

  const long long tok0 = (long long)b * kS;
  const long long q0 = tok0 + qt * 64;

  // Q fragments (direct split loads; zero conversion)
  short8 qh[2], qlo[2];
  {
    const long long qoff = (q0 + wave * 16 + l16) * kD + hoff;
#pragma unroll
    for (int kt = 0; kt < 2; kt++) {
      qh[kt]  = *(const short8*)(Qh + qoff + kt * 32 + quad * 8);
      qlo[kt] = *(const short8*)(Ql + qoff + kt * 32 + quad * 8);
    }
  }

  // K staging: LDS granule g (linear) <- global granule (g&7)^key8(g>>3)
  const int g0i = tid, g1i = 256 + tid;
  const int kr0 = g0i >> 3, kc0 = (g0i & 7) ^ key8(g0i >> 3);
  const int kr1 = g1i >> 3, kc1 = (g1i & 7) ^ key8(g1i >> 3);
  // V staging: thread owns row srow, d-granules sd, sd+1 (transposed write)
  const int srow = tid >> 2, sd = (tid & 3) * 2;
  const int kvg = srow >> 3, kvo = srow & 7;

  f32x4 o[4];
  const f32x4 z4 = {0.f, 0.f, 0.f, 0.f};
  o[0] = z4; o[1] = z4; o[2] = z4; o[3] = z4;
  float mrow[4] = {-3e38f, -3e38f, -3e38f, -3e38f};
  float lrow[4] = {0.f, 0.f, 0.f, 0.f};

  short8 pk0, pk1, pk2, pk3;
  short8 pv0, pv1, pv2, pv3;

  auto loadRegs = [&](int t) {
    const long long kb0 = (tok0 + t * 64 + kr0) * kD + hoff + kc0 * 8;
    const long long kb1 = (tok0 + t * 64 + kr1) * kD + hoff + kc1 * 8;
    pk0 = *(const short8*)(Kh + kb0);
    pk1 = *(const short8*)(Kh + kb1);
    pk2 = *(const short8*)(Kl + kb0);
    pk3 = *(const short8*)(Kl + kb1);
    const long long vb = (tok0 + t * 64 + srow) * kD + hoff + sd * 8;
    pv0 = *(const short8*)(Vh + vb);
    pv1 = *(const short8*)(Vh + vb + 8);
    pv2 = *(const short8*)(Vl + vb);
    pv3 = *(const short8*)(Vl + vb + 8);
  };

  loadRegs(0);

#pragma unroll 1
  for (int t = 0; t < 16; t++) {
    if (t) __syncthreads();
    *(short8*)((u16*)Ksh + g0i * 8) = pk0;
    *(short8*)((u16*)Ksh + g1i * 8) = pk1;
    *(short8*)((u16*)Ksl + g0i * 8) = pk2;
    *(short8*)((u16*)Ksl + g1i * 8) = pk3;
#pragma unroll
    for (int j = 0; j < 16; j++) {
      const int d = sd * 8 + j;
      const int idx = ((kvg ^ key8(d)) << 3) + kvo;
      Vth[d][idx] = (u16)(j < 8 ? pv0[j] : pv1[j - 8]);
      Vtl[d][idx] = (u16)(j < 8 ? pv2[j] : pv3[j - 8]);
    }
    __syncthreads();
    if (t + 1 < 16) loadRegs(t + 1);
    // ---- QK^T (3-term split) ----
    f32x4 sa[4];
    sa[0] = z4; sa[1] = z4; sa[2] = z4; sa[3] = z4;
#pragma unroll
    for (int kt = 0; kt < 2; kt++) {
#pragma unroll
      for (int n = 0; n < 4; n++) {
        const int row = n * 16 + l16;
        const int g = (((kt * 4 + quad) ^ key8(row)) << 3);
        short8 bh_ = *(const short8*)&Ksh[row][g];
        short8 bl_ = *(const short8*)&Ksl[row][g];
        sa[n] = __builtin_amdgcn_mfma_f32_16x16x32_bf16(qlo[kt], bh_, sa[n], 0, 0, 0);
        sa[n] = __builtin_amdgcn_mfma_f32_16x16x32_bf16(qh[kt], bl_, sa[n], 0, 0, 0);
        sa[n] = __builtin_amdgcn_mfma_f32_16x16x32_bf16(qh[kt], bh_, sa[n], 0, 0, 0);
      }
    }
    // ---- online softmax ----
    float s_[4][4];
    float pm[4] = {-3e38f, -3e38f, -3e38f, -3e38f};
#pragma unroll
    for (int n = 0; n < 4; n++) {
      const bool mb = maskf[b * kS + t * 64 + n * 16 + l16] != 0.f;
#pragma unroll
      for (int r = 0; r < 4; r++) {
        float v = mb ? -1e30f : sa[n][r] * kScale;
        s_[n][r] = v;
        pm[r] = fmaxf(pm[r], v);
      }
    }
#pragma unroll
    for (int mo = 1; mo < 16; mo <<= 1) {
#pragma unroll
      for (int r = 0; r < 4; r++) pm[r] = fmaxf(pm[r], __shfl_xor(pm[r], mo, 64));
    }
    float alpha[4], rs[4];
#pragma unroll
    for (int r = 0; r < 4; r++) {
      float mn = fmaxf(mrow[r], pm[r]);
      alpha[r] = __expf(mrow[r] - mn);
      mrow[r] = mn;
      rs[r] = 0.f;
    }
#pragma unroll
    for (int n = 0; n < 4; n++) {
#pragma unroll
      for (int r = 0; r < 4; r++) {
        float p = __expf(s_[n][r] - mrow[r]);
        s_[n][r] = p;
        rs[r] += p;
      }
    }
#pragma unroll
    for (int mo = 1; mo < 16; mo <<= 1) {
#pragma unroll
      for (int r = 0; r < 4; r++) rs[r] += __shfl_xor(rs[r], mo, 64);
    }
#pragma unroll
    for (int r = 0; r < 4; r++) {
      lrow[r] = lrow[r] * alpha[r] + rs[r];
#pragma unroll
      for (int n = 0; n < 4; n++) o[n][r] *= alpha[r];
    }
    // ---- write P hi/lo (swizzled, wave-local) ----
#pragma unroll
    for (int n = 0; n < 4; n++) {
      const int cg = n * 2 + (l16 >> 3);
#pragma unroll
      for (int r = 0; r < 4; r++) {
        const int row = quad * 4 + r;
        const int idx = row * 64 + ((cg ^ key8(row)) << 3) + l7;
        u16 hh = f2b(s_[n][r]);
        Ps[wave][0][idx] = hh;
        Ps[wave][1][idx] = f2b(s_[n][r] - b2f(hh));
      }
    }
    __syncthreads();   // drain P writes (plain barrier)
    // ---- PV (3-term split) ----
#pragma unroll
    for (int ks = 0; ks < 2; ks++) {
      const int gp = (((ks * 4 + quad) ^ key8(l16)) << 3);
      short8 ph = *(const short8*)&Ps[wave][0][l16 * 64 + gp];
      short8 pl = *(const short8*)&Ps[wave][1][l16 * 64 + gp];
#pragma unroll
      for (int n = 0; n < 4; n++) {
        const int row = n * 16 + l16;
        const int g = (((ks * 4 + quad) ^ key8(row)) << 3);
        short8 vh = *(const short8*)&Vth[row][g];
        short8 vl = *(const short8*)&Vtl[row][g];
        o[n] = __builtin_amdgcn_mfma_f32_16x16x32_bf16(pl, vh, o[n], 0, 0, 0);
        o[n] = __builtin_amdgcn_mfma_f32_16x16x32_bf16(ph, vl, o[n], 0, 0, 0);
        o[n] = __builtin_amdgcn_mfma_f32_16x16x32_bf16(ph, vh, o[n], 0, 0, 0);
      }
    }
  }
  // ---- epilogue: split O write ----
#pragma unroll
  for (int r = 0; r < 4; r++) {
    const float inv = 1.f / lrow[r];
    const long long ob = (q0 + wave * 16 + quad * 4 + r) * kD + hoff;
#pragma unroll
    for (int n = 0; n < 4; n++) {
      float val = o[n][r] * inv;
      u16 hh = f2b(val);
      Oh[ob + n * 16 + l16] = hh;
      Ol[ob + n * 16 + l16] = f2b(val - b2f(hh));
    }
  }
}

// ---------------------------- split repack: W [1024][1024] -> hi/lo frag ----
__global__ __launch_bounds__(256) void splitW_k(const void* s0, const void* s1, const void* s2,
                                                u16* h0, u16* l0, u16* h1, u16* l1,
                                                u16* h2, u16* l2, const int* dflag) {
  const int f32 = dflag[0];
  const void* src = blockIdx.z == 0 ? s0 : (blockIdx.z == 1 ? s1 : s2);
  u16* hi = blockIdx.z == 0 ? h0 : (blockIdx.z == 1 ? h1 : h2);
  u16* lo = blockIdx.z == 0 ? l0 : (blockIdx.z == 1 ? l1 : l2);
  const int gid = blockIdx.x * 256 + threadIdx.x;     // < 131072
  const int n = gid & 1023;
  const int kb8 = gid >> 10;                          // k = kb8*8 + j
  const long long s0i = (long long)kb8 * 8 * 1024 + n;
  short8 h8, l8;
#pragma unroll
  for (int j = 0; j < 8; j++) {
    float v = ldIn(src, s0i + (long long)j * 1024, f32);
    u16 hh = f2b(v);
    h8[j] = (short)hh;
    l8[j] = (short)f2b(v - b2f(hh));
  }
  *(short8*)(hi + (long long)gid * 8) = h8;
  *(short8*)(lo + (long long)gid * 8) = l8;
}

// split repack: A [2048][1024] row-major -> hi/lo row-major bf16
__global__ __launch_bounds__(256) void splitA_k(const void* src, u16* hi, u16* lo,
                                                int forceF32, const int* dflag) {
  const int f32 = forceF32 ? 1 : dflag[0];
  const long long gid = (long long)blockIdx.x * 256 + threadIdx.x;   // < 262144
  float v[8];
  ld8f(src, gid * 8, f32, v);
  short8 h8, l8;
#pragma unroll
  for (int j = 0; j < 8; j++) {
    u16 hh = f2b(v[j]);
    h8[j] = (short)hh;
    l8[j] = (short)f2b(v[j] - b2f(hh));
  }
  *(short8*)(hi + gid * 8) = h8;
  *(short8*)(lo + gid * 8) = l8;
}

// ---------------- fast split-bf16 GEMM: C[2048,1024] = A @ B (NB outputs) ----
// OS=1: write split hi/lo bf16 outputs (C* = hi base, Cl* = lo base).
// 2D-blocked XCD swizzle: each XCD (lin&7) owns an 8ty x 8tx region ->
// A-slice 2MB + B-slice 2MB both L2-resident; A L3-traffic cut ~4x.
template <int NB, int OS>
__global__ __launch_bounds__(256) void gemmS_k(const u16* Ah, const u16* Al,
                                               const u16* Bh0, const u16* Bl0,
                                               const u16* Bh1, const u16* Bl1,
                                               const u16* Bh2, const u16* Bl2,
                                               void* C0, void* C1, void* C2,
                                               u16* Cl0, u16* Cl1, u16* Cl2,
                                               const void* bias, const int* dflag) {
  const int lin = blockIdx.y * gridDim.x + blockIdx.x;   // 512 blocks
  const int xc = lin & 7, li = lin >> 3;                 // li in [0,64)
  const int ty = (xc & 3) * 8 + (li >> 3);               // [0,32)
  const int tx = (xc >> 2) * 8 + (li & 7);               // [0,16)
  const int m0 = ty * 64, n0 = tx * 64;
  const int f32in = dflag[0];

  __shared__ __align__(16) u16 AhS[2][64][32], AlS[2][64][32];
  __shared__ __align__(16) u16 BhS[NB][2][4][64][8], BlS[NB][2][4][64][8];

  const int tid = threadIdx.x, wave = tid >> 6, lane = tid & 63;
  const int wr = wave >> 1, wc = wave & 1, quad = lane >> 4, l16 = lane & 15;

  const long long aOff = (long long)(m0 + (tid >> 2)) * kD + (tid & 3) * 8;
  const long long bOff = ((long long)(tid >> 6) * kD + n0 + (tid & 63)) * 8;
  const u16* pBh[3] = {Bh0, Bh1, Bh2};
  const u16* pBl[3] = {Bl0, Bl1, Bl2};
  void* pC[3] = {C0, C1, C2};
  u16* pCl[3] = {Cl0, Cl1, Cl2};

  f32x4 acc[NB][2][2];
  const f32x4 z4 = {0.f, 0.f, 0.f, 0.f};
#pragma unroll
  for (int i = 0; i < NB; i++) {
    acc[i][0][0] = z4; acc[i][0][1] = z4; acc[i][1][0] = z4; acc[i][1][1] = z4;
  }

  auto stage = [&](int buf, int kb) {
    gll16(Ah + aOff + kb * 32, (char*)&AhS[buf][0][0] + (wave << 10));
    gll16(Al + aOff + kb * 32, (char*)&AlS[buf][0][0] + (wave << 10));
    const long long bo = bOff + (long long)kb * (kD * 32);
#pragma unroll
    for (int i = 0; i < NB; i++) {
      gll16(pBh[i] + bo, (char*)&BhS[i][buf][0][0][0] + (wave << 10));
      gll16(pBl[i] + bo, (char*)&BlS[i][buf][0][0][0] + (wave << 10));
    }
  };

  stage(0, 0);
  __syncthreads();
  for (int kb = 0; kb < kD / 32; kb++) {
    const int cur = kb & 1;
    if (kb + 1 < kD / 32) stage(cur ^ 1, kb + 1);
    short8 ah0 = *(const short8*)&AhS[cur][wr * 32 + l16][quad * 8];
    short8 ah1 = *(const short8*)&AhS[cur][wr * 32 + 16 + l16][quad * 8];
    short8 al0 = *(const short8*)&AlS[cur][wr * 32 + l16][quad * 8];
    short8 al1 = *(const short8*)&AlS[cur][wr * 32 + 16 + l16][quad * 8];
#pragma unroll
    for (int i = 0; i < NB; i++) {
      short8 bh0 = *(const short8*)&BhS[i][cur][quad][wc * 32 + l16][0];
      short8 bh1 = *(const short8*)&BhS[i][cur][quad][wc * 32 + 16 + l16][0];
      short8 bl0 = *(const short8*)&BlS[i][cur][quad][wc * 32 + l16][0];
      short8 bl1 = *(const short8*)&BlS[i][cur][quad][wc * 32 + 16 + l16][0];
      acc[i][0][0] = __builtin_amdgcn_mfma_f32_16x16x32_bf16(al0, bh0, acc[i][0][0], 0, 0, 0);
      acc[i][0][1] = __builtin_amdgcn_mfma_f32_16x16x32_bf16(al0, bh1, acc[i][0][1], 0, 0, 0);
      acc[i][1][0] = __builtin_amdgcn_mfma_f32_16x16x32_bf16(al1, bh0, acc[i][1][0], 0, 0, 0);
      acc[i][1][1] = __builtin_amdgcn_mfma_f32_16x16x32_bf16(al1, bh1, acc[i][1][1], 0, 0, 0);
      acc[i][0][0] = __builtin_amdgcn_mfma_f32_16x16x32_bf16(ah0, bl0, acc[i][0][0], 0, 0, 0);
      acc[i][0][1] = __builtin_amdgcn_mfma_f32_16x16x32_bf16(ah0, bl1, acc[i][0][1], 0, 0, 0);
      acc[i][1][0] = __builtin_amdgcn_mfma_f32_16x16x32_bf16(ah1, bl0, acc[i][1][0], 0, 0, 0);
      acc[i][1][1] = __builtin_amdgcn_mfma_f32_16x16x32_bf16(ah1, bl1, acc[i][1][1], 0, 0, 0);
      acc[i][0][0] = __builtin_amdgcn_mfma_f32_16x16x32_bf16(ah0, bh0, acc[i][0][0], 0, 0, 0);
      acc[i][0][1] = __builtin_amdgcn_mfma_f32_16x16x32_bf16(ah0, bh1, acc[i][0][1], 0, 0, 0);
      acc[i][1][0] = __builtin_amdgcn_mfma_f32_16x16x32_bf16(ah1, bh0, acc[i][1][0], 0, 0, 0);
      acc[i][1][1] = __builtin_amdgcn_mfma_f32_16x16x32_bf16(ah1, bh1, acc[i][1][1], 0, 0, 0);
    }
    __syncthreads();
  }

#pragma unroll
  for (int i = 0; i < NB; i++) {
#pragma unroll
    for (int sm = 0; sm < 2; sm++) {
#pragma unroll
      for (int r = 0; r < 4; r++) {
        int row = m0 + wr * 32 + sm * 16 + quad * 4 + r;
#pragma unroll
        for (int sn = 0; sn < 2; sn++) {
          int col = n0 + wc * 32 + sn * 16 + l16;
          float v = acc[i][sm][sn][r];
          const long long idx = (long long)row * kD + col;
          if (OS) {
            u16 hh = f2b(v);
            ((u16*)pC[i])[idx] = hh;
            pCl[i][idx] = f2b(v - b2f(hh));
          } else {
            if (bias && i == 0) v += ldIn(bias, col, f32in);
            ((float*)pC[i])[idx] = v;
          }
        }
      }
    }
  }
}

// ------------------------------------- MoE weight repack fp32 -> bf16 -------
__global__ __launch_bounds__(256) void cvtW_k(const void* src, u16* dst,
                                              int nSh, int kbSh, const int* dflag) {
  const int f32 = dflag[0];
  const int gid = blockIdx.x * 256 + threadIdx.x;
  const int N = 1 << nSh;
  const int n = gid & (N - 1);
  const int rest = gid >> nSh;
  const int kg = rest & 3;
  const int kb = (rest >> 2) & ((1 << kbSh) - 1);
  const int e = rest >> (2 + kbSh);
  const long long src0 = ((long long)e << (5 + kbSh + nSh)) +
                         (long long)(kb * 32 + kg * 8) * N + n;
  short8 o;
#pragma unroll
  for (int j = 0; j < 8; j++) o[j] = (short)f2b(ldIn(src, src0 + (long long)j * N, f32));
  *(short8*)(dst + (long long)gid * 8) = o;
}

// x2f (fp32) -> bf16, linear layout
__global__ __launch_bounds__(256) void cvtX_k(const float* src, u16* dst) {
  const int gid = blockIdx.x * 256 + threadIdx.x;
  const float* s = src + (long long)gid * 8;
  float4 a = *(const float4*)s, b = *(const float4*)(s + 4);
  short8 o;
  o[0]=(short)f2b(a.x); o[1]=(short)f2b(a.y); o[2]=(short)f2b(a.z); o[3]=(short)f2b(a.w);
  o[4]=(short)f2b(b.x); o[5]=(short)f2b(b.y); o[6]=(short)f2b(b.z); o[7]=(short)f2b(b.w);
  *(short8*)(dst + (long long)gid * 8) = o;
}

// -------------------------------------------- fused MoE W1/W3 + SwiGLU ------
// 128x128 tile, 512 thr (2x4 waves). Halves B-panel re-reads (L3-BW bound).
__global__ __launch_bounds__(512) void moe13_k(const u16* Xb, const u16* W1c, const u16* W3c,
                                               const int* counts, const int* offsets,
                                               const int* aidxArr, u16* Hbuf) {
  const int e = blockIdx.z;
  const int Meff = counts[e];
  const int m0 = blockIdx.y * 128;
  if (m0 >= Meff) return;
  const int n0 = blockIdx.x * 128;
  const int csr = offsets[e];

  __shared__ __align__(16) u16 As[2][128][32];
  __shared__ __align__(16) u16 B1s[2][4][128][8];
  __shared__ __align__(16) u16 B3s[2][4][128][8];

  const int tid = threadIdx.x, wave = tid >> 6, lane = tid & 63;
  const int wr = wave >> 2, wc = wave & 3, quad = lane >> 4, l16 = lane & 15;

  int grow = m0 + (tid >> 2); if (grow >= Meff) grow = Meff - 1;
  const u16* pA = Xb + (long long)aidxArr[csr + grow] * kD + (tid & 3) * 8;

  const long long ebase = (long long)e * kD * kHID;
  const long long bo = ebase + ((long long)(tid >> 7) * kHID + n0 + (tid & 127)) * 8;

  f32x4 acc1[4][2], acc3[4][2];
  const f32x4 z4 = {0.f, 0.f, 0.f, 0.f};
#pragma unroll
  for (int i = 0; i < 4; i++) { acc1[i][0]=z4; acc1[i][1]=z4; acc3[i][0]=z4; acc3[i][1]=z4; }

  auto stage = [&](int buf, int kb) {
    gll16(pA + kb * 32, (char*)&As[buf][0][0] + (wave << 10));
    const long long ko = (long long)kb * (4 * kHID * 8);
    gll16(W1c + bo + ko, (char*)&B1s[buf][0][0][0] + (wave << 10));
    gll16(W3c + bo + ko, (char*)&B3s[buf][0][0][0] + (wave << 10));
  };

  stage(0, 0);
  __syncthreads();
  for (int kb = 0; kb < kD / 32; kb++) {
    const int cur = kb & 1;
    if (kb + 1 < kD / 32) stage(cur ^ 1, kb + 1);
    short8 af[4];
#pragma unroll
    for (int sm = 0; sm < 4; sm++)
      af[sm] = *(const short8*)&As[cur][wr * 64 + sm * 16 + l16][quad * 8];
    short8 b1f[2], b3f[2];
#pragma unroll
    for (int sn = 0; sn < 2; sn++) {
      b1f[sn] = *(const short8*)&B1s[cur][quad][wc * 32 + sn * 16 + l16][0];
      b3f[sn] = *(const short8*)&B3s[cur][quad][wc * 32 + sn * 16 + l16][0];
    }
#pragma unroll
    for (int sm = 0; sm < 4; sm++) {
#pragma unroll
      for (int sn = 0; sn < 2; sn++) {
        acc1[sm][sn] = __builtin_amdgcn_mfma_f32_16x16x32_bf16(af[sm], b1f[sn], acc1[sm][sn], 0, 0, 0);
        acc3[sm][sn] = __builtin_amdgcn_mfma_f32_16x16x32_bf16(af[sm], b3f[sn], acc3[sm][sn], 0, 0, 0);
      }
    }
    __syncthreads();
  }

#pragma unroll
  for (int sm = 0; sm < 4; sm++) {
#pragma unroll
    for (int r = 0; r < 4; r++) {
      int row = m0 + wr * 64 + sm * 16 + quad * 4 + r;
      if (row >= Meff) continue;
#pragma unroll
      for (int sn = 0; sn < 2; sn++) {
        int col = n0 + wc * 32 + sn * 16 + l16;
        float g1 = acc1[sm][sn][r], g3 = acc3[sm][sn][r];
        float h = (g1 / (1.f + __expf(-g1))) * g3;
        Hbuf[(long long)(csr + row) * kHID + col] = f2b(h);
      }
    }
  }
}

// ------------------------------------------------ MoE W2 + scatter ---------
__global__ __launch_bounds__(256) void w2_k(const u16* Hbuf, const u16* W2c,
                                            const int* counts, const int* offsets,
                                            const int* aidxArr, const int* slotArr,
                                            const float* wgtArr, float* contrib) {
  const int e = blockIdx.z;
  const int Meff = counts[e];
  const int m0 = blockIdx.y * 64;
  if (m0 >= Meff) return;
  const int n0 = blockIdx.x * 128;
  const int csr = offsets[e];

  __shared__ __align__(16) u16 As[2][64][32];
  __shared__ __align__(16) u16 Bs[2][4][128][8];

  const int tid = threadIdx.x, wave = tid >> 6, lane = tid & 63;
  const int wc = wave, quad = lane >> 4, l16 = lane & 15;

  int grow = m0 + (tid >> 2); if (grow >= Meff) grow = Meff - 1;
  const u16* pA = Hbuf + (long long)(csr + grow) * kHID + (tid & 3) * 8;

  const long long ebase = (long long)e * kHID * kD;
  const int g0 = tid, g1 = 256 + tid;
  const long long b0o = ebase + ((long long)(g0 >> 7) * kD + n0 + (g0 & 127)) * 8;
  const long long b1o = ebase + ((long long)(g1 >> 7) * kD + n0 + (g1 & 127)) * 8;

  f32x4 acc[4][2];
  const f32x4 z4 = {0.f, 0.f, 0.f, 0.f};
#pragma unroll
  for (int i = 0; i < 4; i++) { acc[i][0] = z4; acc[i][1] = z4; }

  auto stage = [&](int buf, int kb) {
    gll16(pA + kb * 32, (char*)&As[buf][0][0] + (wave << 10));
    const long long ko = (long long)kb * (4 * kD * 8);
    gll16(W2c + b0o + ko, (char*)&Bs[buf][0][0][0] + (wave << 10));
    gll16(W2c + b1o + ko, (char*)&Bs[buf][0][0][0] + 4096 + (wave << 10));
  };

  stage(0, 0);
  __syncthreads();
  for (int kb = 0; kb < kHID / 32; kb++) {
    const int cur = kb & 1;
    if (kb + 1 < kHID / 32) stage(cur ^ 1, kb + 1);
    short8 af[4];
#pragma unroll
    for (int sm = 0; sm < 4; sm++)
      af[sm] = *(const short8*)&As[cur][sm * 16 + l16][quad * 8];
    short8 bf[2];
#pragma unroll
    for (int sn = 0; sn < 2; sn++)
      bf[sn] = *(const short8*)&Bs[cur][quad][wc * 32 + sn * 16 + l16][0];
#pragma unroll
    for (int sm = 0; sm < 4; sm++) {
#pragma unroll
      for (int sn = 0; sn < 2; sn++)
        acc[sm][sn] = __builtin_amdgcn_mfma_f32_16x16x32_bf16(af[sm], bf[sn], acc[sm][sn], 0, 0, 0);
    }
    __syncthreads();
  }

#pragma unroll
  for (int sm = 0; sm < 4; sm++) {
#pragma unroll
    for (int r = 0; r < 4; r++) {
      int row = m0 + sm * 16 + quad * 4 + r;
      if (row >= Meff) continue;
      int a = csr + row;
      int t = aidxArr[a]; int s = slotArr[a]; float w = wgtArr[a];
#pragma unroll
      for (int sn = 0; sn < 2; sn++) {
        int col = n0 + wc * 32 + sn * 16 + l16;
        contrib[((long long)s * kTok + t) * kD + col] = acc[sm][sn][r] * w;
      }
    }
  }
}

// ------------------------------------------------------------ small ops -----
__global__ void maskprep_k(const void* srcm, const void* tgtm, const void* midm,
                           float* srcf, float* padf, float* keepf, float* denom) {
  __shared__ int okInt, okFloat, okBf16;
  int tid = threadIdx.x;
  if (tid == 0) { okInt = 1; okFloat = 1; okBf16 = 1; }
  __syncthreads();
  const unsigned int* wi = (const unsigned int*)tgtm;
  const float* wf = (const float*)tgtm;
  int badI = 0, badF = 0, badB = 0;
  for (int i = tid; i < 512; i += 256) {
    unsigned int w = wi[i];
    if (w > 1u) badI = 1;
    float f = wf[i];
    if (!(f == 0.f || f == 1.f)) badF = 1;
    unsigned int lo = w & 0xffffu, hi = w >> 16;
    if (!((lo == 0 || lo == 0x3f80u) && (hi == 0 || hi == 0x3f80u))) badB = 1;
  }
  if (badI) atomicExch(&okInt, 0);
  if (badF) atomicExch(&okFloat, 0);
  if (badB) atomicExch(&okBf16, 0);
  __syncthreads();
  int mode = okInt ? 0 : (okFloat ? 2 : (okBf16 ? 3 : 1));
  for (int i = tid; i < kTok; i += 256) {
    bool sv, pv, mv;
    if (mode == 0) {
      sv = ((const int*)srcm)[i] != 0; pv = ((const int*)tgtm)[i] != 0; mv = ((const int*)midm)[i] != 0;
    } else if (mode == 2) {
      sv = ((const float*)srcm)[i] != 0.f; pv = ((const float*)tgtm)[i] != 0.f; mv = ((const float*)midm)[i] != 0.f;
    } else if (mode == 3) {
      sv = ((const u16*)srcm)[i] != 0; pv = ((const u16*)tgtm)[i] != 0; mv = ((const u16*)midm)[i] != 0;
    } else {
      sv = ((const unsigned char*)srcm)[i] != 0; pv = ((const unsigned char*)tgtm)[i] != 0; mv = ((const unsigned char*)midm)[i] != 0;
    }
    srcf[i] = sv ? 1.f : 0.f;
    padf[i] = pv ? 1.f : 0.f;
    keepf[i] = (pv || mv) ? 0.f : 1.f;
  }
  __syncthreads();
  if (tid < 2) {
    float s = 0;
    for (int j = 0; j < kS; j++) s += keepf[tid * kS + j];
    denom[tid] = fmaxf(s, 1.f);
  }
}

__global__ __launch_bounds__(256) void ln_k(const float* basef, const void* baseb,
                                            const int* dflag, int baseIsIn,
                                            const float* add1, const float* add2,
                                            const void* g, const void* bb,
                                            float* outf, void* outFinal) {
  const int f32in = dflag[0];
  const int baseF32 = baseIsIn && f32in;
  long long base = (long long)blockIdx.x * kD;
  int tid = threadIdx.x;
  float v[4]; float s = 0;
#pragma unroll
  for (int i = 0; i < 4; i++) {
    int d = tid + i * 256;
    float x = basef ? basef[base + d] : ldIn(baseb, base + d, baseF32);
    if (add1) x += add1[base + d];
    if (add2) x += add2[base + d];
    v[i] = x; s += x;
  }
  float mean = blockReduceSum(s) * (1.f / kD);
  float q = 0;
#pragma unroll
  for (int i = 0; i < 4; i++) { float d0 = v[i] - mean; q += d0 * d0; }
  float var = blockReduceSum(q) * (1.f / kD);
  float rstd = rsqrtf(var + 1e-5f);
#pragma unroll
  for (int i = 0; i < 4; i++) {
    int d = tid + i * 256;
    float y = (v[i] - mean) * rstd * ldIn(g, d, f32in) + ldIn(bb, d, f32in);
    if (outf) outf[base + d] = y;
    if (outFinal) stOut(outFinal, base + d, y, f32in);
  }
}

__global__ __launch_bounds__(256) void router_k(const float* xf, const void* gw, void* outBase,
                                                int* sel, float* wsel, int* counts,
                                                const int* dflag) {
  const int f32in = dflag[0];
  int wv = threadIdx.x >> 6, lane = threadIdx.x & 63;
  int t = blockIdx.x * 4 + wv;
  const float* xr = xf + (long long)t * kD;
  float acc[8];
#pragma unroll
  for (int e = 0; e < 8; e++) acc[e] = 0.f;
  for (int d = lane; d < kD; d += 64) {
    float xv = xr[d];
    float gv[8];
    ld8f(gw, (long long)d * 8, f32in, gv);
#pragma unroll
    for (int e = 0; e < 8; e++) acc[e] += xv * gv[e];
  }
#pragma unroll
  for (int o = 32; o; o >>= 1) {
#pragma unroll
    for (int e = 0; e < 8; e++) acc[e] += __shfl_down(acc[e], o, 64);
  }
  if (lane == 0) {
    float mx = acc[0];
    for (int e = 1; e < 8; e++) mx = fmaxf(mx, acc[e]);
    float p[8], sum = 0;
    for (int e = 0; e < 8; e++) { p[e] = expf(acc[e] - mx); sum += p[e]; }
    float inv = 1.f / sum;
    for (int e = 0; e < 8; e++) {
      p[e] *= inv;
      stOut(outBase, kOutProbs + (long long)t * 8 + e, p[e], f32in);
    }
    int e0 = 0; for (int e = 1; e < 8; e++) if (p[e] > p[e0]) e0 = e;
    int e1 = -1; for (int e = 0; e < 8; e++) { if (e == e0) continue; if (e1 < 0 || p[e] > p[e1]) e1 = e; }
    float s2 = p[e0] + p[e1];
    sel[t * 2] = e0; sel[t * 2 + 1] = e1;
    wsel[t * 2] = p[e0] / s2; wsel[t * 2 + 1] = p[e1] / s2;
    atomicAdd(&counts[e0], 1); atomicAdd(&counts[e1], 1);
  }
}

__global__ void offsets_k(const int* counts, int* offsets) {
  if (threadIdx.x == 0) {
    int s = 0;
    for (int e = 0; e < kE; e++) { offsets[e] = s; s += counts[e]; }
    offsets[kE] = s;
  }
}

__global__ void place_k(const int* sel, const float* wsel, const int* offsets, int* fill,
                        int* aidxArr, int* slotArr, float* wgtArr) {
  int t = blockIdx.x * 256 + threadIdx.x;
  if (t >= kTok) return;
  for (int s = 0; s < 2; s++) {
    int e = sel[t * 2 + s];
    int pos = offsets[e] + atomicAdd(&fill[e], 1);
    aidxArr[pos] = t; slotArr[pos] = s; wgtArr[pos] = wsel[t * 2 + s];
  }
}

__global__ void meanacc_k(const int* counts, const int* offsets, const int* aidxArr,
                          const int* slotArr, const float* keepf, const float* contrib,
                          float* meanAcc) {
  int e = blockIdx.x, dc = blockIdx.y, ch = blockIdx.z;
  int d = dc * 128 + threadIdx.x;
  int cnt = counts[e], off = offsets[e];
  int per = (cnt + 15) / 16;
  int i0 = ch * per, i1 = i0 + per; if (i1 > cnt) i1 = cnt;
  float a0 = 0, a1 = 0;
  for (int i = i0; i < i1; i++) {
    int a = off + i; int t = aidxArr[a];
    if (keepf[t] != 0.f) {
      float v = contrib[((long long)slotArr[a] * kTok + t) * kD + d];
      if (t < kS) a0 += v; else a1 += v;
    }
  }
  if (a0 != 0.f) atomicAdd(&meanAcc[(e * 2 + 0) * kD + d], a0);
  if (a1 != 0.f) atomicAdd(&meanAcc[(e * 2 + 1) * kD + d], a1);
}

__global__ __launch_bounds__(256) void dots_k(const float* meanAcc, const void* cls_w,
                                              const float* denom, float* dots,
                                              const int* dflag) {
  const int f32in = dflag[0];
  int eb = blockIdx.x;
  int b = eb & 1;
  float s = 0;
  for (int d = threadIdx.x; d < kD; d += 256)
    s += meanAcc[(long long)eb * kD + d] * ldIn(cls_w, d, f32in);
  s = blockReduceSum(s);
  if (threadIdx.x == 0) dots[eb] = s / denom[b];
}

__global__ void final_logits_k(const float* dots, const void* cls_b, void* outBase,
                               const int* dflag) {
  const int f32in = dflag[0];
  int i = threadIdx.x;
  if (i < kE * kB) {
    int e = i >> 1, b = i & 1;
    float s = ldIn(cls_b, 0, f32in);
    for (int e2 = 0; e2 <= e; e2++) s += dots[e2 * 2 + b];
    stOut(outBase, kOutLogits + e * kB + b, s, f32in);
  }
}

// ------------------------------------------------------------------ host ----
extern "C" void kernel_launch(void* const* d_in, const int* in_sizes, int n_in,
                              void* d_out, int out_size, void* d_ws, size_t ws_size,
                              hipStream_t stream) {
  (void)in_sizes; (void)n_in; (void)out_size; (void)ws_size;

  const void* x_in  = d_in[0];
  const void* enc   = d_in[1];
  const void* srcm = d_in[2];
  const void* tgtm = d_in[3];
  const void* midm = d_in[4];
  const void* ln1g = d_in[5];  const void* ln1b = d_in[6];
  const void* ln2g = d_in[7];  const void* ln2b = d_in[8];
  const void* ln3g = d_in[9];  const void* ln3b = d_in[10];
  const void* sa_wq = d_in[11]; const void* sa_wk = d_in[12];
  const void* sa_wv = d_in[13]; const void* sa_wo = d_in[14];
  const void* sa_bo = d_in[15];
  const void* ca_wq = d_in[16]; const void* ca_wk = d_in[17];
  const void* ca_wv = d_in[18]; const void* ca_wo = d_in[19];
  const void* ca_bo = d_in[20];
  const void* gate_w = d_in[21];
  const void* cls_w  = d_in[22]; const void* cls_b = d_in[23];
  const void* moe_w1 = d_in[24];
  const void* moe_w2 = d_in[25];
  const void* moe_w3 = d_in[26];

  char* wp = (char*)d_ws;
  size_t off = 0;
  auto alloc = [&](size_t bytes) -> void* {
    void* p = wp + off; off = (off + bytes + 255) & ~(size_t)255; return p;
  };
  float* scFP = (float*)alloc((size_t)16 * kS * kS * 4);          // 64 MiB scratch
  u16*   Hbuf = (u16*)scFP;                                        // [0,16) MiB (MoE)
  float* contrib = (float*)((char*)scFP + (size_t)2 * kTok * kHID * 2); // [16,32) MiB
  float* qf    = (float*)alloc((size_t)kTok * kD * 4);
  float* kf    = (float*)alloc((size_t)kTok * kD * 4);
  float* vf    = (float*)alloc((size_t)kTok * kD * 4);
  float* attnof= (float*)alloc((size_t)kTok * kD * 4);
  float* obuf  = (float*)alloc((size_t)kTok * kD * 4);
  float* x1f   = (float*)alloc((size_t)kTok * kD * 4);
  float* x2f   = (float*)alloc((size_t)kTok * kD * 4);
  float* meanAcc = (float*)alloc((size_t)kE * kB * kD * 4);
  float* srcf = (float*)alloc(kTok * 4);
  float* padf = (float*)alloc(kTok * 4);
  float* keepf = (float*)alloc(kTok * 4);
  float* denom = (float*)alloc(2 * 4);
  int* counts = (int*)alloc(256); int* fill = counts + 8;
  int* offsets = (int*)alloc(256);
  int* sel = (int*)alloc(kTok * 2 * 4);
  float* wsel = (float*)alloc(kTok * 2 * 4);
  int* aidxArr = (int*)alloc(2 * kTok * 4);
  int* slotArr = (int*)alloc(2 * kTok * 4);
  float* wgtArr = (float*)alloc(2 * kTok * 4);
  float* dots = (float*)alloc(256);
  int* dflag = (int*)alloc(256);

  // Split scratch (dead-at-the-time regions):
  u16* WH0 = (u16*)x2f;
  u16* WL0 = WH0 + (1 << 20);
  u16* WH1 = WL0 + (1 << 20);
  u16* WL1 = WH1 + (1 << 20);
  u16* WH2 = (u16*)x1f;
  u16* WL2 = WH2 + (1 << 20);
  u16* AH  = (u16*)scFP;
  u16* AL  = AH + (2 << 20);

  // Split Q/K/V/O (live in qf/kf/vf/attnof; hi then lo, 4 MiB each):
  u16* Qh = (u16*)qf;     u16* Ql = Qh + (2 << 20);
  u16* Kh = (u16*)kf;     u16* Kl = Kh + (2 << 20);
  u16* Vh = (u16*)vf;     u16* Vl = Vh + (2 << 20);
  u16* Oh = (u16*)attnof; u16* Ol = Oh + (2 << 20);

  // MoE repack buffers:
  u16* W1c = (u16*)qf;                                     // qf..attnof 32 MiB
  u16* W2c = (u16*)qf;
  u16* W3c = (u16*)((char*)scFP + ((size_t)32 << 20));
  u16* Xb  = (u16*)obuf;

  hipMemsetAsync(counts, 0, 64, stream);
  hipMemsetAsync(meanAcc, 0, (size_t)kE * kB * kD * 4, stream);
  detect_k<<<1, 256, 0, stream>>>(x_in, dflag);
  maskprep_k<<<1, 256, 0, stream>>>(srcm, tgtm, midm, srcf, padf, keepf, denom);

  const dim3 gGrid(16, 32);
  const dim3 aGrid(512);

  // ---- self attention ----
  splitA_k<<<1024, 256, 0, stream>>>(x_in, AH, AL, 0, dflag);
  splitW_k<<<dim3(512, 1, 3), 256, 0, stream>>>(sa_wq, sa_wk, sa_wv,
      WH0, WL0, WH1, WL1, WH2, WL2, dflag);
  gemmS_k<3, 1><<<gGrid, 256, 0, stream>>>(AH, AL, WH0, WL0, WH1, WL1, WH2, WL2,
      Qh, Kh, Vh, Ql, Kl, Vl, nullptr, dflag);
  fattn_k<<<aGrid, 256, 0, stream>>>(Qh, Ql, Kh, Kl, Vh, Vl, padf, Oh, Ol);
  splitW_k<<<dim3(512, 1, 1), 256, 0, stream>>>(sa_wo, nullptr, nullptr,
      WH0, WL0, nullptr, nullptr, nullptr, nullptr, dflag);
  gemmS_k<1, 0><<<gGrid, 256, 0, stream>>>(Oh, Ol, WH0, WL0, WH0, WL0, WH0, WL0,
      obuf, obuf, obuf, nullptr, nullptr, nullptr, sa_bo, dflag);
  ln_k<<<kTok, 256, 0, stream>>>(nullptr, x_in, dflag, 1, obuf, nullptr, ln1g, ln1b, x1f, nullptr);

  // ---- cross attention ----
  splitA_k<<<1024, 256, 0, stream>>>(x1f, AH, AL, 1, dflag);
  splitW_k<<<dim3(512, 1, 1), 256, 0, stream>>>(ca_wq, nullptr, nullptr,
      WH0, WL0, nullptr, nullptr, nullptr, nullptr, dflag);
  gemmS_k<1, 1><<<gGrid, 256, 0, stream>>>(AH, AL, WH0, WL0, WH0, WL0, WH0, WL0,
      Qh, Qh, Qh, Ql, Ql, Ql, nullptr, dflag);
  splitA_k<<<1024, 256, 0, stream>>>(enc, AH, AL, 0, dflag);
  splitW_k<<<dim3(512, 1, 2), 256, 0, stream>>>(ca_wk, ca_wv, nullptr,
      WH0, WL0, WH1, WL1, nullptr, nullptr, dflag);
  gemmS_k<2, 1><<<gGrid, 256, 0, stream>>>(AH, AL, WH0, WL0, WH1, WL1, WH0, WL0,
      Kh, Vh, Vh, Kl, Vl, Vl, nullptr, dflag);
  fattn_k<<<aGrid, 256, 0, stream>>>(Qh, Ql, Kh, Kl, Vh, Vl, srcf, Oh, Ol);
  splitW_k<<<dim3(512, 1, 1), 256, 0, stream>>>(ca_wo, nullptr, nullptr,
      WH0, WL0, nullptr, nullptr, nullptr, nullptr, dflag);
  gemmS_k<1, 0><<<gGrid, 256, 0, stream>>>(Oh, Ol, WH0, WL0, WH0, WL0, WH0, WL0,
      obuf, obuf, obuf, nullptr, nullptr, nullptr, ca_bo, dflag);
  ln_k<<<kTok, 256, 0, stream>>>(x1f, nullptr, dflag, 0, obuf, nullptr, ln2g, ln2b, x2f, nullptr);

  // ---- MoE ----
  router_k<<<kTok / 4, 256, 0, stream>>>(x2f, gate_w, d_out, sel, wsel, counts, dflag);
  offsets_k<<<1, 64, 0, stream>>>(counts, offsets);
  place_k<<<kTok / 256, 256, 0, stream>>>(sel, wsel, offsets, fill, aidxArr, slotArr, wgtArr);

  cvtX_k<<<kTok * kD / (8 * 256), 256, 0, stream>>>(x2f, Xb);
  const int wGrid = (kE * kD * kHID / 8) / 256;   // 8192
  cvtW_k<<<wGrid, 256, 0, stream>>>(moe_w1, W1c, 11, 5, dflag);  // K=1024,N=2048
  cvtW_k<<<wGrid, 256, 0, stream>>>(moe_w3, W3c, 11, 5, dflag);

  moe13_k<<<dim3(kHID / 128, kTok / 128, kE), 512, 0, stream>>>(
      Xb, W1c, W3c, counts, offsets, aidxArr, Hbuf);

  cvtW_k<<<wGrid, 256, 0, stream>>>(moe_w2, W2c, 10, 6, dflag);  // K=2048,N=1024

  w2_k<<<dim3(kD / 128, kTok / 64, kE), 256, 0, stream>>>(
      Hbuf, W2c, counts, offsets, aidxArr, slotArr, wgtArr, contrib);

  meanacc_k<<<dim3(kE, kD / 128, 16), 128, 0, stream>>>(counts, offsets, aidxArr, slotArr, keepf, contrib, meanAcc);
  dots_k<<<kE * kB, 256, 0, stream>>>(meanAcc, cls_w, denom, dots, dflag);
  final_logits_k<<<1, 64, 0, stream>>>(dots, cls_b, d_out, dflag);
  ln_k<<<kTok, 256, 0, stream>>>(x2f, nullptr, dflag, 0, contrib, contrib + (size_t)kTok * kD, ln3g, ln3b, nullptr, d_out);
}